// Round 1
// baseline (1926.905 us; speedup 1.0000x reference)
//
#include <hip/hip_runtime.h>

// Problem constants
static constexpr int B_ = 4;
static constexpr int N_ = 16384;
static constexpr int M_ = 512;
static constexpr int P1 = M_ * 64;   // 32768 per-batch stage1 columns
static constexpr int P2 = M_ * 9;    // 4608 per-batch stage2 columns
static constexpr int PM = B_ * M_;   // 2048 mlp columns

// ---------------------------------------------------------------------------
// Ball query: one wave (64 threads) per (b,m). Scan N points in order, collect
// first 64 indices with dist^2 < 4, count ALL in-ball points, pad with slot 0.
// ---------------------------------------------------------------------------
__global__ void ball_query_kernel(const float* __restrict__ x,
                                  const float* __restrict__ node,
                                  int* __restrict__ idx) {
    int bm = blockIdx.x;             // 0 .. B*M-1
    int b = bm / M_, m = bm % M_;
    int lane = threadIdx.x;          // 0..63
    __shared__ int s_idx[64];
    s_idx[lane] = 0;
    __syncthreads();

    const float* xb = x + (size_t)b * 3 * N_;
    float nx = node[((size_t)b * 3 + 0) * M_ + m];
    float ny = node[((size_t)b * 3 + 1) * M_ + m];
    float nz = node[((size_t)b * 3 + 2) * M_ + m];
    float aa = nx * nx + ny * ny + nz * nz;

    int total = 0;
    for (int n0 = 0; n0 < N_; n0 += 64) {
        int n = n0 + lane;
        float px = xb[n], py = xb[N_ + n], pz = xb[2 * N_ + n];
        float bb = px * px + py * py + pz * pz;
        float ab = nx * px + ny * py + nz * pz;
        float d = aa + bb - 2.0f * ab;
        bool inb = d < 4.0f;
        unsigned long long mask = __ballot(inb);
        if (inb && total < 64) {
            int pos = total + __popcll(mask & ((1ull << lane) - 1ull));
            if (pos < 64) s_idx[pos] = n;
        }
        total += __popcll(mask);
    }
    __syncthreads();
    int start = total < 64 ? total : 64;
    int v = (lane < start) ? s_idx[lane] : s_idx[0];
    idx[(size_t)bm * 64 + lane] = v;
}

// ---------------------------------------------------------------------------
// KNN over nodes: one wave per (b,m); 9 rounds of lexicographic (dist,idx)
// argmin extraction == lax.top_k(-sqd, 9) tie-breaking.
// ---------------------------------------------------------------------------
__global__ void knn_kernel(const float* __restrict__ node, int* __restrict__ knn) {
    int bm = blockIdx.x;
    int b = bm / M_, m = bm % M_;
    int lane = threadIdx.x;
    const float* nb = node + (size_t)b * 3 * M_;
    float nx = nb[m], ny = nb[M_ + m], nz = nb[2 * M_ + m];
    float aa = nx * nx + ny * ny + nz * nz;

    float dist[8];
    int didx[8];
#pragma unroll
    for (int i = 0; i < 8; ++i) {
        int n = lane + i * 64;
        float px = nb[n], py = nb[M_ + n], pz = nb[2 * M_ + n];
        float bb = px * px + py * py + pz * pz;
        float ab = nx * px + ny * py + nz * pz;
        dist[i] = aa + bb - 2.0f * ab;
        didx[i] = n;
    }
    for (int r = 0; r < 9; ++r) {
        float bv = dist[0]; int bi = didx[0]; int bslot = 0;
#pragma unroll
        for (int i = 1; i < 8; ++i) {
            if (dist[i] < bv || (dist[i] == bv && didx[i] < bi)) {
                bv = dist[i]; bi = didx[i]; bslot = i;
            }
        }
        float rv = bv; int ri = bi;
        for (int off = 32; off > 0; off >>= 1) {
            float ov = __shfl_down(rv, off);
            int   oi = __shfl_down(ri, off);
            if (ov < rv || (ov == rv && oi < ri)) { rv = ov; ri = oi; }
        }
        ri = __shfl(ri, 0);
        if (lane == 0) knn[(size_t)bm * 9 + r] = ri;
        if (bi == ri) dist[bslot] = 3.0e38f;
    }
}

// ---------------------------------------------------------------------------
// Gather ball neighborhoods into F0 (6, P1) for batch b; col p = m*64+k.
// ---------------------------------------------------------------------------
__global__ void gather_xb_kernel(const float* __restrict__ x,
                                 const float* __restrict__ sn,
                                 const float* __restrict__ node,
                                 const int* __restrict__ idx,
                                 float* __restrict__ F0, int b) {
    int t = blockIdx.x * blockDim.x + threadIdx.x;   // 6*32768 threads
    if (t >= 6 * P1) return;
    int c = t >> 15;
    int p = t & (P1 - 1);
    int m = p >> 6, k = p & 63;
    int j = idx[(((size_t)b * M_ + m) << 6) + k];
    float v;
    if (c < 3)
        v = x[((size_t)b * 3 + c) * N_ + j] - node[((size_t)b * 3 + c) * M_ + m];
    else
        v = sn[((size_t)b * 3 + (c - 3)) * N_ + j];
    F0[(size_t)c * P1 + p] = v;
}

// ---------------------------------------------------------------------------
// Generic tiled GEMM: out(Co,P) = relu(W(Co,Ci) @ in(Ci,P) + bias)
// 64x64 tile per 256-thread block, 16-deep k chunks, 4x4 register blocking.
// ---------------------------------------------------------------------------
__global__ __launch_bounds__(256) void conv_gemm_kernel(
    const float* __restrict__ in, const float* __restrict__ W,
    const float* __restrict__ bias, float* __restrict__ out,
    int Ci, int Co, int P, int relu) {
    __shared__ float Wt[16][64];   // Wt[kk][co]
    __shared__ float Bt[16][64];   // Bt[kk][p]
    int t = threadIdx.x;
    int p0 = blockIdx.x * 64;
    int co0 = blockIdx.y * 64;
    int tp = t & 15, tco = t >> 4;
    float acc[4][4] = {};

    for (int k0 = 0; k0 < Ci; k0 += 16) {
#pragma unroll
        for (int i = 0; i < 4; ++i) {
            int e = t + i * 256;
            int kk = e & 15, co = e >> 4;
            int gco = co0 + co, gk = k0 + kk;
            Wt[kk][co] = (gco < Co && gk < Ci) ? W[(size_t)gco * Ci + gk] : 0.0f;
            int pp = e & 63, kk2 = e >> 6;
            int gk2 = k0 + kk2;
            Bt[kk2][pp] = (gk2 < Ci) ? in[(size_t)gk2 * P + p0 + pp] : 0.0f;
        }
        __syncthreads();
#pragma unroll
        for (int kk = 0; kk < 16; ++kk) {
            float4 a4 = *(const float4*)&Wt[kk][tco << 2];
            float4 b4 = *(const float4*)&Bt[kk][tp << 2];
            float av[4] = {a4.x, a4.y, a4.z, a4.w};
            float bv[4] = {b4.x, b4.y, b4.z, b4.w};
#pragma unroll
            for (int i = 0; i < 4; ++i)
#pragma unroll
                for (int j = 0; j < 4; ++j)
                    acc[i][j] = fmaf(av[i], bv[j], acc[i][j]);
        }
        __syncthreads();
    }
#pragma unroll
    for (int i = 0; i < 4; ++i) {
        int co = co0 + (tco << 2) + i;
        if (co < Co) {
            float bsv = bias[co];
#pragma unroll
            for (int j = 0; j < 4; ++j) {
                float v = acc[i][j] + bsv;
                if (relu) v = fmaxf(v, 0.0f);
                out[(size_t)co * P + p0 + (tp << 2) + j] = v;
            }
        }
    }
}

// ---------------------------------------------------------------------------
// Fill rows [C..2C) of buf with per-group max over K of rows [0..C).
// ---------------------------------------------------------------------------
__global__ void bcast_max_kernel(float* __restrict__ buf, int C, int P, int K, int cols) {
    int t = blockIdx.x * blockDim.x + threadIdx.x;
    if (t >= C * cols) return;
    int c = t / cols, m = t - c * cols;
    const float* p = buf + (size_t)c * P + (size_t)m * K;
    float v = p[0];
    for (int i = 1; i < K; ++i) v = fmaxf(v, p[i]);
    float* q = buf + (size_t)(C + c) * P + (size_t)m * K;
    for (int i = 0; i < K; ++i) q[i] = v;
}

// Max over K -> out[c*ostride + ooff + m]
__global__ void maxpool_kernel(const float* __restrict__ in, float* __restrict__ out,
                               int C, int K, int cols, int ostride, int ooff) {
    int t = blockIdx.x * blockDim.x + threadIdx.x;
    if (t >= C * cols) return;
    int c = t / cols, m = t - c * cols;
    const float* p = in + (size_t)c * cols * K + (size_t)m * K;
    float v = p[0];
    for (int i = 1; i < K; ++i) v = fmaxf(v, p[i]);
    out[(size_t)c * ostride + ooff + m] = v;
}

// ---------------------------------------------------------------------------
// Gather KNN neighborhoods into G0 (131, P2) for batch b; col p = m*9+kk.
// Rows 0..2: relative coords; rows 3..130: feat1 (h rows 0..127).
// ---------------------------------------------------------------------------
__global__ void gather_g_kernel(const float* __restrict__ node,
                                const float* __restrict__ h,
                                const int* __restrict__ knn,
                                float* __restrict__ G0, int b) {
    int t = blockIdx.x * blockDim.x + threadIdx.x;
    if (t >= 131 * P2) return;
    int c = t / P2, p = t - c * P2;
    int m = p / 9, kk = p - m * 9;
    int j = knn[((size_t)b * M_ + m) * 9 + kk];
    float v;
    if (c < 3)
        v = node[((size_t)b * 3 + c) * M_ + j] - node[((size_t)b * 3 + c) * M_ + m];
    else
        v = h[(size_t)(c - 3) * PM + (size_t)b * M_ + j];
    G0[(size_t)c * P2 + p] = v;
}

// ---------------------------------------------------------------------------
// Epilogue: out = [node | node + ksig[0:3] | softplus(ksig[3]) + 1e-3]
// ---------------------------------------------------------------------------
__global__ void final_kernel(const float* __restrict__ node,
                             const float* __restrict__ ksig,
                             float* __restrict__ out) {
    int t = blockIdx.x * blockDim.x + threadIdx.x;   // 0..2047
    if (t >= PM) return;
    int b = t >> 9, m = t & 511;
#pragma unroll
    for (int c = 0; c < 3; ++c) {
        float nv = node[((size_t)b * 3 + c) * M_ + m];
        out[((size_t)b * 3 + c) * M_ + m] = nv;
        out[6144 + ((size_t)b * 3 + c) * M_ + m] = nv + ksig[(size_t)c * PM + t];
    }
    float s = ksig[(size_t)3 * PM + t];
    out[12288 + t] = fmaxf(s, 0.0f) + log1pf(expf(-fabsf(s))) + 0.001f;
}

// ---------------------------------------------------------------------------
extern "C" void kernel_launch(void* const* d_in, const int* in_sizes, int n_in,
                              void* d_out, int out_size, void* d_ws, size_t ws_size,
                              hipStream_t stream) {
    (void)in_sizes; (void)n_in; (void)out_size; (void)ws_size;
    const float* x    = (const float*)d_in[0];
    const float* sn   = (const float*)d_in[1];
    const float* node = (const float*)d_in[2];
    const float* W[13]; const float* Bs[13];
    for (int i = 0; i < 13; ++i) {
        W[i]  = (const float*)d_in[3 + 2 * i];
        Bs[i] = (const float*)d_in[4 + 2 * i];
    }
    // weight index map: 0..4 conv1..5, 5..7 knnb1..3, 8..9 knna1..2, 10..11 mlp1..2, 12 mlp3
    float* out = (float*)d_out;

    // ---- workspace arena (all offsets 256B aligned) ----
    char* ws = (char*)d_ws;
    int*   idx  = (int*)(ws + 0);                 //   524,288
    int*   knn  = (int*)(ws + 524288);            //    73,728
    float* h    = (float*)(ws + 598016);          // 5,242,880 (640 x 2048)
    float* m1   = (float*)(ws + 5840896);         // 4,194,304
    float* m2   = (float*)(ws + 10035200);        // 2,097,152
    float* ksig = (float*)(ws + 12132352);        //    32,768
    char*  big  = ws + 12165120;                  // ~51 MB reused region
    // stage1 (per batch) layout in big
    float* F0   = (float*)(big + 0);              // (6,P1)
    float* F1a  = (float*)(big + 786432);         // (64,P1)
    float* F1b  = (float*)(big + 9175040);        // (64,P1)
    float* Fcat = (float*)(big + 17563648);       // (128,P1)
    float* F4   = (float*)(big + 34340864);       // (128,P1)
    // stage2 (per batch) layout in big (reused after stage1 of that batch? no —
    // stages are fully sequential across all batches, so reuse is safe)
    float* G0   = (float*)(big + 0);              // (131,P2)
    float* G1   = (float*)(big + 2414592);        // (256,P2)
    float* G2   = (float*)(big + 7133184);        // (256,P2)
    float* Gcat = (float*)(big + 11851776);       // (512,P2)
    float* G3   = (float*)(big + 21288960);       // (512,P2)

    auto conv = [&](const float* in, int wi, float* o, int Ci, int Co, int P, int relu) {
        dim3 grid(P / 64, (Co + 63) / 64);
        conv_gemm_kernel<<<grid, 256, 0, stream>>>(in, W[wi], Bs[wi], o, Ci, Co, P, relu);
    };

    ball_query_kernel<<<B_ * M_, 64, 0, stream>>>(x, node, idx);
    knn_kernel<<<B_ * M_, 64, 0, stream>>>(node, knn);

    // ---- stage 1: ball-neighborhood pointconv stack -> feat1 (h rows 0..127)
    for (int b = 0; b < B_; ++b) {
        gather_xb_kernel<<<(6 * P1) / 256, 256, 0, stream>>>(x, sn, node, idx, F0, b);
        conv(F0, 0, F1a, 6, 64, P1, 1);
        conv(F1a, 1, F1b, 64, 64, P1, 1);
        conv(F1b, 2, Fcat, 64, 64, P1, 1);                      // rows 0..63
        bcast_max_kernel<<<(64 * M_) / 256, 256, 0, stream>>>(Fcat, 64, P1, 64, M_);
        conv(Fcat, 3, F4, 128, 128, P1, 1);
        conv(F4, 4, Fcat, 128, 128, P1, 1);
        maxpool_kernel<<<(128 * M_) / 256, 256, 0, stream>>>(Fcat, h, 128, 64, M_, PM, b * M_);
    }

    // ---- stage 2: knn fusion stack -> feat2 (h rows 128..639)
    for (int b = 0; b < B_; ++b) {
        gather_g_kernel<<<(131 * P2 + 255) / 256, 256, 0, stream>>>(node, h, knn, G0, b);
        conv(G0, 5, G1, 131, 256, P2, 1);
        conv(G1, 6, G2, 256, 256, P2, 1);
        conv(G2, 7, Gcat, 256, 256, P2, 1);                     // rows 0..255
        bcast_max_kernel<<<(256 * M_) / 256, 256, 0, stream>>>(Gcat, 256, P2, 9, M_);
        conv(Gcat, 8, G3, 512, 512, P2, 1);
        conv(G3, 9, Gcat, 512, 512, P2, 1);
        maxpool_kernel<<<(512 * M_) / 256, 256, 0, stream>>>(Gcat, h + (size_t)128 * PM,
                                                             512, 9, M_, PM, b * M_);
    }

    // ---- stage 3: mlp head + epilogue
    conv(h, 10, m1, 640, 512, PM, 1);
    conv(m1, 11, m2, 512, 256, PM, 1);
    conv(m2, 12, ksig, 256, 4, PM, 0);
    final_kernel<<<PM / 256, 256, 0, stream>>>(node, ksig, out);
}

// Round 2
// 419.399 us; speedup vs baseline: 4.5944x; 4.5944x over previous
//
#include <hip/hip_runtime.h>

typedef unsigned short u16;
typedef unsigned int u32;
typedef __bf16 bf16x8 __attribute__((ext_vector_type(8)));
typedef float floatx4 __attribute__((ext_vector_type(4)));
typedef unsigned short u16x4 __attribute__((ext_vector_type(4)));
typedef unsigned int u32x4 __attribute__((ext_vector_type(4)));

static constexpr int B_ = 4;
static constexpr int N_ = 16384;
static constexpr int M_ = 512;

__device__ __forceinline__ u16 f2bf(float f) {
    u32 u = __float_as_uint(f);
    u32 r = (u + 0x7fffu + ((u >> 16) & 1u)) >> 16;
    return (u16)r;
}
__device__ __forceinline__ float bf2f(u16 x) {
    return __uint_as_float(((u32)x) << 16);
}

// 16B async global->LDS stage. ldsbase must be wave-uniform; HW scatters lane*16.
__device__ __forceinline__ void stage16(char* ldsbase, int lane, const void* g) {
#if __has_builtin(__builtin_amdgcn_global_load_lds)
    __builtin_amdgcn_global_load_lds(
        (__attribute__((address_space(1))) void*)(void*)(g),
        (__attribute__((address_space(3))) void*)(void*)(ldsbase), 16, 0, 0);
#else
    *(u32x4*)(ldsbase + lane * 16) = *(const u32x4*)g;
#endif
}

// ---------------------------------------------------------------------------
// Ball query: 4 waves per (b,m); each wave compacts its N/4 chunk, LDS merge.
// ---------------------------------------------------------------------------
__global__ __launch_bounds__(256) void ball_query_kernel(
    const float* __restrict__ x, const float* __restrict__ node, int* __restrict__ idx) {
    int bm = blockIdx.x;
    int b = bm >> 9, m = bm & 511;
    int tid = threadIdx.x, wave = tid >> 6, lane = tid & 63;
    __shared__ int sidx[4][64];
    __shared__ int scnt[4];

    const float* xb = x + (size_t)b * 3 * N_;
    float nx = node[((size_t)b * 3 + 0) * M_ + m];
    float ny = node[((size_t)b * 3 + 1) * M_ + m];
    float nz = node[((size_t)b * 3 + 2) * M_ + m];
    float aa = nx * nx + ny * ny + nz * nz;

    int cnt = 0;
    int base = wave * 4096;
    for (int n0 = base; n0 < base + 4096; n0 += 64) {
        int n = n0 + lane;
        float px = xb[n], py = xb[N_ + n], pz = xb[2 * N_ + n];
        float bb = px * px + py * py + pz * pz;
        float ab = nx * px + ny * py + nz * pz;
        float d = aa + bb - 2.0f * ab;
        bool inb = d < 4.0f;
        unsigned long long mask = __ballot(inb);
        if (inb && cnt < 64) {
            int pos = cnt + __popcll(mask & ((1ull << lane) - 1ull));
            if (pos < 64) sidx[wave][pos] = n;
        }
        cnt += __popcll(mask);
    }
    if (lane == 0) scnt[wave] = cnt;
    __syncthreads();
    if (tid < 64) {
        int c0 = scnt[0], c1 = scnt[1], c2 = scnt[2], c3 = scnt[3];
        int total = c0 + c1 + c2 + c3;
        int v = 0;
        if (total > 0) {
            int lim = total < 64 ? total : 64;
            int slot = tid < lim ? tid : 0;
            int w = 0, pre = 0;
            while (w < 3 && slot >= pre + scnt[w]) { pre += scnt[w]; ++w; }
            v = sidx[w][slot - pre];
        }
        idx[(size_t)bm * 64 + tid] = v;
    }
}

// ---------------------------------------------------------------------------
// KNN over nodes (unchanged from round 0 — exact match with reference top_k).
// ---------------------------------------------------------------------------
__global__ void knn_kernel(const float* __restrict__ node, int* __restrict__ knn) {
    int bm = blockIdx.x;
    int b = bm >> 9, m = bm & 511;
    int lane = threadIdx.x;
    const float* nb = node + (size_t)b * 3 * M_;
    float nx = nb[m], ny = nb[M_ + m], nz = nb[2 * M_ + m];
    float aa = nx * nx + ny * ny + nz * nz;

    float dist[8];
    int didx[8];
#pragma unroll
    for (int i = 0; i < 8; ++i) {
        int n = lane + i * 64;
        float px = nb[n], py = nb[M_ + n], pz = nb[2 * M_ + n];
        float bb = px * px + py * py + pz * pz;
        float ab = nx * px + ny * py + nz * pz;
        dist[i] = aa + bb - 2.0f * ab;
        didx[i] = n;
    }
    for (int r = 0; r < 9; ++r) {
        float bv = dist[0]; int bi = didx[0]; int bslot = 0;
#pragma unroll
        for (int i = 1; i < 8; ++i) {
            if (dist[i] < bv || (dist[i] == bv && didx[i] < bi)) {
                bv = dist[i]; bi = didx[i]; bslot = i;
            }
        }
        float rv = bv; int ri = bi;
        for (int off = 32; off > 0; off >>= 1) {
            float ov = __shfl_down(rv, off);
            int   oi = __shfl_down(ri, off);
            if (ov < rv || (ov == rv && oi < ri)) { rv = ov; ri = oi; }
        }
        ri = __shfl(ri, 0);
        if (lane == 0) knn[(size_t)bm * 9 + r] = ri;
        if (bi == ri) dist[bslot] = 3.0e38f;
    }
}

// ---------------------------------------------------------------------------
// Weight fp32 -> bf16 conversion with K padded to mult-of-32 (zeros).
// ---------------------------------------------------------------------------
struct WConvArgs { const float* src[12]; };

__global__ void convert_weights_kernel(WConvArgs args, u16* __restrict__ dst) {
    const int CI[12] = {6, 64, 64, 128, 128, 131, 256, 256, 512, 512, 640, 512};
    const int KP[12] = {32, 64, 64, 128, 128, 160, 256, 256, 512, 512, 640, 512};
    const int OFF[13] = {0, 2048, 6144, 10240, 26624, 43008, 83968, 149504,
                         215040, 477184, 739328, 1067008, 1198080};
    int e = blockIdx.x * 256 + threadIdx.x;
    if (e >= 1198080) return;
    int w = 0;
    while (e >= OFF[w + 1]) ++w;
    int local = e - OFF[w];
    int kp = KP[w];
    int co = local / kp, k = local - co * kp;
    float v = (k < CI[w]) ? args.src[w][(size_t)co * CI[w] + k] : 0.0f;
    dst[e] = f2bf(v);
}

// ---------------------------------------------------------------------------
// bf16 MFMA GEMM: out[p][co] = relu(sum_k W[co][k]*act[p][k] + bias[co])
// Tile: (WR*64) co x (WC*64) p, 256 threads (4 waves), BK=32.
// Activations/outputs in (P, C) k-major bf16 layout.
// ---------------------------------------------------------------------------
template <int WR, int WC>
__global__ __launch_bounds__(256) void gemm_mfma(
    const u16* __restrict__ Wq, int wstride,
    const u16* __restrict__ act, int astride,
    const float* __restrict__ bias,
    u16* __restrict__ outp, int ostride,
    int K, int relu) {
    constexpr int BM = WR * 64, BN = WC * 64;
    constexpr int ABYTES = BM * 64;   // BM rows x 32 k x 2B
    __shared__ __align__(16) char smem[36864];
    char* ldsA = smem;
    char* ldsB = smem + ABYTES;
    int tid = threadIdx.x;
    int wave = tid >> 6, lane = tid & 63;
    int quad = lane >> 4, l15 = lane & 15;
    int wr = (WR == 2) ? (wave >> 1) : 0;
    int wc = (WR == 2) ? (wave & 1) : wave;
    int co0 = blockIdx.y * BM, p0 = blockIdx.x * BN;

    floatx4 acc[4][4];
#pragma unroll
    for (int t = 0; t < 4; ++t)
#pragma unroll
        for (int u = 0; u < 4; ++u) acc[t][u] = (floatx4){0.f, 0.f, 0.f, 0.f};

    int arow = lane >> 2;
    int acol = (lane & 3) * 8;

    for (int k0 = 0; k0 < K; k0 += 32) {
        __syncthreads();
#pragma unroll
        for (int i = 0; i < WR; ++i) {
            int chunk = wave * WR + i;
            int row = chunk * 16 + arow;
            stage16(ldsA + chunk * 1024, lane,
                    Wq + (size_t)(co0 + row) * wstride + k0 + acol);
        }
#pragma unroll
        for (int i = 0; i < WC; ++i) {
            int chunk = wave * WC + i;
            int row = chunk * 16 + arow;
            stage16(ldsB + chunk * 1024, lane,
                    act + (size_t)(p0 + row) * astride + k0 + acol);
        }
        __syncthreads();
        bf16x8 a[4], b[4];
#pragma unroll
        for (int t = 0; t < 4; ++t)
            a[t] = *(const bf16x8*)(ldsA + ((wr * 64 + t * 16 + l15) * 32 + quad * 8) * 2);
#pragma unroll
        for (int u = 0; u < 4; ++u)
            b[u] = *(const bf16x8*)(ldsB + ((wc * 64 + u * 16 + l15) * 32 + quad * 8) * 2);
#pragma unroll
        for (int t = 0; t < 4; ++t)
#pragma unroll
            for (int u = 0; u < 4; ++u)
                acc[t][u] = __builtin_amdgcn_mfma_f32_16x16x32_bf16(a[t], b[u], acc[t][u], 0, 0, 0);
    }
    __syncthreads();   // all waves done reading staged LDS; reuse as epilogue scratch

    // epilogue: bias+relu+bf16, transpose 64x64 quadrant via LDS (row stride 144B)
    char* ep = smem + wave * 9216;
#pragma unroll
    for (int t = 0; t < 4; ++t)
#pragma unroll
        for (int u = 0; u < 4; ++u) {
            u16x4 pk;
#pragma unroll
            for (int r = 0; r < 4; ++r) {
                int cl = t * 16 + quad * 4 + r;
                float v = acc[t][u][r] + bias[co0 + wr * 64 + cl];
                if (relu) v = fmaxf(v, 0.0f);
                pk[r] = f2bf(v);
            }
            *(u16x4*)(ep + (u * 16 + l15) * 144 + (t * 16 + quad * 4) * 2) = pk;
        }
#pragma unroll
    for (int i = 0; i < 8; ++i) {
        int row = i * 8 + (lane >> 3);
        int col = (lane & 7) * 8;
        u32x4 v = *(const u32x4*)(ep + row * 144 + col * 2);
        *(u32x4*)(outp + (size_t)(p0 + wc * 64 + row) * ostride + co0 + wr * 64 + col) = v;
    }
}

// ---------------------------------------------------------------------------
// Gather ball neighborhoods -> F0 (P_half=65536 rows, 32 ch, k-major bf16).
// ---------------------------------------------------------------------------
__global__ void gather_xb_kernel(const float* __restrict__ x, const float* __restrict__ sn,
                                 const float* __restrict__ node, const int* __restrict__ idx,
                                 u16* __restrict__ F0, int h0) {
    int p = blockIdx.x * 256 + threadIdx.x;   // 0..65535
    int nl = p >> 6, kk = p & 63;
    int bm = h0 * 1024 + nl;
    int b = bm >> 9, m = bm & 511;
    int j = idx[(size_t)bm * 64 + kk];
    const float* xb = x + (size_t)b * 3 * N_;
    const float* sb = sn + (size_t)b * 3 * N_;
    float c0 = xb[j] - node[((size_t)b * 3 + 0) * M_ + m];
    float c1 = xb[N_ + j] - node[((size_t)b * 3 + 1) * M_ + m];
    float c2 = xb[2 * N_ + j] - node[((size_t)b * 3 + 2) * M_ + m];
    float s0 = sb[j], s1 = sb[N_ + j], s2 = sb[2 * N_ + j];
    u32 u0 = (u32)f2bf(c0) | ((u32)f2bf(c1) << 16);
    u32 u1 = (u32)f2bf(c2) | ((u32)f2bf(s0) << 16);
    u32 u2 = (u32)f2bf(s1) | ((u32)f2bf(s2) << 16);
    u32x4* d = (u32x4*)(F0 + (size_t)p * 32);
    d[0] = (u32x4){u0, u1, u2, 0u};
    d[1] = (u32x4){0u, 0u, 0u, 0u};
    d[2] = (u32x4){0u, 0u, 0u, 0u};
    d[3] = (u32x4){0u, 0u, 0u, 0u};
}

// ---------------------------------------------------------------------------
// bcast max stage1: rows of 64 nbrs x 128ch buf; ch 64..127 = max over nbrs of ch 0..63
// ---------------------------------------------------------------------------
__global__ void bcast_max1_kernel(u16* __restrict__ buf) {
    int nodei = blockIdx.x;            // 0..1023
    int lane = threadIdx.x;            // 64
    u16* base = buf + (size_t)nodei * 64 * 128;
    float mx = -3.0e38f;
    for (int k = 0; k < 64; ++k) mx = fmaxf(mx, bf2f(base[k * 128 + lane]));
    u16 mv = f2bf(mx);
    for (int k = 0; k < 64; ++k) base[k * 128 + 64 + lane] = mv;
}

__global__ void maxpool1_kernel(const u16* __restrict__ buf, u16* __restrict__ h, int h0) {
    int nodei = blockIdx.x;            // 0..1023
    int c = threadIdx.x;               // 128
    const u16* base = buf + (size_t)nodei * 64 * 128;
    float mx = -3.0e38f;
    for (int k = 0; k < 64; ++k) mx = fmaxf(mx, bf2f(base[k * 128 + c]));
    h[(size_t)(h0 * 1024 + nodei) * 640 + c] = f2bf(mx);
}

// ---------------------------------------------------------------------------
// Gather knn neighborhoods -> G0 (18432 rows x 160 ch k-major, pad zeros).
// ---------------------------------------------------------------------------
__global__ void gather_g_kernel(const float* __restrict__ node, const u16* __restrict__ h,
                                const int* __restrict__ knn, u16* __restrict__ G0) {
    int p = blockIdx.x;                // 0..18431
    int lane = threadIdx.x;            // 64
    int nodei = p / 9, kk = p - nodei * 9;
    int b = nodei >> 9, m = nodei & 511;
    int j = knn[(size_t)nodei * 9 + kk];
    u16* dst = G0 + (size_t)p * 160;
    const u16* hrow = h + (size_t)(b * 512 + j) * 640;
    for (int c = lane; c < 160; c += 64) {
        u16 v;
        if (c < 3)
            v = f2bf(node[((size_t)b * 3 + c) * M_ + j] - node[((size_t)b * 3 + c) * M_ + m]);
        else if (c < 131)
            v = hrow[c - 3];
        else
            v = 0;
        dst[c] = v;
    }
}

__global__ void bcast_max2_kernel(u16* __restrict__ buf) {
    int nodei = blockIdx.x;            // 0..2047
    int c = threadIdx.x;               // 256
    u16* base = buf + (size_t)nodei * 9 * 512;
    float mx = -3.0e38f;
    for (int k = 0; k < 9; ++k) mx = fmaxf(mx, bf2f(base[k * 512 + c]));
    u16 mv = f2bf(mx);
    for (int k = 0; k < 9; ++k) base[k * 512 + 256 + c] = mv;
}

__global__ void maxpool2_kernel(const u16* __restrict__ buf, u16* __restrict__ h) {
    int nodei = blockIdx.x;            // 0..2047
    int c = threadIdx.x;               // 256
    for (int cc = c; cc < 512; cc += 256) {
        float mx = -3.0e38f;
        for (int k = 0; k < 9; ++k)
            mx = fmaxf(mx, bf2f(buf[((size_t)nodei * 9 + k) * 512 + cc]));
        h[(size_t)nodei * 640 + 128 + cc] = f2bf(mx);
    }
}

// ---------------------------------------------------------------------------
// Fused mlp3 (4x256) + epilogue.
// ---------------------------------------------------------------------------
__global__ void final_kernel(const float* __restrict__ node, const u16* __restrict__ m2,
                             const float* __restrict__ w3, const float* __restrict__ b3,
                             float* __restrict__ out) {
    int bm = blockIdx.x;               // 0..2047
    int lane = threadIdx.x;            // 64
    int b = bm >> 9, m = bm & 511;
    float a0 = 0.f, a1 = 0.f, a2 = 0.f, a3 = 0.f;
    for (int c = lane; c < 256; c += 64) {
        float v = bf2f(m2[(size_t)bm * 256 + c]);
        a0 += v * w3[c];
        a1 += v * w3[256 + c];
        a2 += v * w3[512 + c];
        a3 += v * w3[768 + c];
    }
    for (int off = 32; off > 0; off >>= 1) {
        a0 += __shfl_down(a0, off);
        a1 += __shfl_down(a1, off);
        a2 += __shfl_down(a2, off);
        a3 += __shfl_down(a3, off);
    }
    if (lane == 0) {
        float k0 = a0 + b3[0], k1 = a1 + b3[1], k2 = a2 + b3[2], s = a3 + b3[3];
        float n0 = node[((size_t)b * 3 + 0) * M_ + m];
        float n1 = node[((size_t)b * 3 + 1) * M_ + m];
        float n2 = node[((size_t)b * 3 + 2) * M_ + m];
        out[((size_t)b * 3 + 0) * M_ + m] = n0;
        out[((size_t)b * 3 + 1) * M_ + m] = n1;
        out[((size_t)b * 3 + 2) * M_ + m] = n2;
        out[6144 + ((size_t)b * 3 + 0) * M_ + m] = n0 + k0;
        out[6144 + ((size_t)b * 3 + 1) * M_ + m] = n1 + k1;
        out[6144 + ((size_t)b * 3 + 2) * M_ + m] = n2 + k2;
        out[12288 + bm] = fmaxf(s, 0.0f) + log1pf(expf(-fabsf(s))) + 0.001f;
    }
}

// ---------------------------------------------------------------------------
extern "C" void kernel_launch(void* const* d_in, const int* in_sizes, int n_in,
                              void* d_out, int out_size, void* d_ws, size_t ws_size,
                              hipStream_t stream) {
    (void)in_sizes; (void)n_in; (void)out_size; (void)ws_size;
    const float* x = (const float*)d_in[0];
    const float* sn = (const float*)d_in[1];
    const float* node = (const float*)d_in[2];
    const float* W[13];
    const float* Bs[13];
    for (int i = 0; i < 13; ++i) {
        W[i] = (const float*)d_in[3 + 2 * i];
        Bs[i] = (const float*)d_in[4 + 2 * i];
    }
    float* out = (float*)d_out;

    static const int WOFF[13] = {0, 2048, 6144, 10240, 26624, 43008, 83968, 149504,
                                 215040, 477184, 739328, 1067008, 1198080};

    char* ws = (char*)d_ws;
    int* idx = (int*)(ws + 0);                 //   524,288
    int* knn = (int*)(ws + 524288);            //    73,728
    u16* Wbf = (u16*)(ws + 598016);            // 2,396,160
    u16* h   = (u16*)(ws + 2994176);           // 2,621,440 (2048 x 640)
    u16* m1  = (u16*)(ws + 5615616);           // 2,097,152
    u16* m2  = (u16*)(ws + 7712768);           // 1,048,576
    char* big = ws + 8761344;
    // stage1 (per half: P=65536)
    u16* F0   = (u16*)(big);                   // 65536 x 32   (4.19 MB)
    u16* BufA = (u16*)(big + 4194304);         // 65536 x 128  (16.8 MB)
    u16* BufB = (u16*)(big + 20971520);        // 65536 x 128  (16.8 MB)
    // stage2 (all batches: P=18432) — reuses big region
    u16* G0 = (u16*)(big);                     // 18432 x 160  (5.9 MB)
    u16* Tt = (u16*)(big + 5898240);           // 18432 x 256  (9.4 MB)
    u16* Ga = (u16*)(big + 15335424);          // 18432 x 512  (18.9 MB)
    u16* Gb = (u16*)(big + 34209792);          // 18432 x 512  (18.9 MB)

    WConvArgs wa;
    for (int w = 0; w < 12; ++w) wa.src[w] = W[w];
    convert_weights_kernel<<<(1198080 + 255) / 256, 256, 0, stream>>>(wa, Wbf);

    ball_query_kernel<<<2048, 256, 0, stream>>>(x, node, idx);
    knn_kernel<<<2048, 64, 0, stream>>>(node, knn);

    // ---- stage 1 (two halves of 2 batches each) ----
    for (int h0 = 0; h0 < 2; ++h0) {
        gather_xb_kernel<<<256, 256, 0, stream>>>(x, sn, node, idx, F0, h0);
        gemm_mfma<1, 4><<<dim3(256, 1), 256, 0, stream>>>(Wbf + WOFF[0], 32, F0, 32, Bs[0], BufB, 64, 32, 1);
        gemm_mfma<1, 4><<<dim3(256, 1), 256, 0, stream>>>(Wbf + WOFF[1], 64, BufB, 64, Bs[1], BufA, 64, 64, 1);
        gemm_mfma<1, 4><<<dim3(256, 1), 256, 0, stream>>>(Wbf + WOFF[2], 64, BufA, 64, Bs[2], BufB, 128, 64, 1);
        bcast_max1_kernel<<<1024, 64, 0, stream>>>(BufB);
        gemm_mfma<2, 2><<<dim3(512, 1), 256, 0, stream>>>(Wbf + WOFF[3], 128, BufB, 128, Bs[3], BufA, 128, 128, 1);
        gemm_mfma<2, 2><<<dim3(512, 1), 256, 0, stream>>>(Wbf + WOFF[4], 128, BufA, 128, Bs[4], BufB, 128, 128, 1);
        maxpool1_kernel<<<1024, 128, 0, stream>>>(BufB, h, h0);
    }

    // ---- stage 2 (all batches) ----
    gather_g_kernel<<<18432, 64, 0, stream>>>(node, h, knn, G0);
    gemm_mfma<2, 2><<<dim3(144, 2), 256, 0, stream>>>(Wbf + WOFF[5], 160, G0, 160, Bs[5], Tt, 256, 160, 1);
    gemm_mfma<2, 2><<<dim3(144, 2), 256, 0, stream>>>(Wbf + WOFF[6], 256, Tt, 256, Bs[6], Ga, 512, 256, 1);
    gemm_mfma<2, 2><<<dim3(144, 2), 256, 0, stream>>>(Wbf + WOFF[7], 256, Ga, 512, Bs[7], Gb, 512, 256, 1);
    bcast_max2_kernel<<<2048, 256, 0, stream>>>(Gb);
    gemm_mfma<2, 2><<<dim3(144, 4), 256, 0, stream>>>(Wbf + WOFF[8], 512, Gb, 512, Bs[8], Ga, 512, 512, 1);
    gemm_mfma<2, 2><<<dim3(144, 4), 256, 0, stream>>>(Wbf + WOFF[9], 512, Ga, 512, Bs[9], Gb, 512, 512, 1);
    maxpool2_kernel<<<2048, 256, 0, stream>>>(Gb, h);

    // ---- stage 3 ----
    gemm_mfma<2, 2><<<dim3(16, 4), 256, 0, stream>>>(Wbf + WOFF[10], 640, h, 640, Bs[10], m1, 512, 640, 1);
    gemm_mfma<2, 2><<<dim3(16, 2), 256, 0, stream>>>(Wbf + WOFF[11], 512, m1, 512, Bs[11], m2, 256, 512, 1);
    final_kernel<<<2048, 64, 0, stream>>>(node, m2, W[12], Bs[12], out);
}

// Round 3
// 293.243 us; speedup vs baseline: 6.5710x; 1.4302x over previous
//
#include <hip/hip_runtime.h>

typedef unsigned short u16;
typedef unsigned int u32;
typedef __bf16 bf16x8 __attribute__((ext_vector_type(8)));
typedef float floatx4 __attribute__((ext_vector_type(4)));
typedef unsigned short u16x4 __attribute__((ext_vector_type(4)));
typedef unsigned int u32x4 __attribute__((ext_vector_type(4)));

static constexpr int B_ = 4;
static constexpr int N_ = 16384;
static constexpr int M_ = 512;

__device__ __forceinline__ u16 f2bf(float f) {
    u32 u = __float_as_uint(f);
    u32 r = (u + 0x7fffu + ((u >> 16) & 1u)) >> 16;
    return (u16)r;
}
__device__ __forceinline__ float bf2f(u16 x) {
    return __uint_as_float(((u32)x) << 16);
}

// 16B async global->LDS stage. ldsbase must be wave-uniform; HW scatters lane*16.
__device__ __forceinline__ void stage16(char* ldsbase, int lane, const void* g) {
#if __has_builtin(__builtin_amdgcn_global_load_lds)
    __builtin_amdgcn_global_load_lds(
        (__attribute__((address_space(1))) void*)(void*)(g),
        (__attribute__((address_space(3))) void*)(void*)(ldsbase), 16, 0, 0);
#else
    *(u32x4*)(ldsbase + lane * 16) = *(const u32x4*)g;
#endif
}

// ---------------------------------------------------------------------------
// Pack x into [x,y,z,|p|^2] float4 per point for the ball query.
// ---------------------------------------------------------------------------
__global__ void pack_x_kernel(const float* __restrict__ x, float4* __restrict__ pk) {
    int t = blockIdx.x * 256 + threadIdx.x;   // 0..65535
    int b = t >> 14, n = t & (N_ - 1);
    const float* xb = x + (size_t)b * 3 * N_;
    float px = xb[n], py = xb[N_ + n], pz = xb[2 * N_ + n];
    pk[t] = make_float4(px, py, pz, px * px + py * py + pz * pz);
}

// ---------------------------------------------------------------------------
// Ball query: 4 waves per (b,m); each wave compacts its N/4 chunk (early exit
// once its 64 slots are full - safe: truncated counts are >=64 and the merge
// prefix only needs exact counts below 64), then LDS merge.
// ---------------------------------------------------------------------------
__global__ __launch_bounds__(256) void ball_query_kernel(
    const float4* __restrict__ pk, const float* __restrict__ node, int* __restrict__ idx) {
    int bm = blockIdx.x;
    int b = bm >> 9, m = bm & 511;
    int tid = threadIdx.x, wave = tid >> 6, lane = tid & 63;
    __shared__ int sidx[4][64];
    __shared__ int scnt[4];

    const float4* pb = pk + ((size_t)b << 14);
    float nx = node[((size_t)b * 3 + 0) * M_ + m];
    float ny = node[((size_t)b * 3 + 1) * M_ + m];
    float nz = node[((size_t)b * 3 + 2) * M_ + m];
    float aa = nx * nx + ny * ny + nz * nz;

    int cnt = 0;
    int base = wave * 4096;
    for (int n0 = base; n0 < base + 4096; n0 += 64) {
        float4 p = pb[n0 + lane];
        float d = aa + p.w - 2.0f * (nx * p.x + ny * p.y + nz * p.z);
        bool inb = d < 4.0f;
        unsigned long long mask = __ballot(inb);
        if (inb && cnt < 64) {
            int pos = cnt + __popcll(mask & ((1ull << lane) - 1ull));
            if (pos < 64) sidx[wave][pos] = n0 + lane;
        }
        cnt += __popcll(mask);
        if (cnt >= 64) break;   // wave-uniform
    }
    if (lane == 0) scnt[wave] = cnt;
    __syncthreads();
    if (tid < 64) {
        int total = scnt[0] + scnt[1] + scnt[2] + scnt[3];
        int v = 0;
        if (total > 0) {
            int lim = total < 64 ? total : 64;
            int slot = tid < lim ? tid : 0;
            int w = 0, pre = 0;
            while (w < 3 && slot >= pre + scnt[w]) { pre += scnt[w]; ++w; }
            v = sidx[w][slot - pre];
        }
        idx[(size_t)bm * 64 + tid] = v;
    }
}

// ---------------------------------------------------------------------------
// KNN over nodes (exact match with reference top_k tie-breaking).
// ---------------------------------------------------------------------------
__global__ void knn_kernel(const float* __restrict__ node, int* __restrict__ knn) {
    int bm = blockIdx.x;
    int b = bm >> 9, m = bm & 511;
    int lane = threadIdx.x;
    const float* nb = node + (size_t)b * 3 * M_;
    float nx = nb[m], ny = nb[M_ + m], nz = nb[2 * M_ + m];
    float aa = nx * nx + ny * ny + nz * nz;

    float dist[8];
    int didx[8];
#pragma unroll
    for (int i = 0; i < 8; ++i) {
        int n = lane + i * 64;
        float px = nb[n], py = nb[M_ + n], pz = nb[2 * M_ + n];
        float bb = px * px + py * py + pz * pz;
        float ab = nx * px + ny * py + nz * pz;
        dist[i] = aa + bb - 2.0f * ab;
        didx[i] = n;
    }
    for (int r = 0; r < 9; ++r) {
        float bv = dist[0]; int bi = didx[0]; int bslot = 0;
#pragma unroll
        for (int i = 1; i < 8; ++i) {
            if (dist[i] < bv || (dist[i] == bv && didx[i] < bi)) {
                bv = dist[i]; bi = didx[i]; bslot = i;
            }
        }
        float rv = bv; int ri = bi;
        for (int off = 32; off > 0; off >>= 1) {
            float ov = __shfl_down(rv, off);
            int   oi = __shfl_down(ri, off);
            if (ov < rv || (ov == rv && oi < ri)) { rv = ov; ri = oi; }
        }
        ri = __shfl(ri, 0);
        if (lane == 0) knn[(size_t)bm * 9 + r] = ri;
        if (bi == ri) dist[bslot] = 3.0e38f;
    }
}

// ---------------------------------------------------------------------------
// Weight fp32 -> bf16 conversion with K padded (zeros).
// ---------------------------------------------------------------------------
struct WConvArgs { const float* src[12]; };

__global__ void convert_weights_kernel(WConvArgs args, u16* __restrict__ dst) {
    const int CI[12] = {6, 64, 64, 128, 128, 131, 256, 256, 512, 512, 640, 512};
    const int KP[12] = {32, 64, 64, 128, 128, 160, 256, 256, 512, 512, 640, 512};
    const int OFF[13] = {0, 2048, 6144, 10240, 26624, 43008, 83968, 149504,
                         215040, 477184, 739328, 1067008, 1198080};
    int e = blockIdx.x * 256 + threadIdx.x;
    if (e >= 1198080) return;
    int w = 0;
    while (e >= OFF[w + 1]) ++w;
    int local = e - OFF[w];
    int kp = KP[w];
    int co = local / kp, k = local - co * kp;
    float v = (k < CI[w]) ? args.src[w][(size_t)co * CI[w] + k] : 0.0f;
    dst[e] = f2bf(v);
}

// ---------------------------------------------------------------------------
// Fused stage 1: one block per node. gather -> conv1(6->64) -> conv2 -> conv3
// -> [concat rowmax] -> conv4(128->128) -> conv5 -> maxpool -> h[:,0:128].
// Activation tile (64 rows x <=128 ch) lives in LDS the whole time (in-place:
// all fragment reads of a conv complete before its epilogue writes).
// Weights are read from global (L2-hot, 84 KB total) as B-fragments directly.
// ---------------------------------------------------------------------------
static constexpr int RS = 136;   // act row stride in u16 (272 B: 16B-aligned rows)

__device__ __forceinline__ bf16x8 ldsA(const u16* act, int rf, int l15, int quad, int ks) {
    return *(const bf16x8*)(act + (rf * 16 + l15) * RS + ks * 32 + quad * 8);
}
__device__ __forceinline__ bf16x8 ldW(const u16* W, int ks, int l15, int quad, int kstride) {
    return *(const bf16x8*)(W + (size_t)l15 * kstride + ks * 32 + quad * 8);
}

__global__ __launch_bounds__(256) void fused_stage1_kernel(
    const float* __restrict__ x, const float* __restrict__ sn,
    const float* __restrict__ node, const int* __restrict__ idx,
    const u16* __restrict__ Wbf,
    const float* __restrict__ b1, const float* __restrict__ b2,
    const float* __restrict__ b3, const float* __restrict__ b4,
    const float* __restrict__ b5, u16* __restrict__ h) {
    __shared__ __align__(16) u16 act[64 * RS];
    __shared__ __align__(16) u16 mv[64];
    int bm = blockIdx.x;
    int b = bm >> 9, m = bm & 511;
    int tid = threadIdx.x, wave = tid >> 6, lane = tid & 63;
    int quad = lane >> 4, l15 = lane & 15;

    // ---- phase 0: gather 64 neighbors, 6 ch + zero pad to 32 ----
    if (tid < 64) {
        int j = idx[(size_t)bm * 64 + tid];
        const float* xb = x + (size_t)b * 3 * N_;
        const float* sb = sn + (size_t)b * 3 * N_;
        float c0 = xb[j]          - node[((size_t)b * 3 + 0) * M_ + m];
        float c1 = xb[N_ + j]     - node[((size_t)b * 3 + 1) * M_ + m];
        float c2 = xb[2 * N_ + j] - node[((size_t)b * 3 + 2) * M_ + m];
        float s0 = sb[j], s1 = sb[N_ + j], s2 = sb[2 * N_ + j];
        u32 p0 = (u32)f2bf(c0) | ((u32)f2bf(c1) << 16);
        u32 p1 = (u32)f2bf(c2) | ((u32)f2bf(s0) << 16);
        u32 p2 = (u32)f2bf(s1) | ((u32)f2bf(s2) << 16);
        u32x4* r = (u32x4*)(act + tid * RS);
        r[0] = (u32x4){p0, p1, p2, 0u};
        r[1] = (u32x4){0u, 0u, 0u, 0u};
        r[2] = (u32x4){0u, 0u, 0u, 0u};
        r[3] = (u32x4){0u, 0u, 0u, 0u};
    }
    __syncthreads();

    // ---- conv1: K=32 (6 used), co 64; wave owns 16 co ----
    {
        const u16* Wp = Wbf + 0 + (size_t)(wave * 16) * 32;
        bf16x8 bw = ldW(Wp, 0, l15, quad, 32);
        bf16x8 a[4];
#pragma unroll
        for (int rf = 0; rf < 4; ++rf) a[rf] = ldsA(act, rf, l15, quad, 0);
        floatx4 c[4];
#pragma unroll
        for (int rf = 0; rf < 4; ++rf)
            c[rf] = __builtin_amdgcn_mfma_f32_16x16x32_bf16(a[rf], bw, (floatx4){0.f,0.f,0.f,0.f}, 0, 0, 0);
        float bias = b1[wave * 16 + l15];
        __syncthreads();
#pragma unroll
        for (int rf = 0; rf < 4; ++rf)
#pragma unroll
            for (int r = 0; r < 4; ++r)
                act[(rf * 16 + quad * 4 + r) * RS + wave * 16 + l15] = f2bf(fmaxf(c[rf][r] + bias, 0.0f));
        __syncthreads();
    }

    // ---- conv2 / conv3: K=64, co 64 ----
    const int WOFF23[2] = {2048, 6144};
    const float* bp23[2] = {b2, b3};
#pragma unroll 1
    for (int cv = 0; cv < 2; ++cv) {
        const u16* Wp = Wbf + WOFF23[cv] + (size_t)(wave * 16) * 64;
        bf16x8 bw[2], a[4][2];
#pragma unroll
        for (int ks = 0; ks < 2; ++ks) bw[ks] = ldW(Wp, ks, l15, quad, 64);
#pragma unroll
        for (int rf = 0; rf < 4; ++rf)
#pragma unroll
            for (int ks = 0; ks < 2; ++ks) a[rf][ks] = ldsA(act, rf, l15, quad, ks);
        floatx4 c[4] = {};
#pragma unroll
        for (int ks = 0; ks < 2; ++ks)
#pragma unroll
            for (int rf = 0; rf < 4; ++rf)
                c[rf] = __builtin_amdgcn_mfma_f32_16x16x32_bf16(a[rf][ks], bw[ks], c[rf], 0, 0, 0);
        float bias = bp23[cv][wave * 16 + l15];
        float v[4][4];
        float mx = 0.0f;
#pragma unroll
        for (int rf = 0; rf < 4; ++rf)
#pragma unroll
            for (int r = 0; r < 4; ++r) {
                v[rf][r] = fmaxf(c[rf][r] + bias, 0.0f);
                mx = fmaxf(mx, v[rf][r]);
            }
        __syncthreads();
#pragma unroll
        for (int rf = 0; rf < 4; ++rf)
#pragma unroll
            for (int r = 0; r < 4; ++r)
                act[(rf * 16 + quad * 4 + r) * RS + wave * 16 + l15] = f2bf(v[rf][r]);
        if (cv == 1) {   // row-max over all 64 rows for this co
            mx = fmaxf(mx, __shfl_xor(mx, 16));
            mx = fmaxf(mx, __shfl_xor(mx, 32));
            if (quad == 0) mv[wave * 16 + l15] = f2bf(mx);
        }
        __syncthreads();
    }

    // ---- conv4: K=128 ([conv3 | rowmax bcast]), co 128; wave owns 32 co ----
    {
        const u16* Wp = Wbf + 10240 + (size_t)(wave * 32) * 128;
        bf16x8 bw[2][4];
#pragma unroll
        for (int cf = 0; cf < 2; ++cf)
#pragma unroll
            for (int ks = 0; ks < 4; ++ks)
                bw[cf][ks] = ldW(Wp + (size_t)cf * 16 * 128, ks, l15, quad, 128);
        bf16x8 a01[4][2];
#pragma unroll
        for (int rf = 0; rf < 4; ++rf)
#pragma unroll
            for (int ks = 0; ks < 2; ++ks) a01[rf][ks] = ldsA(act, rf, l15, quad, ks);
        bf16x8 am2 = *(const bf16x8*)(mv + quad * 8);
        bf16x8 am3 = *(const bf16x8*)(mv + 32 + quad * 8);
        floatx4 c[4][2] = {};
#pragma unroll
        for (int ks = 0; ks < 4; ++ks) {
#pragma unroll
            for (int rf = 0; rf < 4; ++rf) {
                bf16x8 a = (ks < 2) ? a01[rf][ks] : (ks == 2 ? am2 : am3);
#pragma unroll
                for (int cf = 0; cf < 2; ++cf)
                    c[rf][cf] = __builtin_amdgcn_mfma_f32_16x16x32_bf16(a, bw[cf][ks], c[rf][cf], 0, 0, 0);
            }
        }
        float bias[2];
#pragma unroll
        for (int cf = 0; cf < 2; ++cf) bias[cf] = b4[wave * 32 + cf * 16 + l15];
        __syncthreads();
#pragma unroll
        for (int rf = 0; rf < 4; ++rf)
#pragma unroll
            for (int cf = 0; cf < 2; ++cf)
#pragma unroll
                for (int r = 0; r < 4; ++r)
                    act[(rf * 16 + quad * 4 + r) * RS + wave * 32 + cf * 16 + l15] =
                        f2bf(fmaxf(c[rf][cf][r] + bias[cf], 0.0f));
        __syncthreads();
    }

    // ---- conv5: K=128, co 128; then maxpool over 64 rows -> h[bm][0:128] ----
    {
        const u16* Wp = Wbf + 26624 + (size_t)(wave * 32) * 128;
        bf16x8 bw[2][4];
#pragma unroll
        for (int cf = 0; cf < 2; ++cf)
#pragma unroll
            for (int ks = 0; ks < 4; ++ks)
                bw[cf][ks] = ldW(Wp + (size_t)cf * 16 * 128, ks, l15, quad, 128);
        floatx4 c[4][2] = {};
#pragma unroll
        for (int ks = 0; ks < 4; ++ks) {
#pragma unroll
            for (int rf = 0; rf < 4; ++rf) {
                bf16x8 a = ldsA(act, rf, l15, quad, ks);
#pragma unroll
                for (int cf = 0; cf < 2; ++cf)
                    c[rf][cf] = __builtin_amdgcn_mfma_f32_16x16x32_bf16(a, bw[cf][ks], c[rf][cf], 0, 0, 0);
            }
        }
#pragma unroll
        for (int cf = 0; cf < 2; ++cf) {
            float bias = b5[wave * 32 + cf * 16 + l15];
            float mx = 0.0f;
#pragma unroll
            for (int rf = 0; rf < 4; ++rf)
#pragma unroll
                for (int r = 0; r < 4; ++r)
                    mx = fmaxf(mx, fmaxf(c[rf][cf][r] + bias, 0.0f));
            mx = fmaxf(mx, __shfl_xor(mx, 16));
            mx = fmaxf(mx, __shfl_xor(mx, 32));
            if (quad == 0) h[(size_t)bm * 640 + wave * 32 + cf * 16 + l15] = f2bf(mx);
        }
    }
}

// ---------------------------------------------------------------------------
// bf16 MFMA GEMM (stage 2/3): out[p][co] = relu(W @ act + bias), (P,C) k-major.
// ---------------------------------------------------------------------------
template <int WR, int WC>
__global__ __launch_bounds__(256) void gemm_mfma(
    const u16* __restrict__ Wq, int wstride,
    const u16* __restrict__ act, int astride,
    const float* __restrict__ bias,
    u16* __restrict__ outp, int ostride,
    int K, int relu) {
    constexpr int BM = WR * 64, BN = WC * 64;
    constexpr int ABYTES = BM * 64;
    __shared__ __align__(16) char smem[36864];
    char* ldsA_ = smem;
    char* ldsB_ = smem + ABYTES;
    int tid = threadIdx.x;
    int wave = tid >> 6, lane = tid & 63;
    int quad = lane >> 4, l15 = lane & 15;
    int wr = (WR == 2) ? (wave >> 1) : 0;
    int wc = (WR == 2) ? (wave & 1) : wave;
    int co0 = blockIdx.y * BM, p0 = blockIdx.x * BN;

    floatx4 acc[4][4];
#pragma unroll
    for (int t = 0; t < 4; ++t)
#pragma unroll
        for (int u = 0; u < 4; ++u) acc[t][u] = (floatx4){0.f, 0.f, 0.f, 0.f};

    int arow = lane >> 2;
    int acol = (lane & 3) * 8;

    for (int k0 = 0; k0 < K; k0 += 32) {
        __syncthreads();
#pragma unroll
        for (int i = 0; i < WR; ++i) {
            int chunk = wave * WR + i;
            int row = chunk * 16 + arow;
            stage16(ldsA_ + chunk * 1024, lane,
                    Wq + (size_t)(co0 + row) * wstride + k0 + acol);
        }
#pragma unroll
        for (int i = 0; i < WC; ++i) {
            int chunk = wave * WC + i;
            int row = chunk * 16 + arow;
            stage16(ldsB_ + chunk * 1024, lane,
                    act + (size_t)(p0 + row) * astride + k0 + acol);
        }
        __syncthreads();
        bf16x8 a[4], b[4];
#pragma unroll
        for (int t = 0; t < 4; ++t)
            a[t] = *(const bf16x8*)(ldsA_ + ((wr * 64 + t * 16 + l15) * 32 + quad * 8) * 2);
#pragma unroll
        for (int u = 0; u < 4; ++u)
            b[u] = *(const bf16x8*)(ldsB_ + ((wc * 64 + u * 16 + l15) * 32 + quad * 8) * 2);
#pragma unroll
        for (int t = 0; t < 4; ++t)
#pragma unroll
            for (int u = 0; u < 4; ++u)
                acc[t][u] = __builtin_amdgcn_mfma_f32_16x16x32_bf16(a[t], b[u], acc[t][u], 0, 0, 0);
    }
    __syncthreads();

    char* ep = smem + wave * 9216;
#pragma unroll
    for (int t = 0; t < 4; ++t)
#pragma unroll
        for (int u = 0; u < 4; ++u) {
            u16x4 pkv;
#pragma unroll
            for (int r = 0; r < 4; ++r) {
                int cl = t * 16 + quad * 4 + r;
                float v = acc[t][u][r] + bias[co0 + wr * 64 + cl];
                if (relu) v = fmaxf(v, 0.0f);
                pkv[r] = f2bf(v);
            }
            *(u16x4*)(ep + (u * 16 + l15) * 144 + (t * 16 + quad * 4) * 2) = pkv;
        }
#pragma unroll
    for (int i = 0; i < 8; ++i) {
        int row = i * 8 + (lane >> 3);
        int col = (lane & 7) * 8;
        u32x4 v = *(const u32x4*)(ep + row * 144 + col * 2);
        *(u32x4*)(outp + (size_t)(p0 + wc * 64 + row) * ostride + co0 + wr * 64 + col) = v;
    }
}

// ---------------------------------------------------------------------------
// Gather knn neighborhoods -> G0 (18432 rows x 160 ch k-major, zero pad).
// ---------------------------------------------------------------------------
__global__ void gather_g_kernel(const float* __restrict__ node, const u16* __restrict__ h,
                                const int* __restrict__ knn, u16* __restrict__ G0) {
    int p = blockIdx.x;
    int lane = threadIdx.x;
    int nodei = p / 9, kk = p - nodei * 9;
    int b = nodei >> 9, m = nodei & 511;
    int j = knn[(size_t)nodei * 9 + kk];
    u16* dst = G0 + (size_t)p * 160;
    const u16* hrow = h + (size_t)(b * 512 + j) * 640;
    for (int c = lane; c < 160; c += 64) {
        u16 v;
        if (c < 3)
            v = f2bf(node[((size_t)b * 3 + c) * M_ + j] - node[((size_t)b * 3 + c) * M_ + m]);
        else if (c < 131)
            v = hrow[c - 3];
        else
            v = 0;
        dst[c] = v;
    }
}

__global__ void bcast_max2_kernel(u16* __restrict__ buf) {
    int nodei = blockIdx.x;
    int c = threadIdx.x;
    u16* base = buf + (size_t)nodei * 9 * 512;
    float mx = -3.0e38f;
    for (int k = 0; k < 9; ++k) mx = fmaxf(mx, bf2f(base[k * 512 + c]));
    u16 mvv = f2bf(mx);
    for (int k = 0; k < 9; ++k) base[k * 512 + 256 + c] = mvv;
}

__global__ void maxpool2_kernel(const u16* __restrict__ buf, u16* __restrict__ h) {
    int nodei = blockIdx.x;
    int c = threadIdx.x;
    for (int cc = c; cc < 512; cc += 256) {
        float mx = -3.0e38f;
        for (int k = 0; k < 9; ++k)
            mx = fmaxf(mx, bf2f(buf[((size_t)nodei * 9 + k) * 512 + cc]));
        h[(size_t)nodei * 640 + 128 + cc] = f2bf(mx);
    }
}

// ---------------------------------------------------------------------------
// Fused mlp3 (4x256) + epilogue.
// ---------------------------------------------------------------------------
__global__ void final_kernel(const float* __restrict__ node, const u16* __restrict__ m2,
                             const float* __restrict__ w3, const float* __restrict__ b3,
                             float* __restrict__ out) {
    int bm = blockIdx.x;
    int lane = threadIdx.x;
    int b = bm >> 9, m = bm & 511;
    float a0 = 0.f, a1 = 0.f, a2 = 0.f, a3 = 0.f;
    for (int c = lane; c < 256; c += 64) {
        float v = bf2f(m2[(size_t)bm * 256 + c]);
        a0 += v * w3[c];
        a1 += v * w3[256 + c];
        a2 += v * w3[512 + c];
        a3 += v * w3[768 + c];
    }
    for (int off = 32; off > 0; off >>= 1) {
        a0 += __shfl_down(a0, off);
        a1 += __shfl_down(a1, off);
        a2 += __shfl_down(a2, off);
        a3 += __shfl_down(a3, off);
    }
    if (lane == 0) {
        float k0 = a0 + b3[0], k1 = a1 + b3[1], k2 = a2 + b3[2], s = a3 + b3[3];
        float n0 = node[((size_t)b * 3 + 0) * M_ + m];
        float n1 = node[((size_t)b * 3 + 1) * M_ + m];
        float n2 = node[((size_t)b * 3 + 2) * M_ + m];
        out[((size_t)b * 3 + 0) * M_ + m] = n0;
        out[((size_t)b * 3 + 1) * M_ + m] = n1;
        out[((size_t)b * 3 + 2) * M_ + m] = n2;
        out[6144 + ((size_t)b * 3 + 0) * M_ + m] = n0 + k0;
        out[6144 + ((size_t)b * 3 + 1) * M_ + m] = n1 + k1;
        out[6144 + ((size_t)b * 3 + 2) * M_ + m] = n2 + k2;
        out[12288 + bm] = fmaxf(s, 0.0f) + log1pf(expf(-fabsf(s))) + 0.001f;
    }
}

// ---------------------------------------------------------------------------
extern "C" void kernel_launch(void* const* d_in, const int* in_sizes, int n_in,
                              void* d_out, int out_size, void* d_ws, size_t ws_size,
                              hipStream_t stream) {
    (void)in_sizes; (void)n_in; (void)out_size; (void)ws_size;
    const float* x = (const float*)d_in[0];
    const float* sn = (const float*)d_in[1];
    const float* node = (const float*)d_in[2];
    const float* W[13];
    const float* Bs[13];
    for (int i = 0; i < 13; ++i) {
        W[i] = (const float*)d_in[3 + 2 * i];
        Bs[i] = (const float*)d_in[4 + 2 * i];
    }
    float* out = (float*)d_out;

    static const int WOFF[13] = {0, 2048, 6144, 10240, 26624, 43008, 83968, 149504,
                                 215040, 477184, 739328, 1067008, 1198080};

    char* ws = (char*)d_ws;
    int* idx = (int*)(ws + 0);                 //   524,288
    int* knn = (int*)(ws + 524288);            //    73,728
    u16* Wbf = (u16*)(ws + 598016);            // 2,396,160
    u16* h   = (u16*)(ws + 2994176);           // 2,621,440 (2048 x 640)
    u16* m1  = (u16*)(ws + 5615616);           // 2,097,152
    u16* m2  = (u16*)(ws + 7712768);           // 1,048,576
    float4* pk = (float4*)(ws + 8761344);      // 1,048,576
    char* big = ws + 9809920;
    u16* G0 = (u16*)(big);                     // 18432 x 160  (5.9 MB)
    u16* Tt = (u16*)(big + 5898240);           // 18432 x 256  (9.4 MB)
    u16* Ga = (u16*)(big + 15335424);          // 18432 x 512  (18.9 MB)
    u16* Gb = (u16*)(big + 34209792);          // 18432 x 512  (18.9 MB)

    WConvArgs wa;
    for (int w = 0; w < 12; ++w) wa.src[w] = W[w];
    convert_weights_kernel<<<(1198080 + 255) / 256, 256, 0, stream>>>(wa, Wbf);

    pack_x_kernel<<<256, 256, 0, stream>>>(x, pk);
    ball_query_kernel<<<2048, 256, 0, stream>>>(pk, node, idx);
    knn_kernel<<<2048, 64, 0, stream>>>(node, knn);

    // ---- stage 1: fully fused per-node pointconv stack -> h[:,0:128] ----
    fused_stage1_kernel<<<2048, 256, 0, stream>>>(x, sn, node, idx, Wbf,
                                                  Bs[0], Bs[1], Bs[2], Bs[3], Bs[4], h);

    // ---- stage 2: knn fusion stack -> h[:,128:640] ----
    gather_g_kernel<<<18432, 64, 0, stream>>>(node, h, knn, G0);
    gemm_mfma<2, 2><<<dim3(144, 2), 256, 0, stream>>>(Wbf + WOFF[5], 160, G0, 160, Bs[5], Tt, 256, 160, 1);
    gemm_mfma<2, 2><<<dim3(144, 2), 256, 0, stream>>>(Wbf + WOFF[6], 256, Tt, 256, Bs[6], Ga, 512, 256, 1);
    gemm_mfma<2, 2><<<dim3(144, 2), 256, 0, stream>>>(Wbf + WOFF[7], 256, Ga, 512, Bs[7], Gb, 512, 256, 1);
    bcast_max2_kernel<<<2048, 256, 0, stream>>>(Gb);
    gemm_mfma<2, 2><<<dim3(144, 4), 256, 0, stream>>>(Wbf + WOFF[8], 512, Gb, 512, Bs[8], Ga, 512, 512, 1);
    gemm_mfma<2, 2><<<dim3(144, 4), 256, 0, stream>>>(Wbf + WOFF[9], 512, Ga, 512, Bs[9], Gb, 512, 512, 1);
    maxpool2_kernel<<<2048, 256, 0, stream>>>(Gb, h);

    // ---- stage 3 ----
    gemm_mfma<2, 2><<<dim3(16, 4), 256, 0, stream>>>(Wbf + WOFF[10], 640, h, 640, Bs[10], m1, 512, 640, 1);
    gemm_mfma<2, 2><<<dim3(16, 2), 256, 0, stream>>>(Wbf + WOFF[11], 512, m1, 512, Bs[11], m2, 256, 512, 1);
    final_kernel<<<2048, 64, 0, stream>>>(node, m2, W[12], Bs[12], out);
}

// Round 4
// 288.025 us; speedup vs baseline: 6.6901x; 1.0181x over previous
//
#include <hip/hip_runtime.h>

typedef unsigned short u16;
typedef unsigned int u32;
typedef __bf16 bf16x8 __attribute__((ext_vector_type(8)));
typedef float floatx4 __attribute__((ext_vector_type(4)));
typedef unsigned short u16x8 __attribute__((ext_vector_type(8)));
typedef unsigned int u32x4 __attribute__((ext_vector_type(4)));

static constexpr int B_ = 4;
static constexpr int N_ = 16384;
static constexpr int M_ = 512;

__device__ __forceinline__ u16 f2bf(float f) {
    u32 u = __float_as_uint(f);
    u32 r = (u + 0x7fffu + ((u >> 16) & 1u)) >> 16;
    return (u16)r;
}
__device__ __forceinline__ float bf2f(u16 x) {
    return __uint_as_float(((u32)x) << 16);
}

// ---------------------------------------------------------------------------
// Pack x into [x,y,z,|p|^2] float4 per point for the ball query.
// ---------------------------------------------------------------------------
__global__ void pack_x_kernel(const float* __restrict__ x, float4* __restrict__ pk) {
    int t = blockIdx.x * 256 + threadIdx.x;   // 0..65535
    int b = t >> 14, n = t & (N_ - 1);
    const float* xb = x + (size_t)b * 3 * N_;
    float px = xb[n], py = xb[N_ + n], pz = xb[2 * N_ + n];
    pk[t] = make_float4(px, py, pz, px * px + py * py + pz * pz);
}

// ---------------------------------------------------------------------------
// Ball query: 4 waves per (b,m); early exit when a wave's 64 slots are full
// (safe: truncated counts are >=64; merge only needs exact counts < 64).
// ---------------------------------------------------------------------------
__global__ __launch_bounds__(256) void ball_query_kernel(
    const float4* __restrict__ pk, const float* __restrict__ node, int* __restrict__ idx) {
    int bm = blockIdx.x;
    int b = bm >> 9, m = bm & 511;
    int tid = threadIdx.x, wave = tid >> 6, lane = tid & 63;
    __shared__ int sidx[4][64];
    __shared__ int scnt[4];

    const float4* pb = pk + ((size_t)b << 14);
    float nx = node[((size_t)b * 3 + 0) * M_ + m];
    float ny = node[((size_t)b * 3 + 1) * M_ + m];
    float nz = node[((size_t)b * 3 + 2) * M_ + m];
    float aa = nx * nx + ny * ny + nz * nz;

    int cnt = 0;
    int base = wave * 4096;
    for (int n0 = base; n0 < base + 4096; n0 += 64) {
        float4 p = pb[n0 + lane];
        float d = aa + p.w - 2.0f * (nx * p.x + ny * p.y + nz * p.z);
        bool inb = d < 4.0f;
        unsigned long long mask = __ballot(inb);
        if (inb && cnt < 64) {
            int pos = cnt + __popcll(mask & ((1ull << lane) - 1ull));
            if (pos < 64) sidx[wave][pos] = n0 + lane;
        }
        cnt += __popcll(mask);
        if (cnt >= 64) break;   // wave-uniform
    }
    if (lane == 0) scnt[wave] = cnt;
    __syncthreads();
    if (tid < 64) {
        int total = scnt[0] + scnt[1] + scnt[2] + scnt[3];
        int v = 0;
        if (total > 0) {
            int lim = total < 64 ? total : 64;
            int slot = tid < lim ? tid : 0;
            int w = 0, pre = 0;
            while (w < 3 && slot >= pre + scnt[w]) { pre += scnt[w]; ++w; }
            v = sidx[w][slot - pre];
        }
        idx[(size_t)bm * 64 + tid] = v;
    }
}

// ---------------------------------------------------------------------------
// KNN over nodes (exact match with reference top_k tie-breaking).
// ---------------------------------------------------------------------------
__global__ void knn_kernel(const float* __restrict__ node, int* __restrict__ knn) {
    int bm = blockIdx.x;
    int b = bm >> 9, m = bm & 511;
    int lane = threadIdx.x;
    const float* nb = node + (size_t)b * 3 * M_;
    float nx = nb[m], ny = nb[M_ + m], nz = nb[2 * M_ + m];
    float aa = nx * nx + ny * ny + nz * nz;

    float dist[8];
    int didx[8];
#pragma unroll
    for (int i = 0; i < 8; ++i) {
        int n = lane + i * 64;
        float px = nb[n], py = nb[M_ + n], pz = nb[2 * M_ + n];
        float bb = px * px + py * py + pz * pz;
        float ab = nx * px + ny * py + nz * pz;
        dist[i] = aa + bb - 2.0f * ab;
        didx[i] = n;
    }
    for (int r = 0; r < 9; ++r) {
        float bv = dist[0]; int bi = didx[0]; int bslot = 0;
#pragma unroll
        for (int i = 1; i < 8; ++i) {
            if (dist[i] < bv || (dist[i] == bv && didx[i] < bi)) {
                bv = dist[i]; bi = didx[i]; bslot = i;
            }
        }
        float rv = bv; int ri = bi;
        for (int off = 32; off > 0; off >>= 1) {
            float ov = __shfl_down(rv, off);
            int   oi = __shfl_down(ri, off);
            if (ov < rv || (ov == rv && oi < ri)) { rv = ov; ri = oi; }
        }
        ri = __shfl(ri, 0);
        if (lane == 0) knn[(size_t)bm * 9 + r] = ri;
        if (bi == ri) dist[bslot] = 3.0e38f;
    }
}

// ---------------------------------------------------------------------------
// Weight fp32 -> bf16 conversion with K padded (zeros).
// ---------------------------------------------------------------------------
struct WConvArgs { const float* src[12]; };

__global__ void convert_weights_kernel(WConvArgs args, u16* __restrict__ dst) {
    const int CI[12] = {6, 64, 64, 128, 128, 131, 256, 256, 512, 512, 640, 512};
    const int KP[12] = {32, 64, 64, 128, 128, 160, 256, 256, 512, 512, 640, 512};
    const int OFF[13] = {0, 2048, 6144, 10240, 26624, 43008, 83968, 149504,
                         215040, 477184, 739328, 1067008, 1198080};
    int e = blockIdx.x * 256 + threadIdx.x;
    if (e >= 1198080) return;
    int w = 0;
    while (e >= OFF[w + 1]) ++w;
    int local = e - OFF[w];
    int kp = KP[w];
    int co = local / kp, k = local - co * kp;
    float v = (k < CI[w]) ? args.src[w][(size_t)co * CI[w] + k] : 0.0f;
    dst[e] = f2bf(v);
}

// ---------------------------------------------------------------------------
// Fused stage 1 (unchanged from round 3): one block per node.
// ---------------------------------------------------------------------------
static constexpr int RS = 136;

__device__ __forceinline__ bf16x8 ldsA(const u16* act, int rf, int l15, int quad, int ks) {
    return *(const bf16x8*)(act + (rf * 16 + l15) * RS + ks * 32 + quad * 8);
}
__device__ __forceinline__ bf16x8 ldW(const u16* W, int ks, int l15, int quad, int kstride) {
    return *(const bf16x8*)(W + (size_t)l15 * kstride + ks * 32 + quad * 8);
}

__global__ __launch_bounds__(256) void fused_stage1_kernel(
    const float* __restrict__ x, const float* __restrict__ sn,
    const float* __restrict__ node, const int* __restrict__ idx,
    const u16* __restrict__ Wbf,
    const float* __restrict__ b1, const float* __restrict__ b2,
    const float* __restrict__ b3, const float* __restrict__ b4,
    const float* __restrict__ b5, u16* __restrict__ h) {
    __shared__ __align__(16) u16 act[64 * RS];
    __shared__ __align__(16) u16 mv[64];
    int bm = blockIdx.x;
    int b = bm >> 9, m = bm & 511;
    int tid = threadIdx.x, wave = tid >> 6, lane = tid & 63;
    int quad = lane >> 4, l15 = lane & 15;

    if (tid < 64) {
        int j = idx[(size_t)bm * 64 + tid];
        const float* xb = x + (size_t)b * 3 * N_;
        const float* sb = sn + (size_t)b * 3 * N_;
        float c0 = xb[j]          - node[((size_t)b * 3 + 0) * M_ + m];
        float c1 = xb[N_ + j]     - node[((size_t)b * 3 + 1) * M_ + m];
        float c2 = xb[2 * N_ + j] - node[((size_t)b * 3 + 2) * M_ + m];
        float s0 = sb[j], s1 = sb[N_ + j], s2 = sb[2 * N_ + j];
        u32 p0 = (u32)f2bf(c0) | ((u32)f2bf(c1) << 16);
        u32 p1 = (u32)f2bf(c2) | ((u32)f2bf(s0) << 16);
        u32 p2 = (u32)f2bf(s1) | ((u32)f2bf(s2) << 16);
        u32x4* r = (u32x4*)(act + tid * RS);
        r[0] = (u32x4){p0, p1, p2, 0u};
        r[1] = (u32x4){0u, 0u, 0u, 0u};
        r[2] = (u32x4){0u, 0u, 0u, 0u};
        r[3] = (u32x4){0u, 0u, 0u, 0u};
    }
    __syncthreads();

    {   // conv1: K=32 (6 used), co 64
        const u16* Wp = Wbf + 0 + (size_t)(wave * 16) * 32;
        bf16x8 bw = ldW(Wp, 0, l15, quad, 32);
        bf16x8 a[4];
#pragma unroll
        for (int rf = 0; rf < 4; ++rf) a[rf] = ldsA(act, rf, l15, quad, 0);
        floatx4 c[4];
#pragma unroll
        for (int rf = 0; rf < 4; ++rf)
            c[rf] = __builtin_amdgcn_mfma_f32_16x16x32_bf16(a[rf], bw, (floatx4){0.f,0.f,0.f,0.f}, 0, 0, 0);
        float bias = b1[wave * 16 + l15];
        __syncthreads();
#pragma unroll
        for (int rf = 0; rf < 4; ++rf)
#pragma unroll
            for (int r = 0; r < 4; ++r)
                act[(rf * 16 + quad * 4 + r) * RS + wave * 16 + l15] = f2bf(fmaxf(c[rf][r] + bias, 0.0f));
        __syncthreads();
    }

    const int WOFF23[2] = {2048, 6144};
    const float* bp23[2] = {b2, b3};
#pragma unroll 1
    for (int cv = 0; cv < 2; ++cv) {   // conv2 / conv3: K=64, co 64
        const u16* Wp = Wbf + WOFF23[cv] + (size_t)(wave * 16) * 64;
        bf16x8 bw[2], a[4][2];
#pragma unroll
        for (int ks = 0; ks < 2; ++ks) bw[ks] = ldW(Wp, ks, l15, quad, 64);
#pragma unroll
        for (int rf = 0; rf < 4; ++rf)
#pragma unroll
            for (int ks = 0; ks < 2; ++ks) a[rf][ks] = ldsA(act, rf, l15, quad, ks);
        floatx4 c[4] = {};
#pragma unroll
        for (int ks = 0; ks < 2; ++ks)
#pragma unroll
            for (int rf = 0; rf < 4; ++rf)
                c[rf] = __builtin_amdgcn_mfma_f32_16x16x32_bf16(a[rf][ks], bw[ks], c[rf], 0, 0, 0);
        float bias = bp23[cv][wave * 16 + l15];
        float v[4][4];
        float mx = 0.0f;
#pragma unroll
        for (int rf = 0; rf < 4; ++rf)
#pragma unroll
            for (int r = 0; r < 4; ++r) {
                v[rf][r] = fmaxf(c[rf][r] + bias, 0.0f);
                mx = fmaxf(mx, v[rf][r]);
            }
        __syncthreads();
#pragma unroll
        for (int rf = 0; rf < 4; ++rf)
#pragma unroll
            for (int r = 0; r < 4; ++r)
                act[(rf * 16 + quad * 4 + r) * RS + wave * 16 + l15] = f2bf(v[rf][r]);
        if (cv == 1) {
            mx = fmaxf(mx, __shfl_xor(mx, 16));
            mx = fmaxf(mx, __shfl_xor(mx, 32));
            if (quad == 0) mv[wave * 16 + l15] = f2bf(mx);
        }
        __syncthreads();
    }

    {   // conv4: K=128 ([conv3 | rowmax]), co 128
        const u16* Wp = Wbf + 10240 + (size_t)(wave * 32) * 128;
        bf16x8 bw[2][4];
#pragma unroll
        for (int cf = 0; cf < 2; ++cf)
#pragma unroll
            for (int ks = 0; ks < 4; ++ks)
                bw[cf][ks] = ldW(Wp + (size_t)cf * 16 * 128, ks, l15, quad, 128);
        bf16x8 a01[4][2];
#pragma unroll
        for (int rf = 0; rf < 4; ++rf)
#pragma unroll
            for (int ks = 0; ks < 2; ++ks) a01[rf][ks] = ldsA(act, rf, l15, quad, ks);
        bf16x8 am2 = *(const bf16x8*)(mv + quad * 8);
        bf16x8 am3 = *(const bf16x8*)(mv + 32 + quad * 8);
        floatx4 c[4][2] = {};
#pragma unroll
        for (int ks = 0; ks < 4; ++ks) {
#pragma unroll
            for (int rf = 0; rf < 4; ++rf) {
                bf16x8 a = (ks < 2) ? a01[rf][ks] : (ks == 2 ? am2 : am3);
#pragma unroll
                for (int cf = 0; cf < 2; ++cf)
                    c[rf][cf] = __builtin_amdgcn_mfma_f32_16x16x32_bf16(a, bw[cf][ks], c[rf][cf], 0, 0, 0);
            }
        }
        float bias[2];
#pragma unroll
        for (int cf = 0; cf < 2; ++cf) bias[cf] = b4[wave * 32 + cf * 16 + l15];
        __syncthreads();
#pragma unroll
        for (int rf = 0; rf < 4; ++rf)
#pragma unroll
            for (int cf = 0; cf < 2; ++cf)
#pragma unroll
                for (int r = 0; r < 4; ++r)
                    act[(rf * 16 + quad * 4 + r) * RS + wave * 32 + cf * 16 + l15] =
                        f2bf(fmaxf(c[rf][cf][r] + bias[cf], 0.0f));
        __syncthreads();
    }

    {   // conv5 + maxpool
        const u16* Wp = Wbf + 26624 + (size_t)(wave * 32) * 128;
        bf16x8 bw[2][4];
#pragma unroll
        for (int cf = 0; cf < 2; ++cf)
#pragma unroll
            for (int ks = 0; ks < 4; ++ks)
                bw[cf][ks] = ldW(Wp + (size_t)cf * 16 * 128, ks, l15, quad, 128);
        floatx4 c[4][2] = {};
#pragma unroll
        for (int ks = 0; ks < 4; ++ks) {
#pragma unroll
            for (int rf = 0; rf < 4; ++rf) {
                bf16x8 a = ldsA(act, rf, l15, quad, ks);
#pragma unroll
                for (int cf = 0; cf < 2; ++cf)
                    c[rf][cf] = __builtin_amdgcn_mfma_f32_16x16x32_bf16(a, bw[cf][ks], c[rf][cf], 0, 0, 0);
            }
        }
#pragma unroll
        for (int cf = 0; cf < 2; ++cf) {
            float bias = b5[wave * 32 + cf * 16 + l15];
            float mx = 0.0f;
#pragma unroll
            for (int rf = 0; rf < 4; ++rf)
#pragma unroll
                for (int r = 0; r < 4; ++r)
                    mx = fmaxf(mx, fmaxf(c[rf][cf][r] + bias, 0.0f));
            mx = fmaxf(mx, __shfl_xor(mx, 16));
            mx = fmaxf(mx, __shfl_xor(mx, 32));
            if (quad == 0) h[(size_t)bm * 640 + wave * 32 + cf * 16 + l15] = f2bf(mx);
        }
    }
}

// ---------------------------------------------------------------------------
// Generic in-LDS in-place conv step for fused stage2/3.
// act tile: (RF*16) rows x RSx u16 cols. Wave owns out cols [cb, cb+CF*16).
// B-frags stream from global (L2-hot) with register ping-pong prefetch.
// ---------------------------------------------------------------------------
template <int KS, int CF, int RF, int RSx>
__device__ __forceinline__ void conv_inplace(u16* act, const u16* __restrict__ W0, int KP,
                                             const float* __restrict__ bias, int cb,
                                             int l15, int quad) {
    floatx4 acc[RF][CF];
#pragma unroll
    for (int rf = 0; rf < RF; ++rf)
#pragma unroll
        for (int cf = 0; cf < CF; ++cf) acc[rf][cf] = (floatx4){0.f, 0.f, 0.f, 0.f};

    bf16x8 bwA[CF], bwB[CF];
#pragma unroll
    for (int cf = 0; cf < CF; ++cf)
        bwA[cf] = *(const bf16x8*)(W0 + (size_t)(cb + cf * 16 + l15) * KP + quad * 8);

#pragma unroll
    for (int ks = 0; ks < KS; ++ks) {
        bf16x8* cur = (ks % 2 == 0) ? bwA : bwB;
        bf16x8* nxt = (ks % 2 == 0) ? bwB : bwA;
        if (ks + 1 < KS) {
#pragma unroll
            for (int cf = 0; cf < CF; ++cf)
                nxt[cf] = *(const bf16x8*)(W0 + (size_t)(cb + cf * 16 + l15) * KP +
                                           (ks + 1) * 32 + quad * 8);
        }
#pragma unroll
        for (int rf = 0; rf < RF; ++rf) {
            bf16x8 a = *(const bf16x8*)(act + (rf * 16 + l15) * RSx + ks * 32 + quad * 8);
#pragma unroll
            for (int cf = 0; cf < CF; ++cf)
                acc[rf][cf] = __builtin_amdgcn_mfma_f32_16x16x32_bf16(a, cur[cf], acc[rf][cf], 0, 0, 0);
        }
    }
    __syncthreads();   // all waves' reads complete before in-place writes
#pragma unroll
    for (int cf = 0; cf < CF; ++cf) {
        float bs = bias[cb + cf * 16 + l15];
#pragma unroll
        for (int rf = 0; rf < RF; ++rf)
#pragma unroll
            for (int r = 0; r < 4; ++r)
                act[(rf * 16 + quad * 4 + r) * RSx + cb + cf * 16 + l15] =
                    f2bf(fmaxf(acc[rf][cf][r] + bs, 0.0f));
    }
    __syncthreads();
}

// ---------------------------------------------------------------------------
// Fused stage 2: one block per 8 nodes (72 rows, padded to 80).
// gather(160) -> knnb1(256) -> knnb2 -> knnb3 -> [gmax concat ->512]
// -> knna1(512) -> knna2(512) -> pool(9) -> h[:,128:640]
// ---------------------------------------------------------------------------
static constexpr int RS2 = 520;   // 1040 B row stride: bank offset 4/row -> 2-way free

__global__ __launch_bounds__(256, 1) void fused_stage2_kernel(
    const float* __restrict__ node, u16* __restrict__ h, const int* __restrict__ knn,
    const u16* __restrict__ Wbf,
    const float* __restrict__ bb1, const float* __restrict__ bb2,
    const float* __restrict__ bb3, const float* __restrict__ ba1,
    const float* __restrict__ ba2) {
    __shared__ __align__(16) u16 act[80 * RS2];   // 83,200 B
    int blk = blockIdx.x;              // 0..255
    int node0 = blk * 8;
    int b = node0 >> 9;
    int tid = threadIdx.x, wave = tid >> 6, lane = tid & 63;
    int quad = lane >> 4, l15 = lane & 15;

    // phase 0a: zero cols 0..159 of all 80 rows
    for (int e = tid; e < 80 * 20; e += 256)
        *(u16x8*)(act + (e / 20) * RS2 + (e % 20) * 8) = (u16x8){0,0,0,0,0,0,0,0};
    __syncthreads();
    // phase 0b: gather rows 0..71 (row = li*9+kk): coords + feat1
    for (int e = tid; e < 72 * 3; e += 256) {
        int r = e / 3, c = e - r * 3;
        int nodei = node0 + r / 9;
        int j = knn[(size_t)nodei * 9 + (r % 9)];
        float v = node[((size_t)b * 3 + c) * M_ + j] - node[((size_t)b * 3 + c) * M_ + (nodei & 511)];
        act[r * RS2 + c] = f2bf(v);
    }
    for (int e = tid; e < 72 * 128; e += 256) {
        int r = e >> 7, c = e & 127;
        int nodei = node0 + r / 9;
        int j = knn[(size_t)nodei * 9 + (r % 9)];
        act[r * RS2 + 3 + c] = h[(size_t)(b * 512 + j) * 640 + c];
    }
    __syncthreads();

    // knnb1: K=160 -> Co=256 (wave owns 64)
    conv_inplace<5, 4, 5, RS2>(act, Wbf + 43008, 160, bb1, wave * 64, l15, quad);
    // knnb2: 256 -> 256
    conv_inplace<8, 4, 5, RS2>(act, Wbf + 83968, 256, bb2, wave * 64, l15, quad);
    // knnb3: 256 -> 256
    conv_inplace<8, 4, 5, RS2>(act, Wbf + 149504, 256, bb3, wave * 64, l15, quad);

    // gmax: per node (9 rows) max of cols 0..255 -> bcast into cols 256..511
    for (int e = tid; e < 8 * 256; e += 256) {
        int li = e >> 8, c = e & 255;
        int r0 = li * 9;
        float mx = -3.0e38f;
#pragma unroll
        for (int kk = 0; kk < 9; ++kk) mx = fmaxf(mx, bf2f(act[(r0 + kk) * RS2 + c]));
        u16 mvv = f2bf(mx);
#pragma unroll
        for (int kk = 0; kk < 9; ++kk) act[(r0 + kk) * RS2 + 256 + c] = mvv;
    }
    __syncthreads();

    // knna1: K=512 -> Co=512 (wave owns 128)
    conv_inplace<16, 8, 5, RS2>(act, Wbf + 215040, 512, ba1, wave * 128, l15, quad);
    // knna2: 512 -> 512
    conv_inplace<16, 8, 5, RS2>(act, Wbf + 477184, 512, ba2, wave * 128, l15, quad);

    // pool: per node max over its 9 rows -> h[nodei][128+c]
    for (int e = tid; e < 8 * 512; e += 256) {
        int li = e >> 9, c = e & 511;
        int r0 = li * 9;
        float mx = -3.0e38f;
#pragma unroll
        for (int kk = 0; kk < 9; ++kk) mx = fmaxf(mx, bf2f(act[(r0 + kk) * RS2 + c]));
        h[(size_t)(node0 + li) * 640 + 128 + c] = f2bf(mx);
    }
}

// ---------------------------------------------------------------------------
// Fused stage 3: one block per 64 nodes. mlp1(640->512) -> mlp2(512->256)
// -> mlp3(256->4, fp32 VALU) -> epilogue (keypoints + softplus sigma).
// ---------------------------------------------------------------------------
static constexpr int RS3 = 648;   // 1296 B row stride: bank offset 4/row

__global__ __launch_bounds__(256, 1) void fused_stage3_kernel(
    const float* __restrict__ node, const u16* __restrict__ h,
    const u16* __restrict__ Wbf,
    const float* __restrict__ bm1, const float* __restrict__ bm2,
    const float* __restrict__ w3, const float* __restrict__ b3,
    float* __restrict__ out) {
    __shared__ __align__(16) u16 act[64 * RS3];   // 82,944 B
    int blk = blockIdx.x;              // 0..31
    int node0 = blk * 64;
    int tid = threadIdx.x, lane = tid & 63, wave = tid >> 6;
    int quad = lane >> 4, l15 = lane & 15;

    for (int e = tid; e < 64 * 80; e += 256) {
        int r = e / 80, seg = e - r * 80;
        *(u16x8*)(act + r * RS3 + seg * 8) = *(const u16x8*)(h + (size_t)(node0 + r) * 640 + seg * 8);
    }
    __syncthreads();

    // mlp1: K=640 -> Co=512 (wave owns 128)
    conv_inplace<20, 8, 4, RS3>(act, Wbf + 739328, 640, bm1, wave * 128, l15, quad);
    // mlp2: K=512 -> Co=256 (wave owns 64)
    conv_inplace<16, 4, 4, RS3>(act, Wbf + 1067008, 512, bm2, wave * 64, l15, quad);

    // mlp3 + epilogue: thread t -> node li = t/4, output oc = t%4
    {
        int li = tid >> 2, oc = tid & 3;
        const u16* row = act + li * RS3;
        const float* wrow = w3 + oc * 256;
        float a = 0.0f;
        for (int c = 0; c < 256; c += 4) {
            a += bf2f(row[c]) * wrow[c];
            a += bf2f(row[c + 1]) * wrow[c + 1];
            a += bf2f(row[c + 2]) * wrow[c + 2];
            a += bf2f(row[c + 3]) * wrow[c + 3];
        }
        a += b3[oc];
        int nodei = node0 + li;
        int b = nodei >> 9, m = nodei & 511;
        if (oc < 3) {
            float nv = node[((size_t)b * 3 + oc) * M_ + m];
            out[((size_t)b * 3 + oc) * M_ + m] = nv;
            out[6144 + ((size_t)b * 3 + oc) * M_ + m] = nv + a;
        } else {
            out[12288 + nodei] = fmaxf(a, 0.0f) + log1pf(expf(-fabsf(a))) + 0.001f;
        }
    }
}

// ---------------------------------------------------------------------------
extern "C" void kernel_launch(void* const* d_in, const int* in_sizes, int n_in,
                              void* d_out, int out_size, void* d_ws, size_t ws_size,
                              hipStream_t stream) {
    (void)in_sizes; (void)n_in; (void)out_size; (void)ws_size;
    const float* x = (const float*)d_in[0];
    const float* sn = (const float*)d_in[1];
    const float* node = (const float*)d_in[2];
    const float* W[13];
    const float* Bs[13];
    for (int i = 0; i < 13; ++i) {
        W[i] = (const float*)d_in[3 + 2 * i];
        Bs[i] = (const float*)d_in[4 + 2 * i];
    }
    float* out = (float*)d_out;

    char* ws = (char*)d_ws;
    int* idx = (int*)(ws + 0);                 //   524,288
    int* knn = (int*)(ws + 524288);            //    73,728
    u16* Wbf = (u16*)(ws + 598016);            // 2,396,160
    u16* h   = (u16*)(ws + 2994176);           // 2,621,440 (2048 x 640)
    float4* pk = (float4*)(ws + 5615616);      // 1,048,576

    WConvArgs wa;
    for (int w = 0; w < 12; ++w) wa.src[w] = W[w];
    convert_weights_kernel<<<(1198080 + 255) / 256, 256, 0, stream>>>(wa, Wbf);

    pack_x_kernel<<<256, 256, 0, stream>>>(x, pk);
    ball_query_kernel<<<2048, 256, 0, stream>>>(pk, node, idx);
    knn_kernel<<<2048, 64, 0, stream>>>(node, knn);

    fused_stage1_kernel<<<2048, 256, 0, stream>>>(x, sn, node, idx, Wbf,
                                                  Bs[0], Bs[1], Bs[2], Bs[3], Bs[4], h);
    fused_stage2_kernel<<<256, 256, 0, stream>>>(node, h, knn, Wbf,
                                                 Bs[5], Bs[6], Bs[7], Bs[8], Bs[9]);
    fused_stage3_kernel<<<32, 256, 0, stream>>>(node, h, Wbf, Bs[10], Bs[11],
                                                W[12], Bs[12], out);
}

// Round 5
// 262.109 us; speedup vs baseline: 7.3515x; 1.0989x over previous
//
#include <hip/hip_runtime.h>

typedef unsigned short u16;
typedef unsigned int u32;
typedef __bf16 bf16x8 __attribute__((ext_vector_type(8)));
typedef float floatx4 __attribute__((ext_vector_type(4)));
typedef unsigned short u16x8 __attribute__((ext_vector_type(8)));
typedef unsigned int u32x4 __attribute__((ext_vector_type(4)));

static constexpr int B_ = 4;
static constexpr int N_ = 16384;
static constexpr int M_ = 512;

__device__ __forceinline__ u16 f2bf(float f) {
    u32 u = __float_as_uint(f);
    u32 r = (u + 0x7fffu + ((u >> 16) & 1u)) >> 16;
    return (u16)r;
}
__device__ __forceinline__ float bf2f(u16 x) {
    return __uint_as_float(((u32)x) << 16);
}
__device__ __forceinline__ u32 pack2(float a, float b) {
    return (u32)f2bf(a) | ((u32)f2bf(b) << 16);
}

// ---------------------------------------------------------------------------
// Pack x into [x,y,z,|p|^2] float4 per point for the ball query.
// ---------------------------------------------------------------------------
__global__ void pack_x_kernel(const float* __restrict__ x, float4* __restrict__ pk) {
    int t = blockIdx.x * 256 + threadIdx.x;   // 0..65535
    int b = t >> 14, n = t & (N_ - 1);
    const float* xb = x + (size_t)b * 3 * N_;
    float px = xb[n], py = xb[N_ + n], pz = xb[2 * N_ + n];
    pk[t] = make_float4(px, py, pz, px * px + py * py + pz * pz);
}

// ---------------------------------------------------------------------------
// Ball query: 4 waves per (b,m); early exit when a wave's 64 slots are full
// (safe: truncated counts are >=64; merge only needs exact counts < 64).
// ---------------------------------------------------------------------------
__global__ __launch_bounds__(256) void ball_query_kernel(
    const float4* __restrict__ pk, const float* __restrict__ node, int* __restrict__ idx) {
    int bm = blockIdx.x;
    int b = bm >> 9, m = bm & 511;
    int tid = threadIdx.x, wave = tid >> 6, lane = tid & 63;
    __shared__ int sidx[4][64];
    __shared__ int scnt[4];

    const float4* pb = pk + ((size_t)b << 14);
    float nx = node[((size_t)b * 3 + 0) * M_ + m];
    float ny = node[((size_t)b * 3 + 1) * M_ + m];
    float nz = node[((size_t)b * 3 + 2) * M_ + m];
    float aa = nx * nx + ny * ny + nz * nz;

    int cnt = 0;
    int base = wave * 4096;
    for (int n0 = base; n0 < base + 4096; n0 += 64) {
        float4 p = pb[n0 + lane];
        float d = aa + p.w - 2.0f * (nx * p.x + ny * p.y + nz * p.z);
        bool inb = d < 4.0f;
        unsigned long long mask = __ballot(inb);
        if (inb && cnt < 64) {
            int pos = cnt + __popcll(mask & ((1ull << lane) - 1ull));
            if (pos < 64) sidx[wave][pos] = n0 + lane;
        }
        cnt += __popcll(mask);
        if (cnt >= 64) break;   // wave-uniform
    }
    if (lane == 0) scnt[wave] = cnt;
    __syncthreads();
    if (tid < 64) {
        int total = scnt[0] + scnt[1] + scnt[2] + scnt[3];
        int v = 0;
        if (total > 0) {
            int lim = total < 64 ? total : 64;
            int slot = tid < lim ? tid : 0;
            int w = 0, pre = 0;
            while (w < 3 && slot >= pre + scnt[w]) { pre += scnt[w]; ++w; }
            v = sidx[w][slot - pre];
        }
        idx[(size_t)bm * 64 + tid] = v;
    }
}

// ---------------------------------------------------------------------------
// KNN over nodes (exact match with reference top_k tie-breaking).
// ---------------------------------------------------------------------------
__global__ void knn_kernel(const float* __restrict__ node, int* __restrict__ knn) {
    int bm = blockIdx.x;
    int b = bm >> 9, m = bm & 511;
    int lane = threadIdx.x;
    const float* nb = node + (size_t)b * 3 * M_;
    float nx = nb[m], ny = nb[M_ + m], nz = nb[2 * M_ + m];
    float aa = nx * nx + ny * ny + nz * nz;

    float dist[8];
    int didx[8];
#pragma unroll
    for (int i = 0; i < 8; ++i) {
        int n = lane + i * 64;
        float px = nb[n], py = nb[M_ + n], pz = nb[2 * M_ + n];
        float bb = px * px + py * py + pz * pz;
        float ab = nx * px + ny * py + nz * pz;
        dist[i] = aa + bb - 2.0f * ab;
        didx[i] = n;
    }
    for (int r = 0; r < 9; ++r) {
        float bv = dist[0]; int bi = didx[0]; int bslot = 0;
#pragma unroll
        for (int i = 1; i < 8; ++i) {
            if (dist[i] < bv || (dist[i] == bv && didx[i] < bi)) {
                bv = dist[i]; bi = didx[i]; bslot = i;
            }
        }
        float rv = bv; int ri = bi;
        for (int off = 32; off > 0; off >>= 1) {
            float ov = __shfl_down(rv, off);
            int   oi = __shfl_down(ri, off);
            if (ov < rv || (ov == rv && oi < ri)) { rv = ov; ri = oi; }
        }
        ri = __shfl(ri, 0);
        if (lane == 0) knn[(size_t)bm * 9 + r] = ri;
        if (bi == ri) dist[bslot] = 3.0e38f;
    }
}

// ---------------------------------------------------------------------------
// Weight fp32 -> bf16 conversion with K padded (zeros).
// knnb1 (w=5) K-layout is permuted: k0..2=coords, 3..7=0, 8..135=feat1, rest 0.
// ---------------------------------------------------------------------------
struct WConvArgs { const float* src[12]; };

__global__ void convert_weights_kernel(WConvArgs args, u16* __restrict__ dst) {
    const int CI[12] = {6, 64, 64, 128, 128, 131, 256, 256, 512, 512, 640, 512};
    const int KP[12] = {32, 64, 64, 128, 128, 160, 256, 256, 512, 512, 640, 512};
    const int OFF[13] = {0, 2048, 6144, 10240, 26624, 43008, 83968, 149504,
                         215040, 477184, 739328, 1067008, 1198080};
    int e = blockIdx.x * 256 + threadIdx.x;
    if (e >= 1198080) return;
    int w = 0;
    while (e >= OFF[w + 1]) ++w;
    int local = e - OFF[w];
    int kp = KP[w];
    int co = local / kp, k = local - co * kp;
    float v = 0.0f;
    if (w == 5) {
        if (k < 3) v = args.src[5][(size_t)co * 131 + k];
        else if (k >= 8 && k < 136) v = args.src[5][(size_t)co * 131 + (k - 5)];
    } else if (k < CI[w]) {
        v = args.src[w][(size_t)co * CI[w] + k];
    }
    dst[e] = f2bf(v);
}

// ---------------------------------------------------------------------------
// Fused stage 1: one block per node (256 threads).
// ---------------------------------------------------------------------------
static constexpr int RS = 136;

__device__ __forceinline__ bf16x8 ldsA(const u16* act, int rf, int l15, int quad, int ks) {
    return *(const bf16x8*)(act + (rf * 16 + l15) * RS + ks * 32 + quad * 8);
}
__device__ __forceinline__ bf16x8 ldW(const u16* W, int ks, int l15, int quad, int kstride) {
    return *(const bf16x8*)(W + (size_t)l15 * kstride + ks * 32 + quad * 8);
}

__global__ __launch_bounds__(256) void fused_stage1_kernel(
    const float* __restrict__ x, const float* __restrict__ sn,
    const float* __restrict__ node, const int* __restrict__ idx,
    const u16* __restrict__ Wbf,
    const float* __restrict__ b1, const float* __restrict__ b2,
    const float* __restrict__ b3, const float* __restrict__ b4,
    const float* __restrict__ b5, u16* __restrict__ h) {
    __shared__ __align__(16) u16 act[64 * RS];
    __shared__ __align__(16) u16 mv[64];
    int bm = blockIdx.x;
    int b = bm >> 9, m = bm & 511;
    int tid = threadIdx.x, wave = tid >> 6, lane = tid & 63;
    int quad = lane >> 4, l15 = lane & 15;

    {   // gather spread over all 256 threads: grp handles a channel pair
        int row = tid & 63, grp = tid >> 6;
        int j = idx[(size_t)bm * 64 + row];
        const float* xb = x + (size_t)b * 3 * N_;
        const float* sb = sn + (size_t)b * 3 * N_;
        if (grp == 0) {
            float c0 = xb[j]      - node[((size_t)b * 3 + 0) * M_ + m];
            float c1 = xb[N_ + j] - node[((size_t)b * 3 + 1) * M_ + m];
            *(u32*)(act + row * RS) = pack2(c0, c1);
        } else if (grp == 1) {
            float c2 = xb[2 * N_ + j] - node[((size_t)b * 3 + 2) * M_ + m];
            *(u32*)(act + row * RS + 2) = pack2(c2, sb[j]);
        } else if (grp == 2) {
            *(u32*)(act + row * RS + 4) = pack2(sb[N_ + j], sb[2 * N_ + j]);
        } else {
            *(u32*)(act + row * RS + 6) = 0u;
            u32x4* r = (u32x4*)(act + row * RS + 8);
            r[0] = (u32x4){0u, 0u, 0u, 0u};
            r[1] = (u32x4){0u, 0u, 0u, 0u};
            r[2] = (u32x4){0u, 0u, 0u, 0u};
        }
    }
    __syncthreads();

    {   // conv1: K=32 (6 used), co 64
        const u16* Wp = Wbf + 0 + (size_t)(wave * 16) * 32;
        bf16x8 bw = ldW(Wp, 0, l15, quad, 32);
        bf16x8 a[4];
#pragma unroll
        for (int rf = 0; rf < 4; ++rf) a[rf] = ldsA(act, rf, l15, quad, 0);
        floatx4 c[4];
#pragma unroll
        for (int rf = 0; rf < 4; ++rf)
            c[rf] = __builtin_amdgcn_mfma_f32_16x16x32_bf16(a[rf], bw, (floatx4){0.f,0.f,0.f,0.f}, 0, 0, 0);
        float bias = b1[wave * 16 + l15];
        __syncthreads();
#pragma unroll
        for (int rf = 0; rf < 4; ++rf)
#pragma unroll
            for (int r = 0; r < 4; ++r)
                act[(rf * 16 + quad * 4 + r) * RS + wave * 16 + l15] = f2bf(fmaxf(c[rf][r] + bias, 0.0f));
        __syncthreads();
    }

    const int WOFF23[2] = {2048, 6144};
    const float* bp23[2] = {b2, b3};
#pragma unroll 1
    for (int cv = 0; cv < 2; ++cv) {   // conv2 / conv3: K=64, co 64
        const u16* Wp = Wbf + WOFF23[cv] + (size_t)(wave * 16) * 64;
        bf16x8 bw[2], a[4][2];
#pragma unroll
        for (int ks = 0; ks < 2; ++ks) bw[ks] = ldW(Wp, ks, l15, quad, 64);
#pragma unroll
        for (int rf = 0; rf < 4; ++rf)
#pragma unroll
            for (int ks = 0; ks < 2; ++ks) a[rf][ks] = ldsA(act, rf, l15, quad, ks);
        floatx4 c[4] = {};
#pragma unroll
        for (int ks = 0; ks < 2; ++ks)
#pragma unroll
            for (int rf = 0; rf < 4; ++rf)
                c[rf] = __builtin_amdgcn_mfma_f32_16x16x32_bf16(a[rf][ks], bw[ks], c[rf], 0, 0, 0);
        float bias = bp23[cv][wave * 16 + l15];
        float v[4][4];
        float mx = 0.0f;
#pragma unroll
        for (int rf = 0; rf < 4; ++rf)
#pragma unroll
            for (int r = 0; r < 4; ++r) {
                v[rf][r] = fmaxf(c[rf][r] + bias, 0.0f);
                mx = fmaxf(mx, v[rf][r]);
            }
        __syncthreads();
#pragma unroll
        for (int rf = 0; rf < 4; ++rf)
#pragma unroll
            for (int r = 0; r < 4; ++r)
                act[(rf * 16 + quad * 4 + r) * RS + wave * 16 + l15] = f2bf(v[rf][r]);
        if (cv == 1) {
            mx = fmaxf(mx, __shfl_xor(mx, 16));
            mx = fmaxf(mx, __shfl_xor(mx, 32));
            if (quad == 0) mv[wave * 16 + l15] = f2bf(mx);
        }
        __syncthreads();
    }

    {   // conv4: K=128 ([conv3 | rowmax]), co 128
        const u16* Wp = Wbf + 10240 + (size_t)(wave * 32) * 128;
        bf16x8 bw[2][4];
#pragma unroll
        for (int cf = 0; cf < 2; ++cf)
#pragma unroll
            for (int ks = 0; ks < 4; ++ks)
                bw[cf][ks] = ldW(Wp + (size_t)cf * 16 * 128, ks, l15, quad, 128);
        bf16x8 a01[4][2];
#pragma unroll
        for (int rf = 0; rf < 4; ++rf)
#pragma unroll
            for (int ks = 0; ks < 2; ++ks) a01[rf][ks] = ldsA(act, rf, l15, quad, ks);
        bf16x8 am2 = *(const bf16x8*)(mv + quad * 8);
        bf16x8 am3 = *(const bf16x8*)(mv + 32 + quad * 8);
        floatx4 c[4][2] = {};
#pragma unroll
        for (int ks = 0; ks < 4; ++ks) {
#pragma unroll
            for (int rf = 0; rf < 4; ++rf) {
                bf16x8 a = (ks < 2) ? a01[rf][ks] : (ks == 2 ? am2 : am3);
#pragma unroll
                for (int cf = 0; cf < 2; ++cf)
                    c[rf][cf] = __builtin_amdgcn_mfma_f32_16x16x32_bf16(a, bw[cf][ks], c[rf][cf], 0, 0, 0);
            }
        }
        float bias[2];
#pragma unroll
        for (int cf = 0; cf < 2; ++cf) bias[cf] = b4[wave * 32 + cf * 16 + l15];
        __syncthreads();
#pragma unroll
        for (int rf = 0; rf < 4; ++rf)
#pragma unroll
            for (int cf = 0; cf < 2; ++cf)
#pragma unroll
                for (int r = 0; r < 4; ++r)
                    act[(rf * 16 + quad * 4 + r) * RS + wave * 32 + cf * 16 + l15] =
                        f2bf(fmaxf(c[rf][cf][r] + bias[cf], 0.0f));
        __syncthreads();
    }

    {   // conv5 + maxpool
        const u16* Wp = Wbf + 26624 + (size_t)(wave * 32) * 128;
        bf16x8 bw[2][4];
#pragma unroll
        for (int cf = 0; cf < 2; ++cf)
#pragma unroll
            for (int ks = 0; ks < 4; ++ks)
                bw[cf][ks] = ldW(Wp + (size_t)cf * 16 * 128, ks, l15, quad, 128);
        floatx4 c[4][2] = {};
#pragma unroll
        for (int ks = 0; ks < 4; ++ks) {
#pragma unroll
            for (int rf = 0; rf < 4; ++rf) {
                bf16x8 a = ldsA(act, rf, l15, quad, ks);
#pragma unroll
                for (int cf = 0; cf < 2; ++cf)
                    c[rf][cf] = __builtin_amdgcn_mfma_f32_16x16x32_bf16(a, bw[cf][ks], c[rf][cf], 0, 0, 0);
            }
        }
#pragma unroll
        for (int cf = 0; cf < 2; ++cf) {
            float bias = b5[wave * 32 + cf * 16 + l15];
            float mx = 0.0f;
#pragma unroll
            for (int rf = 0; rf < 4; ++rf)
#pragma unroll
                for (int r = 0; r < 4; ++r)
                    mx = fmaxf(mx, fmaxf(c[rf][cf][r] + bias, 0.0f));
            mx = fmaxf(mx, __shfl_xor(mx, 16));
            mx = fmaxf(mx, __shfl_xor(mx, 32));
            if (quad == 0) h[(size_t)bm * 640 + wave * 32 + cf * 16 + l15] = f2bf(mx);
        }
    }
}

// ---------------------------------------------------------------------------
// Generic in-LDS in-place conv step. act tile: (RF*16) rows x RSx u16 cols.
// Wave owns out cols [cb, cb+CF*16). Weights stream from L2 (reg ping-pong).
// ---------------------------------------------------------------------------
template <int KS, int CF, int RF, int RSx>
__device__ __forceinline__ void conv_inplace(u16* act, const u16* __restrict__ W0, int KP,
                                             const float* __restrict__ bias, int cb,
                                             int l15, int quad) {
    floatx4 acc[RF][CF];
#pragma unroll
    for (int rf = 0; rf < RF; ++rf)
#pragma unroll
        for (int cf = 0; cf < CF; ++cf) acc[rf][cf] = (floatx4){0.f, 0.f, 0.f, 0.f};

    bf16x8 bwA[CF], bwB[CF];
#pragma unroll
    for (int cf = 0; cf < CF; ++cf)
        bwA[cf] = *(const bf16x8*)(W0 + (size_t)(cb + cf * 16 + l15) * KP + quad * 8);

#pragma unroll
    for (int ks = 0; ks < KS; ++ks) {
        bf16x8* cur = (ks % 2 == 0) ? bwA : bwB;
        bf16x8* nxt = (ks % 2 == 0) ? bwB : bwA;
        if (ks + 1 < KS) {
#pragma unroll
            for (int cf = 0; cf < CF; ++cf)
                nxt[cf] = *(const bf16x8*)(W0 + (size_t)(cb + cf * 16 + l15) * KP +
                                           (ks + 1) * 32 + quad * 8);
        }
#pragma unroll
        for (int rf = 0; rf < RF; ++rf) {
            bf16x8 a = *(const bf16x8*)(act + (rf * 16 + l15) * RSx + ks * 32 + quad * 8);
#pragma unroll
            for (int cf = 0; cf < CF; ++cf)
                acc[rf][cf] = __builtin_amdgcn_mfma_f32_16x16x32_bf16(a, cur[cf], acc[rf][cf], 0, 0, 0);
        }
    }
    __syncthreads();   // all waves' reads complete before in-place writes
#pragma unroll
    for (int cf = 0; cf < CF; ++cf) {
        float bs = bias[cb + cf * 16 + l15];
#pragma unroll
        for (int rf = 0; rf < RF; ++rf)
#pragma unroll
            for (int r = 0; r < 4; ++r)
                act[(rf * 16 + quad * 4 + r) * RSx + cb + cf * 16 + l15] =
                    f2bf(fmaxf(acc[rf][cf][r] + bs, 0.0f));
    }
    __syncthreads();
}

// ---------------------------------------------------------------------------
// Fused stage 2: one block per 8 nodes, 512 threads (8 waves -> 2 waves/SIMD).
// K-layout: [coords 0..2 | pad | feat1 8..135 | pad..159] (weights permuted).
// ---------------------------------------------------------------------------
static constexpr int RS2 = 520;

__global__ __launch_bounds__(512, 1) void fused_stage2_kernel(
    const float* __restrict__ node, u16* __restrict__ h, const int* __restrict__ knn,
    const u16* __restrict__ Wbf,
    const float* __restrict__ bb1, const float* __restrict__ bb2,
    const float* __restrict__ bb3, const float* __restrict__ ba1,
    const float* __restrict__ ba2) {
    __shared__ __align__(16) u16 act[80 * RS2];   // 83,200 B
    int blk = blockIdx.x;              // 0..255
    int node0 = blk * 8;
    int b = node0 >> 9;
    int tid = threadIdx.x, wave = tid >> 6, lane = tid & 63;
    int quad = lane >> 4, l15 = lane & 15;
    (void)lane;

    // zero cols 0..159 of all 80 rows
    for (int e = tid; e < 80 * 20; e += 512)
        *(u16x8*)(act + (e / 20) * RS2 + (e % 20) * 8) = (u16x8){0,0,0,0,0,0,0,0};
    __syncthreads();
    // coords -> cols 0..2
    for (int e = tid; e < 72 * 3; e += 512) {
        int r = e / 3, c = e - r * 3;
        int nodei = node0 + r / 9;
        int j = knn[(size_t)nodei * 9 + (r % 9)];
        float v = node[((size_t)b * 3 + c) * M_ + j] - node[((size_t)b * 3 + c) * M_ + (nodei & 511)];
        act[r * RS2 + c] = f2bf(v);
    }
    // feat1 -> cols 8..135 (16B-aligned vector copies)
    for (int e = tid; e < 72 * 16; e += 512) {
        int r = e >> 4, s = e & 15;
        int nodei = node0 + r / 9;
        int j = knn[(size_t)nodei * 9 + (r % 9)];
        *(u16x8*)(act + r * RS2 + 8 + s * 8) =
            *(const u16x8*)(h + (size_t)(b * 512 + j) * 640 + s * 8);
    }
    __syncthreads();

    // knnb1: K=160 -> 256 ; knnb2/3: 256 -> 256 (wave owns 32 cols)
    conv_inplace<5, 2, 5, RS2>(act, Wbf + 43008, 160, bb1, wave * 32, l15, quad);
    conv_inplace<8, 2, 5, RS2>(act, Wbf + 83968, 256, bb2, wave * 32, l15, quad);
    conv_inplace<8, 2, 5, RS2>(act, Wbf + 149504, 256, bb3, wave * 32, l15, quad);

    // gmax: per node max over 9 rows of cols 0..255 -> bcast cols 256..511
    for (int e = tid; e < 8 * 32; e += 512) {
        int li = e >> 5, s = e & 31;
        int r0 = li * 9;
        float mx[8];
#pragma unroll
        for (int i = 0; i < 8; ++i) mx[i] = -3.0e38f;
#pragma unroll
        for (int kk = 0; kk < 9; ++kk) {
            u16x8 v = *(const u16x8*)(act + (r0 + kk) * RS2 + s * 8);
#pragma unroll
            for (int i = 0; i < 8; ++i) mx[i] = fmaxf(mx[i], bf2f(v[i]));
        }
        u16x8 o;
#pragma unroll
        for (int i = 0; i < 8; ++i) o[i] = f2bf(mx[i]);
#pragma unroll
        for (int kk = 0; kk < 9; ++kk)
            *(u16x8*)(act + (r0 + kk) * RS2 + 256 + s * 8) = o;
    }
    __syncthreads();

    // knna1/2: K=512 -> 512 (wave owns 64 cols)
    conv_inplace<16, 4, 5, RS2>(act, Wbf + 215040, 512, ba1, wave * 64, l15, quad);
    conv_inplace<16, 4, 5, RS2>(act, Wbf + 477184, 512, ba2, wave * 64, l15, quad);

    // pool: per node max over 9 rows -> h[nodei][128..639]
    for (int e = tid; e < 8 * 64; e += 512) {
        int li = e >> 6, s = e & 63;
        int r0 = li * 9;
        float mx[8];
#pragma unroll
        for (int i = 0; i < 8; ++i) mx[i] = -3.0e38f;
#pragma unroll
        for (int kk = 0; kk < 9; ++kk) {
            u16x8 v = *(const u16x8*)(act + (r0 + kk) * RS2 + s * 8);
#pragma unroll
            for (int i = 0; i < 8; ++i) mx[i] = fmaxf(mx[i], bf2f(v[i]));
        }
        u16x8 o;
#pragma unroll
        for (int i = 0; i < 8; ++i) o[i] = f2bf(mx[i]);
        *(u16x8*)(h + (size_t)(node0 + li) * 640 + 128 + s * 8) = o;
    }
}

// ---------------------------------------------------------------------------
// Fused stage 3: 128 blocks x 16 nodes, 512 threads.
// mlp1(640->512) -> mlp2(512->256) -> mlp3(256->4 fp32) -> epilogue.
// ---------------------------------------------------------------------------
static constexpr int RS3 = 648;

__global__ __launch_bounds__(512, 1) void fused_stage3_kernel(
    const float* __restrict__ node, const u16* __restrict__ h,
    const u16* __restrict__ Wbf,
    const float* __restrict__ bm1, const float* __restrict__ bm2,
    const float* __restrict__ w3, const float* __restrict__ b3,
    float* __restrict__ out) {
    __shared__ __align__(16) u16 act[16 * RS3];   // 20,736 B
    int blk = blockIdx.x;              // 0..127
    int node0 = blk * 16;
    int tid = threadIdx.x, lane = tid & 63, wave = tid >> 6;
    int quad = lane >> 4, l15 = lane & 15;

    for (int e = tid; e < 16 * 80; e += 512) {
        int r = e / 80, seg = e - r * 80;
        *(u16x8*)(act + r * RS3 + seg * 8) = *(const u16x8*)(h + (size_t)(node0 + r) * 640 + seg * 8);
    }
    __syncthreads();

    // mlp1: K=640 -> 512 (wave owns 64 cols); mlp2: K=512 -> 256 (32 cols)
    conv_inplace<20, 4, 1, RS3>(act, Wbf + 739328, 640, bm1, wave * 64, l15, quad);
    conv_inplace<16, 2, 1, RS3>(act, Wbf + 1067008, 512, bm2, wave * 32, l15, quad);

    // mlp3 + epilogue: thread t<64 -> node li = t/4, output oc = t%4
    if (tid < 64) {
        int li = tid >> 2, oc = tid & 3;
        const u16* row = act + li * RS3;
        const float* wrow = w3 + oc * 256;
        float a = 0.0f;
        for (int c = 0; c < 256; c += 4) {
            a += bf2f(row[c]) * wrow[c];
            a += bf2f(row[c + 1]) * wrow[c + 1];
            a += bf2f(row[c + 2]) * wrow[c + 2];
            a += bf2f(row[c + 3]) * wrow[c + 3];
        }
        a += b3[oc];
        int nodei = node0 + li;
        int b = nodei >> 9, m = nodei & 511;
        if (oc < 3) {
            float nv = node[((size_t)b * 3 + oc) * M_ + m];
            out[((size_t)b * 3 + oc) * M_ + m] = nv;
            out[6144 + ((size_t)b * 3 + oc) * M_ + m] = nv + a;
        } else {
            out[12288 + nodei] = fmaxf(a, 0.0f) + log1pf(expf(-fabsf(a))) + 0.001f;
        }
    }
}

// ---------------------------------------------------------------------------
extern "C" void kernel_launch(void* const* d_in, const int* in_sizes, int n_in,
                              void* d_out, int out_size, void* d_ws, size_t ws_size,
                              hipStream_t stream) {
    (void)in_sizes; (void)n_in; (void)out_size; (void)ws_size;
    const float* x = (const float*)d_in[0];
    const float* sn = (const float*)d_in[1];
    const float* node = (const float*)d_in[2];
    const float* W[13];
    const float* Bs[13];
    for (int i = 0; i < 13; ++i) {
        W[i] = (const float*)d_in[3 + 2 * i];
        Bs[i] = (const float*)d_in[4 + 2 * i];
    }
    float* out = (float*)d_out;

    char* ws = (char*)d_ws;
    int* idx = (int*)(ws + 0);                 //   524,288
    int* knn = (int*)(ws + 524288);            //    73,728
    u16* Wbf = (u16*)(ws + 598016);            // 2,396,160
    u16* h   = (u16*)(ws + 2994176);           // 2,621,440 (2048 x 640)
    float4* pk = (float4*)(ws + 5615616);      // 1,048,576

    WConvArgs wa;
    for (int w = 0; w < 12; ++w) wa.src[w] = W[w];
    convert_weights_kernel<<<(1198080 + 255) / 256, 256, 0, stream>>>(wa, Wbf);

    pack_x_kernel<<<256, 256, 0, stream>>>(x, pk);
    ball_query_kernel<<<2048, 256, 0, stream>>>(pk, node, idx);
    knn_kernel<<<2048, 64, 0, stream>>>(node, knn);

    fused_stage1_kernel<<<2048, 256, 0, stream>>>(x, sn, node, idx, Wbf,
                                                  Bs[0], Bs[1], Bs[2], Bs[3], Bs[4], h);
    fused_stage2_kernel<<<256, 512, 0, stream>>>(node, h, knn, Wbf,
                                                 Bs[5], Bs[6], Bs[7], Bs[8], Bs[9]);
    fused_stage3_kernel<<<128, 512, 0, stream>>>(node, h, Wbf, Bs[10], Bs[11],
                                                 W[12], Bs[12], out);
}

// Round 6
// 257.576 us; speedup vs baseline: 7.4809x; 1.0176x over previous
//
#include <hip/hip_runtime.h>

typedef unsigned short u16;
typedef unsigned int u32;
typedef __bf16 bf16x8 __attribute__((ext_vector_type(8)));
typedef float floatx4 __attribute__((ext_vector_type(4)));
typedef unsigned short u16x8 __attribute__((ext_vector_type(8)));
typedef unsigned int u32x4 __attribute__((ext_vector_type(4)));

static constexpr int B_ = 4;
static constexpr int N_ = 16384;
static constexpr int M_ = 512;

__device__ __forceinline__ u16 f2bf(float f) {
    u32 u = __float_as_uint(f);
    u32 r = (u + 0x7fffu + ((u >> 16) & 1u)) >> 16;
    return (u16)r;
}
__device__ __forceinline__ float bf2f(u16 x) {
    return __uint_as_float(((u32)x) << 16);
}
__device__ __forceinline__ u32 pack2(float a, float b) {
    return (u32)f2bf(a) | ((u32)f2bf(b) << 16);
}

// ---------------------------------------------------------------------------
// Pack x into [x,y,z,|p|^2] float4 per point for the ball query.
// ---------------------------------------------------------------------------
__global__ void pack_x_kernel(const float* __restrict__ x, float4* __restrict__ pk) {
    int t = blockIdx.x * 256 + threadIdx.x;   // 0..65535
    int b = t >> 14, n = t & (N_ - 1);
    const float* xb = x + (size_t)b * 3 * N_;
    float px = xb[n], py = xb[N_ + n], pz = xb[2 * N_ + n];
    pk[t] = make_float4(px, py, pz, px * px + py * py + pz * pz);
}

// ---------------------------------------------------------------------------
// Ball query: 4 waves per (b,m); early exit when a wave's 64 slots are full.
// ---------------------------------------------------------------------------
__global__ __launch_bounds__(256) void ball_query_kernel(
    const float4* __restrict__ pk, const float* __restrict__ node, int* __restrict__ idx) {
    int bm = blockIdx.x;
    int b = bm >> 9, m = bm & 511;
    int tid = threadIdx.x, wave = tid >> 6, lane = tid & 63;
    __shared__ int sidx[4][64];
    __shared__ int scnt[4];

    const float4* pb = pk + ((size_t)b << 14);
    float nx = node[((size_t)b * 3 + 0) * M_ + m];
    float ny = node[((size_t)b * 3 + 1) * M_ + m];
    float nz = node[((size_t)b * 3 + 2) * M_ + m];
    float aa = nx * nx + ny * ny + nz * nz;

    int cnt = 0;
    int base = wave * 4096;
    for (int n0 = base; n0 < base + 4096; n0 += 64) {
        float4 p = pb[n0 + lane];
        float d = aa + p.w - 2.0f * (nx * p.x + ny * p.y + nz * p.z);
        bool inb = d < 4.0f;
        unsigned long long mask = __ballot(inb);
        if (inb && cnt < 64) {
            int pos = cnt + __popcll(mask & ((1ull << lane) - 1ull));
            if (pos < 64) sidx[wave][pos] = n0 + lane;
        }
        cnt += __popcll(mask);
        if (cnt >= 64) break;   // wave-uniform
    }
    if (lane == 0) scnt[wave] = cnt;
    __syncthreads();
    if (tid < 64) {
        int total = scnt[0] + scnt[1] + scnt[2] + scnt[3];
        int v = 0;
        if (total > 0) {
            int lim = total < 64 ? total : 64;
            int slot = tid < lim ? tid : 0;
            int w = 0, pre = 0;
            while (w < 3 && slot >= pre + scnt[w]) { pre += scnt[w]; ++w; }
            v = sidx[w][slot - pre];
        }
        idx[(size_t)bm * 64 + tid] = v;
    }
}

// ---------------------------------------------------------------------------
// KNN over nodes (exact match with reference top_k tie-breaking).
// ---------------------------------------------------------------------------
__global__ void knn_kernel(const float* __restrict__ node, int* __restrict__ knn) {
    int bm = blockIdx.x;
    int b = bm >> 9, m = bm & 511;
    int lane = threadIdx.x;
    const float* nb = node + (size_t)b * 3 * M_;
    float nx = nb[m], ny = nb[M_ + m], nz = nb[2 * M_ + m];
    float aa = nx * nx + ny * ny + nz * nz;

    float dist[8];
    int didx[8];
#pragma unroll
    for (int i = 0; i < 8; ++i) {
        int n = lane + i * 64;
        float px = nb[n], py = nb[M_ + n], pz = nb[2 * M_ + n];
        float bb = px * px + py * py + pz * pz;
        float ab = nx * px + ny * py + nz * pz;
        dist[i] = aa + bb - 2.0f * ab;
        didx[i] = n;
    }
    for (int r = 0; r < 9; ++r) {
        float bv = dist[0]; int bi = didx[0]; int bslot = 0;
#pragma unroll
        for (int i = 1; i < 8; ++i) {
            if (dist[i] < bv || (dist[i] == bv && didx[i] < bi)) {
                bv = dist[i]; bi = didx[i]; bslot = i;
            }
        }
        float rv = bv; int ri = bi;
        for (int off = 32; off > 0; off >>= 1) {
            float ov = __shfl_down(rv, off);
            int   oi = __shfl_down(ri, off);
            if (ov < rv || (ov == rv && oi < ri)) { rv = ov; ri = oi; }
        }
        ri = __shfl(ri, 0);
        if (lane == 0) knn[(size_t)bm * 9 + r] = ri;
        if (bi == ri) dist[bslot] = 3.0e38f;
    }
}

// ---------------------------------------------------------------------------
// Weight fp32 -> bf16 conversion with K padded (zeros).
// knnb1 (w=5) K-layout permuted: k0..2=coords, 3..7=0, 8..135=feat1, rest 0.
// ---------------------------------------------------------------------------
struct WConvArgs { const float* src[12]; };

__global__ void convert_weights_kernel(WConvArgs args, u16* __restrict__ dst) {
    const int CI[12] = {6, 64, 64, 128, 128, 131, 256, 256, 512, 512, 640, 512};
    const int KP[12] = {32, 64, 64, 128, 128, 160, 256, 256, 512, 512, 640, 512};
    const int OFF[13] = {0, 2048, 6144, 10240, 26624, 43008, 83968, 149504,
                         215040, 477184, 739328, 1067008, 1198080};
    int e = blockIdx.x * 256 + threadIdx.x;
    if (e >= 1198080) return;
    int w = 0;
    while (e >= OFF[w + 1]) ++w;
    int local = e - OFF[w];
    int kp = KP[w];
    int co = local / kp, k = local - co * kp;
    float v = 0.0f;
    if (w == 5) {
        if (k < 3) v = args.src[5][(size_t)co * 131 + k];
        else if (k >= 8 && k < 136) v = args.src[5][(size_t)co * 131 + (k - 5)];
    } else if (k < CI[w]) {
        v = args.src[w][(size_t)co * CI[w] + k];
    }
    dst[e] = f2bf(v);
}

// ---------------------------------------------------------------------------
// Fused stage 1: one block per 2 nodes (128 rows), 256 threads.
// ---------------------------------------------------------------------------
static constexpr int RS = 136;

__device__ __forceinline__ bf16x8 ldsA(const u16* act, int rf, int l15, int quad, int ks) {
    return *(const bf16x8*)(act + (rf * 16 + l15) * RS + ks * 32 + quad * 8);
}
__device__ __forceinline__ bf16x8 ldW(const u16* W, int ks, int l15, int quad, int kstride) {
    return *(const bf16x8*)(W + (size_t)l15 * kstride + ks * 32 + quad * 8);
}

__global__ __launch_bounds__(256, 2) void fused_stage1_kernel(
    const float* __restrict__ x, const float* __restrict__ sn,
    const float* __restrict__ node, const int* __restrict__ idx,
    const u16* __restrict__ Wbf,
    const float* __restrict__ b1, const float* __restrict__ b2,
    const float* __restrict__ b3, const float* __restrict__ b4,
    const float* __restrict__ b5, u16* __restrict__ h) {
    __shared__ __align__(16) u16 act[128 * RS];   // 34,816 B
    __shared__ __align__(16) u16 mv[2][64];
    int blk = blockIdx.x;              // 0..1023
    int bm0 = blk * 2;
    int tid = threadIdx.x, wave = tid >> 6, lane = tid & 63;
    int quad = lane >> 4, l15 = lane & 15;

    {   // gather 2 nodes x 64 neighbors; grp 0: cols 0..3, grp 1: cols 4..31
        int row = tid & 127, grp = tid >> 7;
        int bm = bm0 + (row >> 6);
        int b = bm >> 9, m = bm & 511;
        int j = idx[(size_t)bm * 64 + (row & 63)];
        const float* xb = x + (size_t)b * 3 * N_;
        const float* sb = sn + (size_t)b * 3 * N_;
        u16* r = act + row * RS;
        if (grp == 0) {
            float c0 = xb[j]          - node[((size_t)b * 3 + 0) * M_ + m];
            float c1 = xb[N_ + j]     - node[((size_t)b * 3 + 1) * M_ + m];
            float c2 = xb[2 * N_ + j] - node[((size_t)b * 3 + 2) * M_ + m];
            *(u32*)(r)     = pack2(c0, c1);
            *(u32*)(r + 2) = pack2(c2, sb[j]);
        } else {
            *(u32*)(r + 4) = pack2(sb[N_ + j], sb[2 * N_ + j]);
            *(u32*)(r + 6) = 0u;
            u32x4* z = (u32x4*)(r + 8);
            z[0] = (u32x4){0u, 0u, 0u, 0u};
            z[1] = (u32x4){0u, 0u, 0u, 0u};
            z[2] = (u32x4){0u, 0u, 0u, 0u};
        }
    }
    __syncthreads();

    {   // conv1: K=32 (6 used), co 64 (wave owns 16)
        const u16* Wp = Wbf + (size_t)(wave * 16) * 32;
        bf16x8 bw = ldW(Wp, 0, l15, quad, 32);
        floatx4 c[8];
#pragma unroll
        for (int rf = 0; rf < 8; ++rf) {
            bf16x8 a = ldsA(act, rf, l15, quad, 0);
            c[rf] = __builtin_amdgcn_mfma_f32_16x16x32_bf16(a, bw, (floatx4){0.f,0.f,0.f,0.f}, 0, 0, 0);
        }
        float bias = b1[wave * 16 + l15];
        __syncthreads();
#pragma unroll
        for (int rf = 0; rf < 8; ++rf)
#pragma unroll
            for (int r = 0; r < 4; ++r)
                act[(rf * 16 + quad * 4 + r) * RS + wave * 16 + l15] = f2bf(fmaxf(c[rf][r] + bias, 0.0f));
        __syncthreads();
    }

    const int WOFF23[2] = {2048, 6144};
    const float* bp23[2] = {b2, b3};
#pragma unroll 1
    for (int cv = 0; cv < 2; ++cv) {   // conv2 / conv3: K=64, co 64
        const u16* Wp = Wbf + WOFF23[cv] + (size_t)(wave * 16) * 64;
        bf16x8 bw0 = ldW(Wp, 0, l15, quad, 64);
        bf16x8 bw1 = ldW(Wp, 1, l15, quad, 64);
        floatx4 c[8] = {};
#pragma unroll
        for (int ks = 0; ks < 2; ++ks)
#pragma unroll
            for (int rf = 0; rf < 8; ++rf) {
                bf16x8 a = ldsA(act, rf, l15, quad, ks);
                c[rf] = __builtin_amdgcn_mfma_f32_16x16x32_bf16(a, ks ? bw1 : bw0, c[rf], 0, 0, 0);
            }
        float bias = bp23[cv][wave * 16 + l15];
        float mxA = 0.0f, mxB = 0.0f;
#pragma unroll
        for (int rf = 0; rf < 8; ++rf)
#pragma unroll
            for (int r = 0; r < 4; ++r) {
                float v = fmaxf(c[rf][r] + bias, 0.0f);
                if (rf < 4) mxA = fmaxf(mxA, v); else mxB = fmaxf(mxB, v);
            }
        __syncthreads();
#pragma unroll
        for (int rf = 0; rf < 8; ++rf)
#pragma unroll
            for (int r = 0; r < 4; ++r)
                act[(rf * 16 + quad * 4 + r) * RS + wave * 16 + l15] = f2bf(fmaxf(c[rf][r] + bias, 0.0f));
        if (cv == 1) {
            mxA = fmaxf(mxA, __shfl_xor(mxA, 16));
            mxA = fmaxf(mxA, __shfl_xor(mxA, 32));
            mxB = fmaxf(mxB, __shfl_xor(mxB, 16));
            mxB = fmaxf(mxB, __shfl_xor(mxB, 32));
            if (quad == 0) {
                mv[0][wave * 16 + l15] = f2bf(mxA);
                mv[1][wave * 16 + l15] = f2bf(mxB);
            }
        }
        __syncthreads();
    }

    {   // conv4: K=128 ([conv3 | per-node rowmax]), co 128 (wave owns 32)
        const u16* Wp = Wbf + 10240 + (size_t)(wave * 32) * 128;
        bf16x8 bw[2][4];
#pragma unroll
        for (int cf = 0; cf < 2; ++cf)
#pragma unroll
            for (int ks = 0; ks < 4; ++ks)
                bw[cf][ks] = ldW(Wp + (size_t)cf * 16 * 128, ks, l15, quad, 128);
        floatx4 c[8][2] = {};
#pragma unroll
        for (int ks = 0; ks < 4; ++ks)
#pragma unroll
            for (int rf = 0; rf < 8; ++rf) {
                bf16x8 a = (ks < 2) ? ldsA(act, rf, l15, quad, ks)
                                    : *(const bf16x8*)(&mv[rf >> 2][(ks - 2) * 32 + quad * 8]);
#pragma unroll
                for (int cf = 0; cf < 2; ++cf)
                    c[rf][cf] = __builtin_amdgcn_mfma_f32_16x16x32_bf16(a, bw[cf][ks], c[rf][cf], 0, 0, 0);
            }
        float bias[2];
#pragma unroll
        for (int cf = 0; cf < 2; ++cf) bias[cf] = b4[wave * 32 + cf * 16 + l15];
        __syncthreads();
#pragma unroll
        for (int rf = 0; rf < 8; ++rf)
#pragma unroll
            for (int cf = 0; cf < 2; ++cf)
#pragma unroll
                for (int r = 0; r < 4; ++r)
                    act[(rf * 16 + quad * 4 + r) * RS + wave * 32 + cf * 16 + l15] =
                        f2bf(fmaxf(c[rf][cf][r] + bias[cf], 0.0f));
        __syncthreads();
    }

    {   // conv5 + per-node maxpool -> h[bm][0:128]
        const u16* Wp = Wbf + 26624 + (size_t)(wave * 32) * 128;
        bf16x8 bw[2][4];
#pragma unroll
        for (int cf = 0; cf < 2; ++cf)
#pragma unroll
            for (int ks = 0; ks < 4; ++ks)
                bw[cf][ks] = ldW(Wp + (size_t)cf * 16 * 128, ks, l15, quad, 128);
        floatx4 c[8][2] = {};
#pragma unroll
        for (int ks = 0; ks < 4; ++ks)
#pragma unroll
            for (int rf = 0; rf < 8; ++rf) {
                bf16x8 a = ldsA(act, rf, l15, quad, ks);
#pragma unroll
                for (int cf = 0; cf < 2; ++cf)
                    c[rf][cf] = __builtin_amdgcn_mfma_f32_16x16x32_bf16(a, bw[cf][ks], c[rf][cf], 0, 0, 0);
            }
#pragma unroll
        for (int cf = 0; cf < 2; ++cf) {
            float bias = b5[wave * 32 + cf * 16 + l15];
            float mxA = 0.0f, mxB = 0.0f;
#pragma unroll
            for (int rf = 0; rf < 8; ++rf)
#pragma unroll
                for (int r = 0; r < 4; ++r) {
                    float v = fmaxf(c[rf][cf][r] + bias, 0.0f);
                    if (rf < 4) mxA = fmaxf(mxA, v); else mxB = fmaxf(mxB, v);
                }
            mxA = fmaxf(mxA, __shfl_xor(mxA, 16));
            mxA = fmaxf(mxA, __shfl_xor(mxA, 32));
            mxB = fmaxf(mxB, __shfl_xor(mxB, 16));
            mxB = fmaxf(mxB, __shfl_xor(mxB, 32));
            if (quad == 0) {
                h[(size_t)bm0 * 640 + wave * 32 + cf * 16 + l15] = f2bf(mxA);
                h[(size_t)(bm0 + 1) * 640 + wave * 32 + cf * 16 + l15] = f2bf(mxB);
            }
        }
    }
}

// ---------------------------------------------------------------------------
// Generic in-LDS in-place conv step. act tile: (RF*16) rows x RSx u16 cols.
// Wave owns out cols [cb, cb+CF*16). Weights stream from L2 (reg ping-pong).
// ---------------------------------------------------------------------------
template <int KS, int CF, int RF, int RSx>
__device__ __forceinline__ void conv_inplace(u16* act, const u16* __restrict__ W0, int KP,
                                             const float* __restrict__ bias, int cb,
                                             int l15, int quad) {
    floatx4 acc[RF][CF];
#pragma unroll
    for (int rf = 0; rf < RF; ++rf)
#pragma unroll
        for (int cf = 0; cf < CF; ++cf) acc[rf][cf] = (floatx4){0.f, 0.f, 0.f, 0.f};

    bf16x8 bwA[CF], bwB[CF];
#pragma unroll
    for (int cf = 0; cf < CF; ++cf)
        bwA[cf] = *(const bf16x8*)(W0 + (size_t)(cb + cf * 16 + l15) * KP + quad * 8);

#pragma unroll
    for (int ks = 0; ks < KS; ++ks) {
        bf16x8* cur = (ks % 2 == 0) ? bwA : bwB;
        bf16x8* nxt = (ks % 2 == 0) ? bwB : bwA;
        if (ks + 1 < KS) {
#pragma unroll
            for (int cf = 0; cf < CF; ++cf)
                nxt[cf] = *(const bf16x8*)(W0 + (size_t)(cb + cf * 16 + l15) * KP +
                                           (ks + 1) * 32 + quad * 8);
        }
#pragma unroll
        for (int rf = 0; rf < RF; ++rf) {
            bf16x8 a = *(const bf16x8*)(act + (rf * 16 + l15) * RSx + ks * 32 + quad * 8);
#pragma unroll
            for (int cf = 0; cf < CF; ++cf)
                acc[rf][cf] = __builtin_amdgcn_mfma_f32_16x16x32_bf16(a, cur[cf], acc[rf][cf], 0, 0, 0);
        }
    }
    __syncthreads();   // all waves' reads complete before in-place writes
#pragma unroll
    for (int cf = 0; cf < CF; ++cf) {
        float bs = bias[cb + cf * 16 + l15];
#pragma unroll
        for (int rf = 0; rf < RF; ++rf)
#pragma unroll
            for (int r = 0; r < 4; ++r)
                act[(rf * 16 + quad * 4 + r) * RSx + cb + cf * 16 + l15] =
                    f2bf(fmaxf(acc[rf][cf][r] + bs, 0.0f));
    }
    __syncthreads();
}

// ---------------------------------------------------------------------------
// Fused stage 2: one block per 8 nodes, 1024 threads (16 waves = 4/SIMD).
// K-layout: [coords 0..2 | pad | feat1 8..135 | pad..159] (weights permuted).
// ---------------------------------------------------------------------------
static constexpr int RS2 = 520;

__global__ __launch_bounds__(1024, 4) void fused_stage2_kernel(
    const float* __restrict__ node, u16* __restrict__ h, const int* __restrict__ knn,
    const u16* __restrict__ Wbf,
    const float* __restrict__ bb1, const float* __restrict__ bb2,
    const float* __restrict__ bb3, const float* __restrict__ ba1,
    const float* __restrict__ ba2) {
    __shared__ __align__(16) u16 act[80 * RS2];   // 83,200 B
    int blk = blockIdx.x;              // 0..255
    int node0 = blk * 8;
    int b = node0 >> 9;
    int tid = threadIdx.x, wave = tid >> 6, lane = tid & 63;
    int quad = lane >> 4, l15 = lane & 15;
    (void)lane;

    // zero cols 0..159 of all 80 rows
    for (int e = tid; e < 80 * 20; e += 1024)
        *(u16x8*)(act + (e / 20) * RS2 + (e % 20) * 8) = (u16x8){0,0,0,0,0,0,0,0};
    __syncthreads();
    // coords -> cols 0..2
    for (int e = tid; e < 72 * 3; e += 1024) {
        int r = e / 3, c = e - r * 3;
        int nodei = node0 + r / 9;
        int j = knn[(size_t)nodei * 9 + (r % 9)];
        float v = node[((size_t)b * 3 + c) * M_ + j] - node[((size_t)b * 3 + c) * M_ + (nodei & 511)];
        act[r * RS2 + c] = f2bf(v);
    }
    // feat1 -> cols 8..135 (16B-aligned vector copies)
    for (int e = tid; e < 72 * 16; e += 1024) {
        int r = e >> 4, s = e & 15;
        int nodei = node0 + r / 9;
        int j = knn[(size_t)nodei * 9 + (r % 9)];
        *(u16x8*)(act + r * RS2 + 8 + s * 8) =
            *(const u16x8*)(h + (size_t)(b * 512 + j) * 640 + s * 8);
    }
    __syncthreads();

    // knnb1: K=160 -> 256 ; knnb2/3: 256 -> 256 (wave owns 16 cols)
    conv_inplace<5, 1, 5, RS2>(act, Wbf + 43008, 160, bb1, wave * 16, l15, quad);
    conv_inplace<8, 1, 5, RS2>(act, Wbf + 83968, 256, bb2, wave * 16, l15, quad);
    conv_inplace<8, 1, 5, RS2>(act, Wbf + 149504, 256, bb3, wave * 16, l15, quad);

    // gmax: per node max over 9 rows of cols 0..255 -> bcast cols 256..511
    for (int e = tid; e < 8 * 32; e += 1024) {
        int li = e >> 5, s = e & 31;
        int r0 = li * 9;
        float mx[8];
#pragma unroll
        for (int i = 0; i < 8; ++i) mx[i] = -3.0e38f;
#pragma unroll
        for (int kk = 0; kk < 9; ++kk) {
            u16x8 v = *(const u16x8*)(act + (r0 + kk) * RS2 + s * 8);
#pragma unroll
            for (int i = 0; i < 8; ++i) mx[i] = fmaxf(mx[i], bf2f(v[i]));
        }
        u16x8 o;
#pragma unroll
        for (int i = 0; i < 8; ++i) o[i] = f2bf(mx[i]);
#pragma unroll
        for (int kk = 0; kk < 9; ++kk)
            *(u16x8*)(act + (r0 + kk) * RS2 + 256 + s * 8) = o;
    }
    __syncthreads();

    // knna1/2: K=512 -> 512 (wave owns 32 cols)
    conv_inplace<16, 2, 5, RS2>(act, Wbf + 215040, 512, ba1, wave * 32, l15, quad);
    conv_inplace<16, 2, 5, RS2>(act, Wbf + 477184, 512, ba2, wave * 32, l15, quad);

    // pool: per node max over 9 rows -> h[nodei][128..639]
    for (int e = tid; e < 8 * 64; e += 1024) {
        int li = e >> 6, s = e & 63;
        int r0 = li * 9;
        float mx[8];
#pragma unroll
        for (int i = 0; i < 8; ++i) mx[i] = -3.0e38f;
#pragma unroll
        for (int kk = 0; kk < 9; ++kk) {
            u16x8 v = *(const u16x8*)(act + (r0 + kk) * RS2 + s * 8);
#pragma unroll
            for (int i = 0; i < 8; ++i) mx[i] = fmaxf(mx[i], bf2f(v[i]));
        }
        u16x8 o;
#pragma unroll
        for (int i = 0; i < 8; ++i) o[i] = f2bf(mx[i]);
        *(u16x8*)(h + (size_t)(node0 + li) * 640 + 128 + s * 8) = o;
    }
}

// ---------------------------------------------------------------------------
// Fused stage 3: 256 blocks x 8 nodes, 512 threads (8 waves).
// mlp1(640->512) -> mlp2(512->256) -> mlp3(256->4 fp32) -> epilogue.
// ---------------------------------------------------------------------------
static constexpr int RS3 = 648;

__global__ __launch_bounds__(512, 2) void fused_stage3_kernel(
    const float* __restrict__ node, const u16* __restrict__ h,
    const u16* __restrict__ Wbf,
    const float* __restrict__ bm1, const float* __restrict__ bm2,
    const float* __restrict__ w3, const float* __restrict__ b3,
    float* __restrict__ out) {
    __shared__ __align__(16) u16 act[16 * RS3];   // 20,736 B
    int blk = blockIdx.x;              // 0..255
    int node0 = blk * 8;
    int tid = threadIdx.x, lane = tid & 63, wave = tid >> 6;
    int quad = lane >> 4, l15 = lane & 15;

    for (int e = tid; e < 16 * 80; e += 512) {
        int r = e / 80, seg = e - r * 80;
        u16x8 v = (r < 8) ? *(const u16x8*)(h + (size_t)(node0 + r) * 640 + seg * 8)
                          : (u16x8){0,0,0,0,0,0,0,0};
        *(u16x8*)(act + r * RS3 + seg * 8) = v;
    }
    __syncthreads();

    // mlp1: K=640 -> 512 (wave owns 64 cols); mlp2: K=512 -> 256 (32 cols)
    conv_inplace<20, 4, 1, RS3>(act, Wbf + 739328, 640, bm1, wave * 64, l15, quad);
    conv_inplace<16, 2, 1, RS3>(act, Wbf + 1067008, 512, bm2, wave * 32, l15, quad);

    // mlp3 + epilogue: thread t<32 -> node li = t/4, output oc = t%4
    if (tid < 32) {
        int li = tid >> 2, oc = tid & 3;
        const u16* row = act + li * RS3;
        const float* wrow = w3 + oc * 256;
        float a = 0.0f;
        for (int c = 0; c < 256; c += 4) {
            a += bf2f(row[c]) * wrow[c];
            a += bf2f(row[c + 1]) * wrow[c + 1];
            a += bf2f(row[c + 2]) * wrow[c + 2];
            a += bf2f(row[c + 3]) * wrow[c + 3];
        }
        a += b3[oc];
        int nodei = node0 + li;
        int b = nodei >> 9, m = nodei & 511;
        if (oc < 3) {
            float nv = node[((size_t)b * 3 + oc) * M_ + m];
            out[((size_t)b * 3 + oc) * M_ + m] = nv;
            out[6144 + ((size_t)b * 3 + oc) * M_ + m] = nv + a;
        } else {
            out[12288 + nodei] = fmaxf(a, 0.0f) + log1pf(expf(-fabsf(a))) + 0.001f;
        }
    }
}

// ---------------------------------------------------------------------------
extern "C" void kernel_launch(void* const* d_in, const int* in_sizes, int n_in,
                              void* d_out, int out_size, void* d_ws, size_t ws_size,
                              hipStream_t stream) {
    (void)in_sizes; (void)n_in; (void)out_size; (void)ws_size;
    const float* x = (const float*)d_in[0];
    const float* sn = (const float*)d_in[1];
    const float* node = (const float*)d_in[2];
    const float* W[13];
    const float* Bs[13];
    for (int i = 0; i < 13; ++i) {
        W[i] = (const float*)d_in[3 + 2 * i];
        Bs[i] = (const float*)d_in[4 + 2 * i];
    }
    float* out = (float*)d_out;

    char* ws = (char*)d_ws;
    int* idx = (int*)(ws + 0);                 //   524,288
    int* knn = (int*)(ws + 524288);            //    73,728
    u16* Wbf = (u16*)(ws + 598016);            // 2,396,160
    u16* h   = (u16*)(ws + 2994176);           // 2,621,440 (2048 x 640)
    float4* pk = (float4*)(ws + 5615616);      // 1,048,576

    WConvArgs wa;
    for (int w = 0; w < 12; ++w) wa.src[w] = W[w];
    convert_weights_kernel<<<(1198080 + 255) / 256, 256, 0, stream>>>(wa, Wbf);

    pack_x_kernel<<<256, 256, 0, stream>>>(x, pk);
    ball_query_kernel<<<2048, 256, 0, stream>>>(pk, node, idx);
    knn_kernel<<<2048, 64, 0, stream>>>(node, knn);

    fused_stage1_kernel<<<1024, 256, 0, stream>>>(x, sn, node, idx, Wbf,
                                                  Bs[0], Bs[1], Bs[2], Bs[3], Bs[4], h);
    fused_stage2_kernel<<<256, 1024, 0, stream>>>(node, h, knn, Wbf,
                                                  Bs[5], Bs[6], Bs[7], Bs[8], Bs[9]);
    fused_stage3_kernel<<<256, 512, 0, stream>>>(node, h, Wbf, Bs[10], Bs[11],
                                                 W[12], Bs[12], out);
}

// Round 7
// 248.761 us; speedup vs baseline: 7.7460x; 1.0354x over previous
//
#include <hip/hip_runtime.h>

typedef unsigned short u16;
typedef unsigned int u32;
typedef __bf16 bf16x8 __attribute__((ext_vector_type(8)));
typedef float floatx4 __attribute__((ext_vector_type(4)));
typedef unsigned short u16x8 __attribute__((ext_vector_type(8)));
typedef unsigned int u32x4 __attribute__((ext_vector_type(4)));

static constexpr int B_ = 4;
static constexpr int N_ = 16384;
static constexpr int M_ = 512;

__device__ __forceinline__ u16 f2bf(float f) {
    u32 u = __float_as_uint(f);
    u32 r = (u + 0x7fffu + ((u >> 16) & 1u)) >> 16;
    return (u16)r;
}
__device__ __forceinline__ float bf2f(u16 x) {
    return __uint_as_float(((u32)x) << 16);
}
__device__ __forceinline__ u32 pack2(float a, float b) {
    return (u32)f2bf(a) | ((u32)f2bf(b) << 16);
}

struct WConvArgs { const float* src[12]; };

// ---------------------------------------------------------------------------
// prep_kernel: blocks [0,2048) ball query; [2048,2560) knn (4 nodes/block);
// [2560,7240) weight fp32->bf16 conversion. All parts independent.
// ---------------------------------------------------------------------------
__global__ __launch_bounds__(256) void prep_kernel(
    const float* __restrict__ x, const float* __restrict__ node,
    int* __restrict__ idx, int* __restrict__ knn,
    WConvArgs wa, u16* __restrict__ Wbf) {
    int bid = blockIdx.x;
    int tid = threadIdx.x, wave = tid >> 6, lane = tid & 63;

    if (bid < 2048) {
        // ---- ball query: 4 waves per (b,m); early exit when 64 slots full ----
        int bm = bid;
        int b = bm >> 9, m = bm & 511;
        __shared__ int sidx[4][64];
        __shared__ int scnt[4];
        const float* xb = x + (size_t)b * 3 * N_;
        float nx = node[((size_t)b * 3 + 0) * M_ + m];
        float ny = node[((size_t)b * 3 + 1) * M_ + m];
        float nz = node[((size_t)b * 3 + 2) * M_ + m];
        float aa = nx * nx + ny * ny + nz * nz;
        int cnt = 0;
        int base = wave * 4096;
        for (int n0 = base; n0 < base + 4096; n0 += 64) {
            int n = n0 + lane;
            float px = xb[n], py = xb[N_ + n], pz = xb[2 * N_ + n];
            float w = px * px + py * py + pz * pz;
            float d = aa + w - 2.0f * (nx * px + ny * py + nz * pz);
            bool inb = d < 4.0f;
            unsigned long long mask = __ballot(inb);
            if (inb && cnt < 64) {
                int pos = cnt + __popcll(mask & ((1ull << lane) - 1ull));
                if (pos < 64) sidx[wave][pos] = n;
            }
            cnt += __popcll(mask);
            if (cnt >= 64) break;   // wave-uniform
        }
        if (lane == 0) scnt[wave] = cnt;
        __syncthreads();
        if (tid < 64) {
            int total = scnt[0] + scnt[1] + scnt[2] + scnt[3];
            int v = 0;
            if (total > 0) {
                int lim = total < 64 ? total : 64;
                int slot = tid < lim ? tid : 0;
                int w = 0, pre = 0;
                while (w < 3 && slot >= pre + scnt[w]) { pre += scnt[w]; ++w; }
                v = sidx[w][slot - pre];
            }
            idx[(size_t)bm * 64 + tid] = v;
        }
    } else if (bid < 2560) {
        // ---- knn: wave handles node (bid-2048)*4 + wave ----
        int bm = (bid - 2048) * 4 + wave;
        int b = bm >> 9, m = bm & 511;
        const float* nb = node + (size_t)b * 3 * M_;
        float nx = nb[m], ny = nb[M_ + m], nz = nb[2 * M_ + m];
        float aa = nx * nx + ny * ny + nz * nz;
        float dist[8];
        int didx[8];
#pragma unroll
        for (int i = 0; i < 8; ++i) {
            int n = lane + i * 64;
            float px = nb[n], py = nb[M_ + n], pz = nb[2 * M_ + n];
            float bb = px * px + py * py + pz * pz;
            float ab = nx * px + ny * py + nz * pz;
            dist[i] = aa + bb - 2.0f * ab;
            didx[i] = n;
        }
        for (int r = 0; r < 9; ++r) {
            float bv = dist[0]; int bi = didx[0]; int bslot = 0;
#pragma unroll
            for (int i = 1; i < 8; ++i) {
                if (dist[i] < bv || (dist[i] == bv && didx[i] < bi)) {
                    bv = dist[i]; bi = didx[i]; bslot = i;
                }
            }
            float rv = bv; int ri = bi;
            for (int off = 32; off > 0; off >>= 1) {
                float ov = __shfl_down(rv, off);
                int   oi = __shfl_down(ri, off);
                if (ov < rv || (ov == rv && oi < ri)) { rv = ov; ri = oi; }
            }
            ri = __shfl(ri, 0);
            if (lane == 0) knn[(size_t)bm * 9 + r] = ri;
            if (bi == ri) dist[bslot] = 3.0e38f;
        }
    } else {
        // ---- weight conversion (segments are 256-aligned: block-uniform w) ----
        const int CI[12] = {6, 64, 64, 128, 128, 131, 256, 256, 512, 512, 640, 512};
        const int KP[12] = {32, 64, 64, 128, 128, 160, 256, 256, 512, 512, 640, 512};
        const int OFF[13] = {0, 2048, 6144, 10240, 26624, 43008, 83968, 149504,
                             215040, 477184, 739328, 1067008, 1198080};
        int e = (bid - 2560) * 256 + tid;
        int w = 0;
        while (e >= OFF[w + 1]) ++w;
        int local = e - OFF[w];
        int kp = KP[w];
        int co = local / kp, k = local - co * kp;
        float v = 0.0f;
        if (w == 5) {   // knnb1 K-layout: 0..2 coords, 8..135 feat1
            if (k < 3) v = wa.src[5][(size_t)co * 131 + k];
            else if (k >= 8 && k < 136) v = wa.src[5][(size_t)co * 131 + (k - 5)];
        } else if (k < CI[w]) {
            v = wa.src[w][(size_t)co * CI[w] + k];
        }
        Wbf[e] = f2bf(v);
    }
}

// ---------------------------------------------------------------------------
// Fused stage 1: one block per 2 nodes (128 rows), 256 threads, 3 blocks/CU.
// ---------------------------------------------------------------------------
static constexpr int RS = 136;

__device__ __forceinline__ bf16x8 ldsA(const u16* act, int rf, int l15, int quad, int ks) {
    return *(const bf16x8*)(act + (rf * 16 + l15) * RS + ks * 32 + quad * 8);
}
__device__ __forceinline__ bf16x8 ldW(const u16* W, int ks, int l15, int quad, int kstride) {
    return *(const bf16x8*)(W + (size_t)l15 * kstride + ks * 32 + quad * 8);
}

__global__ __launch_bounds__(256, 3) void fused_stage1_kernel(
    const float* __restrict__ x, const float* __restrict__ sn,
    const float* __restrict__ node, const int* __restrict__ idx,
    const u16* __restrict__ Wbf,
    const float* __restrict__ b1, const float* __restrict__ b2,
    const float* __restrict__ b3, const float* __restrict__ b4,
    const float* __restrict__ b5, u16* __restrict__ h) {
    __shared__ __align__(16) u16 act[128 * RS];   // 34,816 B
    __shared__ __align__(16) u16 mv[2][64];
    int blk = blockIdx.x;              // 0..1023
    int bm0 = blk * 2;
    int tid = threadIdx.x, wave = tid >> 6, lane = tid & 63;
    int quad = lane >> 4, l15 = lane & 15;

    {   // gather 2 nodes x 64 neighbors
        int row = tid & 127, grp = tid >> 7;
        int bm = bm0 + (row >> 6);
        int b = bm >> 9, m = bm & 511;
        int j = idx[(size_t)bm * 64 + (row & 63)];
        const float* xb = x + (size_t)b * 3 * N_;
        const float* sb = sn + (size_t)b * 3 * N_;
        u16* r = act + row * RS;
        if (grp == 0) {
            float c0 = xb[j]          - node[((size_t)b * 3 + 0) * M_ + m];
            float c1 = xb[N_ + j]     - node[((size_t)b * 3 + 1) * M_ + m];
            float c2 = xb[2 * N_ + j] - node[((size_t)b * 3 + 2) * M_ + m];
            *(u32*)(r)     = pack2(c0, c1);
            *(u32*)(r + 2) = pack2(c2, sb[j]);
        } else {
            *(u32*)(r + 4) = pack2(sb[N_ + j], sb[2 * N_ + j]);
            *(u32*)(r + 6) = 0u;
            u32x4* z = (u32x4*)(r + 8);
            z[0] = (u32x4){0u, 0u, 0u, 0u};
            z[1] = (u32x4){0u, 0u, 0u, 0u};
            z[2] = (u32x4){0u, 0u, 0u, 0u};
        }
    }
    __syncthreads();

    {   // conv1: K=32 (6 used), co 64 (wave owns 16)
        const u16* Wp = Wbf + (size_t)(wave * 16) * 32;
        bf16x8 bw = ldW(Wp, 0, l15, quad, 32);
        floatx4 c[8];
#pragma unroll
        for (int rf = 0; rf < 8; ++rf) {
            bf16x8 a = ldsA(act, rf, l15, quad, 0);
            c[rf] = __builtin_amdgcn_mfma_f32_16x16x32_bf16(a, bw, (floatx4){0.f,0.f,0.f,0.f}, 0, 0, 0);
        }
        float bias = b1[wave * 16 + l15];
        __syncthreads();
#pragma unroll
        for (int rf = 0; rf < 8; ++rf)
#pragma unroll
            for (int r = 0; r < 4; ++r)
                act[(rf * 16 + quad * 4 + r) * RS + wave * 16 + l15] = f2bf(fmaxf(c[rf][r] + bias, 0.0f));
        __syncthreads();
    }

    const int WOFF23[2] = {2048, 6144};
    const float* bp23[2] = {b2, b3};
#pragma unroll 1
    for (int cv = 0; cv < 2; ++cv) {   // conv2 / conv3: K=64, co 64
        const u16* Wp = Wbf + WOFF23[cv] + (size_t)(wave * 16) * 64;
        bf16x8 bw0 = ldW(Wp, 0, l15, quad, 64);
        bf16x8 bw1 = ldW(Wp, 1, l15, quad, 64);
        floatx4 c[8] = {};
#pragma unroll
        for (int ks = 0; ks < 2; ++ks)
#pragma unroll
            for (int rf = 0; rf < 8; ++rf) {
                bf16x8 a = ldsA(act, rf, l15, quad, ks);
                c[rf] = __builtin_amdgcn_mfma_f32_16x16x32_bf16(a, ks ? bw1 : bw0, c[rf], 0, 0, 0);
            }
        float bias = bp23[cv][wave * 16 + l15];
        float mxA = 0.0f, mxB = 0.0f;
#pragma unroll
        for (int rf = 0; rf < 8; ++rf)
#pragma unroll
            for (int r = 0; r < 4; ++r) {
                float v = fmaxf(c[rf][r] + bias, 0.0f);
                if (rf < 4) mxA = fmaxf(mxA, v); else mxB = fmaxf(mxB, v);
            }
        __syncthreads();
#pragma unroll
        for (int rf = 0; rf < 8; ++rf)
#pragma unroll
            for (int r = 0; r < 4; ++r)
                act[(rf * 16 + quad * 4 + r) * RS + wave * 16 + l15] = f2bf(fmaxf(c[rf][r] + bias, 0.0f));
        if (cv == 1) {
            mxA = fmaxf(mxA, __shfl_xor(mxA, 16));
            mxA = fmaxf(mxA, __shfl_xor(mxA, 32));
            mxB = fmaxf(mxB, __shfl_xor(mxB, 16));
            mxB = fmaxf(mxB, __shfl_xor(mxB, 32));
            if (quad == 0) {
                mv[0][wave * 16 + l15] = f2bf(mxA);
                mv[1][wave * 16 + l15] = f2bf(mxB);
            }
        }
        __syncthreads();
    }

    {   // conv4: K=128 ([conv3 | per-node rowmax]), co 128 (wave owns 32)
        const u16* Wp = Wbf + 10240 + (size_t)(wave * 32) * 128;
        bf16x8 bw[2][4];
#pragma unroll
        for (int cf = 0; cf < 2; ++cf)
#pragma unroll
            for (int ks = 0; ks < 4; ++ks)
                bw[cf][ks] = ldW(Wp + (size_t)cf * 16 * 128, ks, l15, quad, 128);
        floatx4 c[8][2] = {};
#pragma unroll
        for (int ks = 0; ks < 4; ++ks)
#pragma unroll
            for (int rf = 0; rf < 8; ++rf) {
                bf16x8 a = (ks < 2) ? ldsA(act, rf, l15, quad, ks)
                                    : *(const bf16x8*)(&mv[rf >> 2][(ks - 2) * 32 + quad * 8]);
#pragma unroll
                for (int cf = 0; cf < 2; ++cf)
                    c[rf][cf] = __builtin_amdgcn_mfma_f32_16x16x32_bf16(a, bw[cf][ks], c[rf][cf], 0, 0, 0);
            }
        float bias[2];
#pragma unroll
        for (int cf = 0; cf < 2; ++cf) bias[cf] = b4[wave * 32 + cf * 16 + l15];
        __syncthreads();
#pragma unroll
        for (int rf = 0; rf < 8; ++rf)
#pragma unroll
            for (int cf = 0; cf < 2; ++cf)
#pragma unroll
                for (int r = 0; r < 4; ++r)
                    act[(rf * 16 + quad * 4 + r) * RS + wave * 32 + cf * 16 + l15] =
                        f2bf(fmaxf(c[rf][cf][r] + bias[cf], 0.0f));
        __syncthreads();
    }

    {   // conv5 + per-node maxpool -> h[bm][0:128]
        const u16* Wp = Wbf + 26624 + (size_t)(wave * 32) * 128;
        bf16x8 bw[2][4];
#pragma unroll
        for (int cf = 0; cf < 2; ++cf)
#pragma unroll
            for (int ks = 0; ks < 4; ++ks)
                bw[cf][ks] = ldW(Wp + (size_t)cf * 16 * 128, ks, l15, quad, 128);
        floatx4 c[8][2] = {};
#pragma unroll
        for (int ks = 0; ks < 4; ++ks)
#pragma unroll
            for (int rf = 0; rf < 8; ++rf) {
                bf16x8 a = ldsA(act, rf, l15, quad, ks);
#pragma unroll
                for (int cf = 0; cf < 2; ++cf)
                    c[rf][cf] = __builtin_amdgcn_mfma_f32_16x16x32_bf16(a, bw[cf][ks], c[rf][cf], 0, 0, 0);
            }
#pragma unroll
        for (int cf = 0; cf < 2; ++cf) {
            float bias = b5[wave * 32 + cf * 16 + l15];
            float mxA = 0.0f, mxB = 0.0f;
#pragma unroll
            for (int rf = 0; rf < 8; ++rf)
#pragma unroll
                for (int r = 0; r < 4; ++r) {
                    float v = fmaxf(c[rf][cf][r] + bias, 0.0f);
                    if (rf < 4) mxA = fmaxf(mxA, v); else mxB = fmaxf(mxB, v);
                }
            mxA = fmaxf(mxA, __shfl_xor(mxA, 16));
            mxA = fmaxf(mxA, __shfl_xor(mxA, 32));
            mxB = fmaxf(mxB, __shfl_xor(mxB, 16));
            mxB = fmaxf(mxB, __shfl_xor(mxB, 32));
            if (quad == 0) {
                h[(size_t)bm0 * 640 + wave * 32 + cf * 16 + l15] = f2bf(mxA);
                h[(size_t)(bm0 + 1) * 640 + wave * 32 + cf * 16 + l15] = f2bf(mxB);
            }
        }
    }
}

// ---------------------------------------------------------------------------
// In-LDS in-place conv with 4-deep weight prefetch (3 k-steps ahead in flight).
// act tile: (RF*16) rows x RSx u16 cols. Wave owns out cols [cb, cb+CF*16).
// ---------------------------------------------------------------------------
template <int KS, int CF, int RF, int RSx>
__device__ __forceinline__ void conv_inplace(u16* act, const u16* __restrict__ W0, int KP,
                                             const float* __restrict__ bias, int cb,
                                             int l15, int quad) {
    floatx4 acc[RF][CF];
#pragma unroll
    for (int rf = 0; rf < RF; ++rf)
#pragma unroll
        for (int cf = 0; cf < CF; ++cf) acc[rf][cf] = (floatx4){0.f, 0.f, 0.f, 0.f};

    bf16x8 bw[4][CF];
#pragma unroll
    for (int p = 0; p < 3; ++p)
        if (p < KS)
#pragma unroll
            for (int cf = 0; cf < CF; ++cf)
                bw[p][cf] = *(const bf16x8*)(W0 + (size_t)(cb + cf * 16 + l15) * KP +
                                             p * 32 + quad * 8);

#pragma unroll
    for (int ks = 0; ks < KS; ++ks) {
        if (ks + 3 < KS) {
#pragma unroll
            for (int cf = 0; cf < CF; ++cf)
                bw[(ks + 3) & 3][cf] = *(const bf16x8*)(W0 + (size_t)(cb + cf * 16 + l15) * KP +
                                                        (ks + 3) * 32 + quad * 8);
        }
#pragma unroll
        for (int rf = 0; rf < RF; ++rf) {
            bf16x8 a = *(const bf16x8*)(act + (rf * 16 + l15) * RSx + ks * 32 + quad * 8);
#pragma unroll
            for (int cf = 0; cf < CF; ++cf)
                acc[rf][cf] = __builtin_amdgcn_mfma_f32_16x16x32_bf16(a, bw[ks & 3][cf], acc[rf][cf], 0, 0, 0);
        }
    }
    __syncthreads();   // all waves' reads complete before in-place writes
#pragma unroll
    for (int cf = 0; cf < CF; ++cf) {
        float bs = bias[cb + cf * 16 + l15];
#pragma unroll
        for (int rf = 0; rf < RF; ++rf)
#pragma unroll
            for (int r = 0; r < 4; ++r)
                act[(rf * 16 + quad * 4 + r) * RSx + cb + cf * 16 + l15] =
                    f2bf(fmaxf(acc[rf][cf][r] + bs, 0.0f));
    }
    __syncthreads();
}

// ---------------------------------------------------------------------------
// Fused stage 2: one block per 8 nodes, 1024 threads (16 waves = 4/SIMD).
// K-layout: [coords 0..2 | pad | feat1 8..135 | pad..159] (weights permuted).
// ---------------------------------------------------------------------------
static constexpr int RS2 = 520;

__global__ __launch_bounds__(1024, 4) void fused_stage2_kernel(
    const float* __restrict__ node, u16* __restrict__ h, const int* __restrict__ knn,
    const u16* __restrict__ Wbf,
    const float* __restrict__ bb1, const float* __restrict__ bb2,
    const float* __restrict__ bb3, const float* __restrict__ ba1,
    const float* __restrict__ ba2) {
    __shared__ __align__(16) u16 act[80 * RS2];   // 83,200 B
    int blk = blockIdx.x;              // 0..255
    int node0 = blk * 8;
    int b = node0 >> 9;
    int tid = threadIdx.x, wave = tid >> 6, lane = tid & 63;
    int quad = lane >> 4, l15 = lane & 15;
    (void)lane;

    for (int e = tid; e < 80 * 20; e += 1024)
        *(u16x8*)(act + (e / 20) * RS2 + (e % 20) * 8) = (u16x8){0,0,0,0,0,0,0,0};
    __syncthreads();
    for (int e = tid; e < 72 * 3; e += 1024) {
        int r = e / 3, c = e - r * 3;
        int nodei = node0 + r / 9;
        int j = knn[(size_t)nodei * 9 + (r % 9)];
        float v = node[((size_t)b * 3 + c) * M_ + j] - node[((size_t)b * 3 + c) * M_ + (nodei & 511)];
        act[r * RS2 + c] = f2bf(v);
    }
    for (int e = tid; e < 72 * 16; e += 1024) {
        int r = e >> 4, s = e & 15;
        int nodei = node0 + r / 9;
        int j = knn[(size_t)nodei * 9 + (r % 9)];
        *(u16x8*)(act + r * RS2 + 8 + s * 8) =
            *(const u16x8*)(h + (size_t)(b * 512 + j) * 640 + s * 8);
    }
    __syncthreads();

    conv_inplace<5, 1, 5, RS2>(act, Wbf + 43008, 160, bb1, wave * 16, l15, quad);
    conv_inplace<8, 1, 5, RS2>(act, Wbf + 83968, 256, bb2, wave * 16, l15, quad);
    conv_inplace<8, 1, 5, RS2>(act, Wbf + 149504, 256, bb3, wave * 16, l15, quad);

    for (int e = tid; e < 8 * 32; e += 1024) {
        int li = e >> 5, s = e & 31;
        int r0 = li * 9;
        float mx[8];
#pragma unroll
        for (int i = 0; i < 8; ++i) mx[i] = -3.0e38f;
#pragma unroll
        for (int kk = 0; kk < 9; ++kk) {
            u16x8 v = *(const u16x8*)(act + (r0 + kk) * RS2 + s * 8);
#pragma unroll
            for (int i = 0; i < 8; ++i) mx[i] = fmaxf(mx[i], bf2f(v[i]));
        }
        u16x8 o;
#pragma unroll
        for (int i = 0; i < 8; ++i) o[i] = f2bf(mx[i]);
#pragma unroll
        for (int kk = 0; kk < 9; ++kk)
            *(u16x8*)(act + (r0 + kk) * RS2 + 256 + s * 8) = o;
    }
    __syncthreads();

    conv_inplace<16, 2, 5, RS2>(act, Wbf + 215040, 512, ba1, wave * 32, l15, quad);
    conv_inplace<16, 2, 5, RS2>(act, Wbf + 477184, 512, ba2, wave * 32, l15, quad);

    for (int e = tid; e < 8 * 64; e += 1024) {
        int li = e >> 6, s = e & 63;
        int r0 = li * 9;
        float mx[8];
#pragma unroll
        for (int i = 0; i < 8; ++i) mx[i] = -3.0e38f;
#pragma unroll
        for (int kk = 0; kk < 9; ++kk) {
            u16x8 v = *(const u16x8*)(act + (r0 + kk) * RS2 + s * 8);
#pragma unroll
            for (int i = 0; i < 8; ++i) mx[i] = fmaxf(mx[i], bf2f(v[i]));
        }
        u16x8 o;
#pragma unroll
        for (int i = 0; i < 8; ++i) o[i] = f2bf(mx[i]);
        *(u16x8*)(h + (size_t)(node0 + li) * 640 + 128 + s * 8) = o;
    }
}

// ---------------------------------------------------------------------------
// Fused stage 3: 256 blocks x 8 nodes, 512 threads (8 waves).
// ---------------------------------------------------------------------------
static constexpr int RS3 = 648;

__global__ __launch_bounds__(512, 2) void fused_stage3_kernel(
    const float* __restrict__ node, const u16* __restrict__ h,
    const u16* __restrict__ Wbf,
    const float* __restrict__ bm1, const float* __restrict__ bm2,
    const float* __restrict__ w3, const float* __restrict__ b3,
    float* __restrict__ out) {
    __shared__ __align__(16) u16 act[16 * RS3];   // 20,736 B
    int blk = blockIdx.x;              // 0..255
    int node0 = blk * 8;
    int tid = threadIdx.x, lane = tid & 63, wave = tid >> 6;
    int quad = lane >> 4, l15 = lane & 15;

    for (int e = tid; e < 16 * 80; e += 512) {
        int r = e / 80, seg = e - r * 80;
        u16x8 v = (r < 8) ? *(const u16x8*)(h + (size_t)(node0 + r) * 640 + seg * 8)
                          : (u16x8){0,0,0,0,0,0,0,0};
        *(u16x8*)(act + r * RS3 + seg * 8) = v;
    }
    __syncthreads();

    conv_inplace<20, 4, 1, RS3>(act, Wbf + 739328, 640, bm1, wave * 64, l15, quad);
    conv_inplace<16, 2, 1, RS3>(act, Wbf + 1067008, 512, bm2, wave * 32, l15, quad);

    if (tid < 32) {
        int li = tid >> 2, oc = tid & 3;
        const u16* row = act + li * RS3;
        const float* wrow = w3 + oc * 256;
        float a = 0.0f;
        for (int c = 0; c < 256; c += 4) {
            a += bf2f(row[c]) * wrow[c];
            a += bf2f(row[c + 1]) * wrow[c + 1];
            a += bf2f(row[c + 2]) * wrow[c + 2];
            a += bf2f(row[c + 3]) * wrow[c + 3];
        }
        a += b3[oc];
        int nodei = node0 + li;
        int b = nodei >> 9, m = nodei & 511;
        if (oc < 3) {
            float nv = node[((size_t)b * 3 + oc) * M_ + m];
            out[((size_t)b * 3 + oc) * M_ + m] = nv;
            out[6144 + ((size_t)b * 3 + oc) * M_ + m] = nv + a;
        } else {
            out[12288 + nodei] = fmaxf(a, 0.0f) + log1pf(expf(-fabsf(a))) + 0.001f;
        }
    }
}

// ---------------------------------------------------------------------------
extern "C" void kernel_launch(void* const* d_in, const int* in_sizes, int n_in,
                              void* d_out, int out_size, void* d_ws, size_t ws_size,
                              hipStream_t stream) {
    (void)in_sizes; (void)n_in; (void)out_size; (void)ws_size;
    const float* x = (const float*)d_in[0];
    const float* sn = (const float*)d_in[1];
    const float* node = (const float*)d_in[2];
    const float* W[13];
    const float* Bs[13];
    for (int i = 0; i < 13; ++i) {
        W[i] = (const float*)d_in[3 + 2 * i];
        Bs[i] = (const float*)d_in[4 + 2 * i];
    }
    float* out = (float*)d_out;

    char* ws = (char*)d_ws;
    int* idx = (int*)(ws + 0);                 //   524,288
    int* knn = (int*)(ws + 524288);            //    73,728
    u16* Wbf = (u16*)(ws + 598016);            // 2,396,160
    u16* h   = (u16*)(ws + 2994176);           // 2,621,440 (2048 x 640)

    WConvArgs wa;
    for (int w = 0; w < 12; ++w) wa.src[w] = W[w];

    prep_kernel<<<7240, 256, 0, stream>>>(x, node, idx, knn, wa, Wbf);

    fused_stage1_kernel<<<1024, 256, 0, stream>>>(x, sn, node, idx, Wbf,
                                                  Bs[0], Bs[1], Bs[2], Bs[3], Bs[4], h);
    fused_stage2_kernel<<<256, 1024, 0, stream>>>(node, h, knn, Wbf,
                                                  Bs[5], Bs[6], Bs[7], Bs[8], Bs[9]);
    fused_stage3_kernel<<<256, 512, 0, stream>>>(node, h, Wbf, Bs[10], Bs[11],
                                                 W[12], Bs[12], out);
}

// Round 8
// 225.116 us; speedup vs baseline: 8.5596x; 1.1050x over previous
//
#include <hip/hip_runtime.h>

typedef unsigned short u16;
typedef unsigned int u32;
typedef __bf16 bf16x8 __attribute__((ext_vector_type(8)));
typedef float floatx4 __attribute__((ext_vector_type(4)));
typedef unsigned short u16x8 __attribute__((ext_vector_type(8)));
typedef unsigned int u32x4 __attribute__((ext_vector_type(4)));

static constexpr int B_ = 4;
static constexpr int N_ = 16384;
static constexpr int M_ = 512;

__device__ __forceinline__ u16 f2bf(float f) {
    u32 u = __float_as_uint(f);
    u32 r = (u + 0x7fffu + ((u >> 16) & 1u)) >> 16;
    return (u16)r;
}
__device__ __forceinline__ float bf2f(u16 x) {
    return __uint_as_float(((u32)x) << 16);
}
__device__ __forceinline__ u32 pack2(float a, float b) {
    return (u32)f2bf(a) | ((u32)f2bf(b) << 16);
}

struct WConvArgs { const float* src[12]; };

// ---------------------------------------------------------------------------
// prep_kernel: blocks [0,2048) ball query; [2048,2560) knn (4 nodes/block);
// [2560,7240) weight fp32->bf16 conversion. All parts independent.
// ---------------------------------------------------------------------------
__global__ __launch_bounds__(256) void prep_kernel(
    const float* __restrict__ x, const float* __restrict__ node,
    int* __restrict__ idx, int* __restrict__ knn,
    WConvArgs wa, u16* __restrict__ Wbf) {
    int bid = blockIdx.x;
    int tid = threadIdx.x, wave = tid >> 6, lane = tid & 63;

    if (bid < 2048) {
        // ---- ball query: 4 waves per (b,m); 4-iter batched loads ----
        int bm = bid;
        int b = bm >> 9, m = bm & 511;
        __shared__ int sidx[4][64];
        __shared__ int scnt[4];
        const float* xb = x + (size_t)b * 3 * N_;
        float nx = node[((size_t)b * 3 + 0) * M_ + m];
        float ny = node[((size_t)b * 3 + 1) * M_ + m];
        float nz = node[((size_t)b * 3 + 2) * M_ + m];
        float aa = nx * nx + ny * ny + nz * nz;
        int cnt = 0;
        int base = wave * 4096;
        for (int n0 = base; n0 < base + 4096; n0 += 256) {
            float px[4], py[4], pz[4];
#pragma unroll
            for (int i = 0; i < 4; ++i) {
                int n = n0 + i * 64 + lane;
                px[i] = xb[n]; py[i] = xb[N_ + n]; pz[i] = xb[2 * N_ + n];
            }
#pragma unroll
            for (int i = 0; i < 4; ++i) {
                float bb = px[i] * px[i] + py[i] * py[i] + pz[i] * pz[i];
                float d = aa + bb - 2.0f * (nx * px[i] + ny * py[i] + nz * pz[i]);
                bool inb = d < 4.0f;
                unsigned long long mask = __ballot(inb);
                if (inb && cnt < 64) {
                    int pos = cnt + __popcll(mask & ((1ull << lane) - 1ull));
                    if (pos < 64) sidx[wave][pos] = n0 + i * 64 + lane;
                }
                cnt += __popcll(mask);
            }
            if (cnt >= 64) break;   // wave-uniform; truncated counts stay >=64
        }
        if (lane == 0) scnt[wave] = cnt;
        __syncthreads();
        if (tid < 64) {
            int total = scnt[0] + scnt[1] + scnt[2] + scnt[3];
            int v = 0;
            if (total > 0) {
                int lim = total < 64 ? total : 64;
                int slot = tid < lim ? tid : 0;
                int w = 0, pre = 0;
                while (w < 3 && slot >= pre + scnt[w]) { pre += scnt[w]; ++w; }
                v = sidx[w][slot - pre];
            }
            idx[(size_t)bm * 64 + tid] = v;
        }
    } else if (bid < 2560) {
        // ---- knn: wave handles node (bid-2048)*4 + wave ----
        int bm = (bid - 2048) * 4 + wave;
        int b = bm >> 9, m = bm & 511;
        const float* nb = node + (size_t)b * 3 * M_;
        float nx = nb[m], ny = nb[M_ + m], nz = nb[2 * M_ + m];
        float aa = nx * nx + ny * ny + nz * nz;
        float dist[8];
        int didx[8];
#pragma unroll
        for (int i = 0; i < 8; ++i) {
            int n = lane + i * 64;
            float px = nb[n], py = nb[M_ + n], pz = nb[2 * M_ + n];
            float bb = px * px + py * py + pz * pz;
            float ab = nx * px + ny * py + nz * pz;
            dist[i] = aa + bb - 2.0f * ab;
            didx[i] = n;
        }
        for (int r = 0; r < 9; ++r) {
            float bv = dist[0]; int bi = didx[0]; int bslot = 0;
#pragma unroll
            for (int i = 1; i < 8; ++i) {
                if (dist[i] < bv || (dist[i] == bv && didx[i] < bi)) {
                    bv = dist[i]; bi = didx[i]; bslot = i;
                }
            }
            float rv = bv; int ri = bi;
            for (int off = 32; off > 0; off >>= 1) {
                float ov = __shfl_down(rv, off);
                int   oi = __shfl_down(ri, off);
                if (ov < rv || (ov == rv && oi < ri)) { rv = ov; ri = oi; }
            }
            ri = __shfl(ri, 0);
            if (lane == 0) knn[(size_t)bm * 9 + r] = ri;
            if (bi == ri) dist[bslot] = 3.0e38f;
        }
    } else {
        // ---- weight conversion ----
        const int CI[12] = {6, 64, 64, 128, 128, 131, 256, 256, 512, 512, 640, 512};
        const int KP[12] = {32, 64, 64, 128, 128, 160, 256, 256, 512, 512, 640, 512};
        const int OFF[13] = {0, 2048, 6144, 10240, 26624, 43008, 83968, 149504,
                             215040, 477184, 739328, 1067008, 1198080};
        int e = (bid - 2560) * 256 + tid;
        int w = 0;
        while (e >= OFF[w + 1]) ++w;
        int local = e - OFF[w];
        int kp = KP[w];
        int co = local / kp, k = local - co * kp;
        float v = 0.0f;
        if (w == 5) {   // knnb1 K-layout: 0..2 coords, 8..135 feat1
            if (k < 3) v = wa.src[5][(size_t)co * 131 + k];
            else if (k >= 8 && k < 136) v = wa.src[5][(size_t)co * 131 + (k - 5)];
        } else if (k < CI[w]) {
            v = wa.src[w][(size_t)co * CI[w] + k];
        }
        Wbf[e] = f2bf(v);
    }
}

// ---------------------------------------------------------------------------
// Fused stage 1: one block per 2 nodes (128 rows), 256 threads, 3 blocks/CU.
// ---------------------------------------------------------------------------
static constexpr int RS = 136;

__device__ __forceinline__ bf16x8 ldsA(const u16* act, int rf, int l15, int quad, int ks) {
    return *(const bf16x8*)(act + (rf * 16 + l15) * RS + ks * 32 + quad * 8);
}
__device__ __forceinline__ bf16x8 ldW(const u16* W, int ks, int l15, int quad, int kstride) {
    return *(const bf16x8*)(W + (size_t)l15 * kstride + ks * 32 + quad * 8);
}

__global__ __launch_bounds__(256, 3) void fused_stage1_kernel(
    const float* __restrict__ x, const float* __restrict__ sn,
    const float* __restrict__ node, const int* __restrict__ idx,
    const u16* __restrict__ Wbf,
    const float* __restrict__ b1, const float* __restrict__ b2,
    const float* __restrict__ b3, const float* __restrict__ b4,
    const float* __restrict__ b5, u16* __restrict__ h) {
    __shared__ __align__(16) u16 act[128 * RS];   // 34,816 B
    __shared__ __align__(16) u16 mv[2][64];
    int blk = blockIdx.x;              // 0..1023
    int bm0 = blk * 2;
    int tid = threadIdx.x, wave = tid >> 6, lane = tid & 63;
    int quad = lane >> 4, l15 = lane & 15;

    {   // gather 2 nodes x 64 neighbors
        int row = tid & 127, grp = tid >> 7;
        int bm = bm0 + (row >> 6);
        int b = bm >> 9, m = bm & 511;
        int j = idx[(size_t)bm * 64 + (row & 63)];
        const float* xb = x + (size_t)b * 3 * N_;
        const float* sb = sn + (size_t)b * 3 * N_;
        u16* r = act + row * RS;
        if (grp == 0) {
            float c0 = xb[j]          - node[((size_t)b * 3 + 0) * M_ + m];
            float c1 = xb[N_ + j]     - node[((size_t)b * 3 + 1) * M_ + m];
            float c2 = xb[2 * N_ + j] - node[((size_t)b * 3 + 2) * M_ + m];
            *(u32*)(r)     = pack2(c0, c1);
            *(u32*)(r + 2) = pack2(c2, sb[j]);
        } else {
            *(u32*)(r + 4) = pack2(sb[N_ + j], sb[2 * N_ + j]);
            *(u32*)(r + 6) = 0u;
            u32x4* z = (u32x4*)(r + 8);
            z[0] = (u32x4){0u, 0u, 0u, 0u};
            z[1] = (u32x4){0u, 0u, 0u, 0u};
            z[2] = (u32x4){0u, 0u, 0u, 0u};
        }
    }
    __syncthreads();

    {   // conv1: K=32 (6 used), co 64 (wave owns 16)
        const u16* Wp = Wbf + (size_t)(wave * 16) * 32;
        bf16x8 bw = ldW(Wp, 0, l15, quad, 32);
        floatx4 c[8];
#pragma unroll
        for (int rf = 0; rf < 8; ++rf) {
            bf16x8 a = ldsA(act, rf, l15, quad, 0);
            c[rf] = __builtin_amdgcn_mfma_f32_16x16x32_bf16(a, bw, (floatx4){0.f,0.f,0.f,0.f}, 0, 0, 0);
        }
        float bias = b1[wave * 16 + l15];
        __syncthreads();
#pragma unroll
        for (int rf = 0; rf < 8; ++rf)
#pragma unroll
            for (int r = 0; r < 4; ++r)
                act[(rf * 16 + quad * 4 + r) * RS + wave * 16 + l15] = f2bf(fmaxf(c[rf][r] + bias, 0.0f));
        __syncthreads();
    }

    const int WOFF23[2] = {2048, 6144};
    const float* bp23[2] = {b2, b3};
#pragma unroll 1
    for (int cv = 0; cv < 2; ++cv) {   // conv2 / conv3: K=64, co 64
        const u16* Wp = Wbf + WOFF23[cv] + (size_t)(wave * 16) * 64;
        bf16x8 bw0 = ldW(Wp, 0, l15, quad, 64);
        bf16x8 bw1 = ldW(Wp, 1, l15, quad, 64);
        floatx4 c[8] = {};
#pragma unroll
        for (int ks = 0; ks < 2; ++ks)
#pragma unroll
            for (int rf = 0; rf < 8; ++rf) {
                bf16x8 a = ldsA(act, rf, l15, quad, ks);
                c[rf] = __builtin_amdgcn_mfma_f32_16x16x32_bf16(a, ks ? bw1 : bw0, c[rf], 0, 0, 0);
            }
        float bias = bp23[cv][wave * 16 + l15];
        float mxA = 0.0f, mxB = 0.0f;
#pragma unroll
        for (int rf = 0; rf < 8; ++rf)
#pragma unroll
            for (int r = 0; r < 4; ++r) {
                float v = fmaxf(c[rf][r] + bias, 0.0f);
                if (rf < 4) mxA = fmaxf(mxA, v); else mxB = fmaxf(mxB, v);
            }
        __syncthreads();
#pragma unroll
        for (int rf = 0; rf < 8; ++rf)
#pragma unroll
            for (int r = 0; r < 4; ++r)
                act[(rf * 16 + quad * 4 + r) * RS + wave * 16 + l15] = f2bf(fmaxf(c[rf][r] + bias, 0.0f));
        if (cv == 1) {
            mxA = fmaxf(mxA, __shfl_xor(mxA, 16));
            mxA = fmaxf(mxA, __shfl_xor(mxA, 32));
            mxB = fmaxf(mxB, __shfl_xor(mxB, 16));
            mxB = fmaxf(mxB, __shfl_xor(mxB, 32));
            if (quad == 0) {
                mv[0][wave * 16 + l15] = f2bf(mxA);
                mv[1][wave * 16 + l15] = f2bf(mxB);
            }
        }
        __syncthreads();
    }

    {   // conv4: K=128 ([conv3 | per-node rowmax]), co 128 (wave owns 32)
        const u16* Wp = Wbf + 10240 + (size_t)(wave * 32) * 128;
        bf16x8 bw[2][4];
#pragma unroll
        for (int cf = 0; cf < 2; ++cf)
#pragma unroll
            for (int ks = 0; ks < 4; ++ks)
                bw[cf][ks] = ldW(Wp + (size_t)cf * 16 * 128, ks, l15, quad, 128);
        floatx4 c[8][2] = {};
#pragma unroll
        for (int ks = 0; ks < 4; ++ks)
#pragma unroll
            for (int rf = 0; rf < 8; ++rf) {
                bf16x8 a = (ks < 2) ? ldsA(act, rf, l15, quad, ks)
                                    : *(const bf16x8*)(&mv[rf >> 2][(ks - 2) * 32 + quad * 8]);
#pragma unroll
                for (int cf = 0; cf < 2; ++cf)
                    c[rf][cf] = __builtin_amdgcn_mfma_f32_16x16x32_bf16(a, bw[cf][ks], c[rf][cf], 0, 0, 0);
            }
        float bias[2];
#pragma unroll
        for (int cf = 0; cf < 2; ++cf) bias[cf] = b4[wave * 32 + cf * 16 + l15];
        __syncthreads();
#pragma unroll
        for (int rf = 0; rf < 8; ++rf)
#pragma unroll
            for (int cf = 0; cf < 2; ++cf)
#pragma unroll
                for (int r = 0; r < 4; ++r)
                    act[(rf * 16 + quad * 4 + r) * RS + wave * 32 + cf * 16 + l15] =
                        f2bf(fmaxf(c[rf][cf][r] + bias[cf], 0.0f));
        __syncthreads();
    }

    {   // conv5 + per-node maxpool -> h[bm][0:128]
        const u16* Wp = Wbf + 26624 + (size_t)(wave * 32) * 128;
        bf16x8 bw[2][4];
#pragma unroll
        for (int cf = 0; cf < 2; ++cf)
#pragma unroll
            for (int ks = 0; ks < 4; ++ks)
                bw[cf][ks] = ldW(Wp + (size_t)cf * 16 * 128, ks, l15, quad, 128);
        floatx4 c[8][2] = {};
#pragma unroll
        for (int ks = 0; ks < 4; ++ks)
#pragma unroll
            for (int rf = 0; rf < 8; ++rf) {
                bf16x8 a = ldsA(act, rf, l15, quad, ks);
#pragma unroll
                for (int cf = 0; cf < 2; ++cf)
                    c[rf][cf] = __builtin_amdgcn_mfma_f32_16x16x32_bf16(a, bw[cf][ks], c[rf][cf], 0, 0, 0);
            }
#pragma unroll
        for (int cf = 0; cf < 2; ++cf) {
            float bias = b5[wave * 32 + cf * 16 + l15];
            float mxA = 0.0f, mxB = 0.0f;
#pragma unroll
            for (int rf = 0; rf < 8; ++rf)
#pragma unroll
                for (int r = 0; r < 4; ++r) {
                    float v = fmaxf(c[rf][cf][r] + bias, 0.0f);
                    if (rf < 4) mxA = fmaxf(mxA, v); else mxB = fmaxf(mxB, v);
                }
            mxA = fmaxf(mxA, __shfl_xor(mxA, 16));
            mxA = fmaxf(mxA, __shfl_xor(mxA, 32));
            mxB = fmaxf(mxB, __shfl_xor(mxB, 16));
            mxB = fmaxf(mxB, __shfl_xor(mxB, 32));
            if (quad == 0) {
                h[(size_t)bm0 * 640 + wave * 32 + cf * 16 + l15] = f2bf(mxA);
                h[(size_t)(bm0 + 1) * 640 + wave * 32 + cf * 16 + l15] = f2bf(mxB);
            }
        }
    }
}

// ---------------------------------------------------------------------------
// In-LDS in-place conv with 4-deep weight prefetch (3 k-steps ahead in flight).
// act tile: (RF*16) rows x RSx u16 cols. Wave owns out cols [cb, cb+CF*16).
// ---------------------------------------------------------------------------
template <int KS, int CF, int RF, int RSx>
__device__ __forceinline__ void conv_inplace(u16* act, const u16* __restrict__ W0, int KP,
                                             const float* __restrict__ bias, int cb,
                                             int l15, int quad) {
    floatx4 acc[RF][CF];
#pragma unroll
    for (int rf = 0; rf < RF; ++rf)
#pragma unroll
        for (int cf = 0; cf < CF; ++cf) acc[rf][cf] = (floatx4){0.f, 0.f, 0.f, 0.f};

    bf16x8 bw[4][CF];
#pragma unroll
    for (int p = 0; p < 3; ++p)
        if (p < KS)
#pragma unroll
            for (int cf = 0; cf < CF; ++cf)
                bw[p][cf] = *(const bf16x8*)(W0 + (size_t)(cb + cf * 16 + l15) * KP +
                                             p * 32 + quad * 8);

#pragma unroll
    for (int ks = 0; ks < KS; ++ks) {
        if (ks + 3 < KS) {
#pragma unroll
            for (int cf = 0; cf < CF; ++cf)
                bw[(ks + 3) & 3][cf] = *(const bf16x8*)(W0 + (size_t)(cb + cf * 16 + l15) * KP +
                                                        (ks + 3) * 32 + quad * 8);
        }
#pragma unroll
        for (int rf = 0; rf < RF; ++rf) {
            bf16x8 a = *(const bf16x8*)(act + (rf * 16 + l15) * RSx + ks * 32 + quad * 8);
#pragma unroll
            for (int cf = 0; cf < CF; ++cf)
                acc[rf][cf] = __builtin_amdgcn_mfma_f32_16x16x32_bf16(a, bw[ks & 3][cf], acc[rf][cf], 0, 0, 0);
        }
    }
    __syncthreads();   // all waves' reads complete before in-place writes
#pragma unroll
    for (int cf = 0; cf < CF; ++cf) {
        float bs = bias[cb + cf * 16 + l15];
#pragma unroll
        for (int rf = 0; rf < RF; ++rf)
#pragma unroll
            for (int r = 0; r < 4; ++r)
                act[(rf * 16 + quad * 4 + r) * RSx + cb + cf * 16 + l15] =
                    f2bf(fmaxf(acc[rf][cf][r] + bs, 0.0f));
    }
    __syncthreads();
}

// ---------------------------------------------------------------------------
// Fused stage 2: one block per 8 nodes, 512 threads (8 waves = 2/SIMD).
// Col-split c=8 halves LDS A-re-reads vs 16 waves; depth-4 weight prefetch
// covers the L2 latency that round 5's depth-1 ping-pong exposed.
// ---------------------------------------------------------------------------
static constexpr int RS2 = 520;

__global__ __launch_bounds__(512, 2) void fused_stage2_kernel(
    const float* __restrict__ node, u16* __restrict__ h, const int* __restrict__ knn,
    const u16* __restrict__ Wbf,
    const float* __restrict__ bb1, const float* __restrict__ bb2,
    const float* __restrict__ bb3, const float* __restrict__ ba1,
    const float* __restrict__ ba2) {
    __shared__ __align__(16) u16 act[80 * RS2];   // 83,200 B
    int blk = blockIdx.x;              // 0..255
    int node0 = blk * 8;
    int b = node0 >> 9;
    int tid = threadIdx.x, wave = tid >> 6, lane = tid & 63;
    int quad = lane >> 4, l15 = lane & 15;
    (void)lane;

    for (int e = tid; e < 80 * 20; e += 512)
        *(u16x8*)(act + (e / 20) * RS2 + (e % 20) * 8) = (u16x8){0,0,0,0,0,0,0,0};
    __syncthreads();
    for (int e = tid; e < 72 * 3; e += 512) {
        int r = e / 3, c = e - r * 3;
        int nodei = node0 + r / 9;
        int j = knn[(size_t)nodei * 9 + (r % 9)];
        float v = node[((size_t)b * 3 + c) * M_ + j] - node[((size_t)b * 3 + c) * M_ + (nodei & 511)];
        act[r * RS2 + c] = f2bf(v);
    }
    for (int e = tid; e < 72 * 16; e += 512) {
        int r = e >> 4, s = e & 15;
        int nodei = node0 + r / 9;
        int j = knn[(size_t)nodei * 9 + (r % 9)];
        *(u16x8*)(act + r * RS2 + 8 + s * 8) =
            *(const u16x8*)(h + (size_t)(b * 512 + j) * 640 + s * 8);
    }
    __syncthreads();

    // knnb1: K=160 -> 256 ; knnb2/3: 256 -> 256 (wave owns 32 cols)
    conv_inplace<5, 2, 5, RS2>(act, Wbf + 43008, 160, bb1, wave * 32, l15, quad);
    conv_inplace<8, 2, 5, RS2>(act, Wbf + 83968, 256, bb2, wave * 32, l15, quad);
    conv_inplace<8, 2, 5, RS2>(act, Wbf + 149504, 256, bb3, wave * 32, l15, quad);

    // gmax: per node max over 9 rows of cols 0..255 -> bcast cols 256..511
    for (int e = tid; e < 8 * 32; e += 512) {
        int li = e >> 5, s = e & 31;
        int r0 = li * 9;
        float mx[8];
#pragma unroll
        for (int i = 0; i < 8; ++i) mx[i] = -3.0e38f;
#pragma unroll
        for (int kk = 0; kk < 9; ++kk) {
            u16x8 v = *(const u16x8*)(act + (r0 + kk) * RS2 + s * 8);
#pragma unroll
            for (int i = 0; i < 8; ++i) mx[i] = fmaxf(mx[i], bf2f(v[i]));
        }
        u16x8 o;
#pragma unroll
        for (int i = 0; i < 8; ++i) o[i] = f2bf(mx[i]);
#pragma unroll
        for (int kk = 0; kk < 9; ++kk)
            *(u16x8*)(act + (r0 + kk) * RS2 + 256 + s * 8) = o;
    }
    __syncthreads();

    // knna1/2: K=512 -> 512 (wave owns 64 cols)
    conv_inplace<16, 4, 5, RS2>(act, Wbf + 215040, 512, ba1, wave * 64, l15, quad);
    conv_inplace<16, 4, 5, RS2>(act, Wbf + 477184, 512, ba2, wave * 64, l15, quad);

    // pool: per node max over 9 rows -> h[nodei][128..639]
    for (int e = tid; e < 8 * 64; e += 512) {
        int li = e >> 6, s = e & 63;
        int r0 = li * 9;
        float mx[8];
#pragma unroll
        for (int i = 0; i < 8; ++i) mx[i] = -3.0e38f;
#pragma unroll
        for (int kk = 0; kk < 9; ++kk) {
            u16x8 v = *(const u16x8*)(act + (r0 + kk) * RS2 + s * 8);
#pragma unroll
            for (int i = 0; i < 8; ++i) mx[i] = fmaxf(mx[i], bf2f(v[i]));
        }
        u16x8 o;
#pragma unroll
        for (int i = 0; i < 8; ++i) o[i] = f2bf(mx[i]);
        *(u16x8*)(h + (size_t)(node0 + li) * 640 + 128 + s * 8) = o;
    }
}

// ---------------------------------------------------------------------------
// Fused stage 3: 256 blocks x 8 nodes, 512 threads (8 waves).
// ---------------------------------------------------------------------------
static constexpr int RS3 = 648;

__global__ __launch_bounds__(512, 2) void fused_stage3_kernel(
    const float* __restrict__ node, const u16* __restrict__ h,
    const u16* __restrict__ Wbf,
    const float* __restrict__ bm1, const float* __restrict__ bm2,
    const float* __restrict__ w3, const float* __restrict__ b3,
    float* __restrict__ out) {
    __shared__ __align__(16) u16 act[16 * RS3];   // 20,736 B
    int blk = blockIdx.x;              // 0..255
    int node0 = blk * 8;
    int tid = threadIdx.x, lane = tid & 63, wave = tid >> 6;
    int quad = lane >> 4, l15 = lane & 15;

    for (int e = tid; e < 16 * 80; e += 512) {
        int r = e / 80, seg = e - r * 80;
        u16x8 v = (r < 8) ? *(const u16x8*)(h + (size_t)(node0 + r) * 640 + seg * 8)
                          : (u16x8){0,0,0,0,0,0,0,0};
        *(u16x8*)(act + r * RS3 + seg * 8) = v;
    }
    __syncthreads();

    conv_inplace<20, 4, 1, RS3>(act, Wbf + 739328, 640, bm1, wave * 64, l15, quad);
    conv_inplace<16, 2, 1, RS3>(act, Wbf + 1067008, 512, bm2, wave * 32, l15, quad);

    if (tid < 32) {
        int li = tid >> 2, oc = tid & 3;
        const u16* row = act + li * RS3;
        const float* wrow = w3 + oc * 256;
        float a = 0.0f;
        for (int c = 0; c < 256; c += 4) {
            a += bf2f(row[c]) * wrow[c];
            a += bf2f(row[c + 1]) * wrow[c + 1];
            a += bf2f(row[c + 2]) * wrow[c + 2];
            a += bf2f(row[c + 3]) * wrow[c + 3];
        }
        a += b3[oc];
        int nodei = node0 + li;
        int b = nodei >> 9, m = nodei & 511;
        if (oc < 3) {
            float nv = node[((size_t)b * 3 + oc) * M_ + m];
            out[((size_t)b * 3 + oc) * M_ + m] = nv;
            out[6144 + ((size_t)b * 3 + oc) * M_ + m] = nv + a;
        } else {
            out[12288 + nodei] = fmaxf(a, 0.0f) + log1pf(expf(-fabsf(a))) + 0.001f;
        }
    }
}

// ---------------------------------------------------------------------------
extern "C" void kernel_launch(void* const* d_in, const int* in_sizes, int n_in,
                              void* d_out, int out_size, void* d_ws, size_t ws_size,
                              hipStream_t stream) {
    (void)in_sizes; (void)n_in; (void)out_size; (void)ws_size;
    const float* x = (const float*)d_in[0];
    const float* sn = (const float*)d_in[1];
    const float* node = (const float*)d_in[2];
    const float* W[13];
    const float* Bs[13];
    for (int i = 0; i < 13; ++i) {
        W[i] = (const float*)d_in[3 + 2 * i];
        Bs[i] = (const float*)d_in[4 + 2 * i];
    }
    float* out = (float*)d_out;

    char* ws = (char*)d_ws;
    int* idx = (int*)(ws + 0);                 //   524,288
    int* knn = (int*)(ws + 524288);            //    73,728
    u16* Wbf = (u16*)(ws + 598016);            // 2,396,160
    u16* h   = (u16*)(ws + 2994176);           // 2,621,440 (2048 x 640)

    WConvArgs wa;
    for (int w = 0; w < 12; ++w) wa.src[w] = W[w];

    prep_kernel<<<7240, 256, 0, stream>>>(x, node, idx, knn, wa, Wbf);

    fused_stage1_kernel<<<1024, 256, 0, stream>>>(x, sn, node, idx, Wbf,
                                                  Bs[0], Bs[1], Bs[2], Bs[3], Bs[4], h);
    fused_stage2_kernel<<<256, 512, 0, stream>>>(node, h, knn, Wbf,
                                                 Bs[5], Bs[6], Bs[7], Bs[8], Bs[9]);
    fused_stage3_kernel<<<256, 512, 0, stream>>>(node, h, Wbf, Bs[10], Bs[11],
                                                 W[12], Bs[12], out);
}